// Round 2
// baseline (588.651 us; speedup 1.0000x reference)
//
#include <hip/hip_runtime.h>
#include <hip/hip_bf16.h>

typedef __hip_bfloat16 bf16;
typedef __attribute__((ext_vector_type(8))) short short8;   // 8 bf16 (4 VGPRs)
typedef __attribute__((ext_vector_type(4))) float f32x4;

#define NB 2
#define NT 2048
#define ND 2048
#define NH 32
#define NM (NB*NT)   // 4096 rows
#define NCH 32       // chunks per (b,h): NT/64

// ---- dtype hedge: inputs may be bf16 (harness-converted) or fp32 (per reference) ----
__global__ void detect_dtype(const unsigned short* __restrict__ hs, int* __restrict__ flag) {
  if (threadIdx.x == 0 && blockIdx.x == 0) {
    int cnt = 0;
    for (int i = 0; i < 2048; i += 2) {
      int e = (hs[i] >> 7) & 0xFF;
      if (e >= 141) ++cnt;
    }
    *flag = (cnt > 64) ? 1 : 0;   // 1 = fp32, 0 = bf16
  }
}

__device__ __forceinline__ float loadf(const void* p, size_t i, int isf32) {
  return isf32 ? ((const float*)p)[i] : __bfloat162float(((const bf16*)p)[i]);
}

__global__ __launch_bounds__(256) void convert_bf16(const void* __restrict__ src,
                                                    bf16* __restrict__ dst,
                                                    long n, const int* __restrict__ flag) {
  const long i0 = ((long)blockIdx.x * 256 + threadIdx.x) * 8;
  if (i0 >= n) return;
  if (*flag) {
    const float* s = (const float*)src;
    #pragma unroll
    for (int j = 0; j < 8; ++j) dst[i0 + j] = __float2bfloat16(s[i0 + j]);
  } else {
    *(short8*)(dst + i0) = *(const short8*)((const bf16*)src + i0);
  }
}

// ---- transpose + convert one matrix: dst[c][r] = bf16(src[r][c]); zero-pad cols ----
__global__ __launch_bounds__(256) void transpose_cvt(const void* __restrict__ src,
                                                     bf16* __restrict__ dst,
                                                     int src_rows, int src_cols,
                                                     const int* __restrict__ flag) {
  __shared__ bf16 tile[64][65];
  const int f = *flag;
  const int tb_r = blockIdx.y * 64, tb_c = blockIdx.x * 64;
  const int tx = threadIdx.x & 63, ty = threadIdx.x >> 6;
  #pragma unroll
  for (int i = 0; i < 64; i += 4) {
    const int cc = tb_c + tx;
    tile[i + ty][tx] = (cc < src_cols)
      ? __float2bfloat16(loadf(src, (size_t)(tb_r + i + ty) * src_cols + cc, f))
      : __float2bfloat16(0.f);
  }
  __syncthreads();
  #pragma unroll
  for (int i = 0; i < 64; i += 4)
    dst[(size_t)(tb_c + i + ty) * src_rows + tb_r + tx] = tile[tx][i + ty];
}

// ---- merged transpose of Wq/Wk/Wv/Wb into WT, z-sliced (beta block padded to 256 rows) ----
__global__ __launch_bounds__(256) void transpose_qkvb(const void* __restrict__ Wq,
                                                      const void* __restrict__ Wk,
                                                      const void* __restrict__ Wv,
                                                      const void* __restrict__ Wb,
                                                      bf16* __restrict__ WT,
                                                      const int* __restrict__ flag) {
  __shared__ bf16 tile[64][65];
  const int z = blockIdx.z;
  if (z == 3 && blockIdx.x >= 4) return;   // Wb^T: 256 padded rows
  const void* src = (z == 0) ? Wq : (z == 1) ? Wk : (z == 2) ? Wv : Wb;
  const int src_cols = (z == 3) ? 32 : 2048;
  bf16* dst = WT + (size_t)z * 2048 * 2048;
  const int f = *flag;
  const int tb_r = blockIdx.y * 64, tb_c = blockIdx.x * 64;
  const int tx = threadIdx.x & 63, ty = threadIdx.x >> 6;
  #pragma unroll
  for (int i = 0; i < 64; i += 4) {
    const int cc = tb_c + tx;
    tile[i + ty][tx] = (cc < src_cols)
      ? __float2bfloat16(loadf(src, (size_t)(tb_r + i + ty) * src_cols + cc, f))
      : __float2bfloat16(0.f);
  }
  __syncthreads();
  #pragma unroll
  for (int i = 0; i < 64; i += 4)
    dst[(size_t)(tb_c + i + ty) * 2048 + tb_r + tx] = tile[tx][i + ty];
}

// async 16B/lane global->LDS (wave-uniform LDS base + lane*16)
__device__ __forceinline__ void gload_lds16(const void* g, void* l) {
  __builtin_amdgcn_global_load_lds((__attribute__((address_space(1))) const void*)g,
                                   (__attribute__((address_space(3))) void*)l,
                                   16, 0, 0);
}

// ------------- legacy GEMM (out-projection + fallback): C = A @ Bt^T -------------
__global__ __launch_bounds__(256) void gemm_bt(const bf16* __restrict__ A,
                                               const bf16* __restrict__ Bt,
                                               bf16* __restrict__ oq, bf16* __restrict__ ok2,
                                               bf16* __restrict__ ov, bf16* __restrict__ ob,
                                               void* __restrict__ outv,
                                               const int* __restrict__ outflag,
                                               int M, int K, int n_base) {
  __shared__ bf16 As[128 * 32];
  __shared__ bf16 Bs[128 * 32];
  const int tid = threadIdx.x;
  const int wave = tid >> 6, lane = tid & 63;
  const int m0 = blockIdx.y * 128, n0 = blockIdx.x * 128;
  const int wm = (wave >> 1) * 64, wn = (wave & 1) * 64;
  const int srow = lane >> 2, scol = (lane & 3) * 8;
  const int frow = lane & 15, fk = (lane >> 4) * 8;
  f32x4 acc[4][4] = {};

  for (int kb = 0; kb < K; kb += 32) {
    __syncthreads();
    #pragma unroll
    for (int j = 0; j < 2; ++j) {
      const int rbase = wave * 32 + j * 16;
      gload_lds16(A  + (size_t)(m0 + rbase + srow) * K + kb + scol, As + rbase * 32);
      gload_lds16(Bt + (size_t)(n0 + rbase + srow) * K + kb + scol, Bs + rbase * 32);
    }
    __syncthreads();
    short8 af[4], bfr[4];
    #pragma unroll
    for (int i = 0; i < 4; ++i)
      af[i] = *(const short8*)(As + (wm + i * 16 + frow) * 32 + fk);
    #pragma unroll
    for (int i = 0; i < 4; ++i)
      bfr[i] = *(const short8*)(Bs + (wn + i * 16 + frow) * 32 + fk);
    #pragma unroll
    for (int mi = 0; mi < 4; ++mi)
      #pragma unroll
      for (int ni = 0; ni < 4; ++ni)
        acc[mi][ni] = __builtin_amdgcn_mfma_f32_16x16x32_bf16(af[mi], bfr[ni], acc[mi][ni], 0, 0, 0);
  }

  const int crow = (lane >> 4) * 4, ccol = lane & 15;
  const int gn0 = n_base + n0;
  if (outflag) {
    const int f = *outflag;
    #pragma unroll
    for (int mi = 0; mi < 4; ++mi)
      #pragma unroll
      for (int ni = 0; ni < 4; ++ni)
        #pragma unroll
        for (int r = 0; r < 4; ++r) {
          const size_t idx = (size_t)(m0 + wm + mi * 16 + crow + r) * 2048 + gn0 + wn + ni * 16 + ccol;
          const float val = acc[mi][ni][r];
          if (f == 1) ((float*)outv)[idx] = val;
          else        ((bf16*)outv)[idx] = __float2bfloat16(val);
        }
  } else {
    const int seg = gn0 >> 11;
    bf16* o = (seg == 0) ? oq : (seg == 1) ? ok2 : (seg == 2) ? ov : ob;
    const int stride = (seg < 3) ? 2048 : 128;
    const int cb = (gn0 & 2047) + wn;
    if (seg <= 1) {
      #pragma unroll
      for (int mi = 0; mi < 4; ++mi)
        #pragma unroll
        for (int r = 0; r < 4; ++r) {
          float s = acc[mi][0][r] * acc[mi][0][r] + acc[mi][1][r] * acc[mi][1][r]
                  + acc[mi][2][r] * acc[mi][2][r] + acc[mi][3][r] * acc[mi][3][r];
          s += __shfl_xor(s, 1, 64); s += __shfl_xor(s, 2, 64);
          s += __shfl_xor(s, 4, 64); s += __shfl_xor(s, 8, 64);
          const float inv = rsqrtf(s + 1e-6f);
          #pragma unroll
          for (int ni = 0; ni < 4; ++ni) acc[mi][ni][r] *= inv;
        }
    }
    #pragma unroll
    for (int mi = 0; mi < 4; ++mi)
      #pragma unroll
      for (int ni = 0; ni < 4; ++ni)
        #pragma unroll
        for (int r = 0; r < 4; ++r)
          o[(size_t)(m0 + wm + mi * 16 + crow + r) * stride + cb + ni * 16 + ccol] =
            __float2bfloat16(acc[mi][ni][r]);
  }
}

// ============ 256x256 8-phase GEMM (T2 swizzle + T3/T4 counted vmcnt + T5 setprio) ============
// C = A[M][K] @ Bt[N][K]^T, routed epilogue (fused QKVB). N = 25 tiles (6400, beta stride 256).
// 8 waves (2M x 4N), BK=64, 128 KiB LDS double-buffer. A-frags register-prefetched at phase 0
// (A LDS slots die at p0 -> A-halves staged 6-7 phases ahead; B-halves 3-4 ahead).
// Boundary s_waitcnt vmcnt(4) once per K-tile (never 0 mid-loop); tail drains with vmcnt(0).

#define MFMA_Q(MB, NB_)                                                          \
  _Pragma("unroll") for (int mi2 = 0; mi2 < 4; ++mi2) {                          \
    _Pragma("unroll") for (int ni2 = 0; ni2 < 2; ++ni2) {                        \
      acc[(MB) + mi2][(NB_) + ni2] = __builtin_amdgcn_mfma_f32_16x16x32_bf16(    \
          aF[(MB) + mi2][0], bF[ni2][0], acc[(MB) + mi2][(NB_) + ni2], 0, 0, 0); \
      acc[(MB) + mi2][(NB_) + ni2] = __builtin_amdgcn_mfma_f32_16x16x32_bf16(    \
          aF[(MB) + mi2][1], bF[ni2][1], acc[(MB) + mi2][(NB_) + ni2], 0, 0, 0); \
    } }

#define READ_B(NBASE)                                                            \
  _Pragma("unroll") for (int ni2 = 0; ni2 < 2; ++ni2)                            \
    _Pragma("unroll") for (int kk = 0; kk < 2; ++kk)                             \
      bF[ni2][kk] = *(const short8*)((const char*)lB +                           \
        (brow0 + ((NBASE) + ni2) * 16 + frow) * 128 + kk * 64 + fcol);

#define PH_OPEN() do { __builtin_amdgcn_s_barrier();                             \
  asm volatile("s_waitcnt lgkmcnt(0)" ::: "memory");                             \
  __builtin_amdgcn_sched_barrier(0);                                             \
  __builtin_amdgcn_s_setprio(1); } while (0)

#define PH_CLOSE() do { __builtin_amdgcn_s_setprio(0);                           \
  __builtin_amdgcn_s_barrier(); } while (0)

__global__ __launch_bounds__(512, 2) void gemm256(const bf16* __restrict__ A,
                                                  const bf16* __restrict__ Bt,
                                                  bf16* __restrict__ oq, bf16* __restrict__ ok2,
                                                  bf16* __restrict__ ov, bf16* __restrict__ ob,
                                                  int K, int ntn) {
  __shared__ bf16 LA[2][2][8192];   // [parity][half(128 rows)][128*64]
  __shared__ bf16 LB[2][2][8192];
  const int tid = threadIdx.x;
  const int wave = tid >> 6, lane = tid & 63;
  const int wm = wave >> 2, wn = wave & 3;
  const int frow = lane & 15, fq = lane >> 4;
  // bijective XCD swizzle (gridDim.x % 8 == 0 by construction)
  const int cpx = (int)gridDim.x >> 3;
  const int wg = ((int)blockIdx.x & 7) * cpx + ((int)blockIdx.x >> 3);
  const int mtile = wg / ntn, ntile = wg % ntn;
  const int m0 = mtile * 256, n0 = ntile * 256;
  const int NTK = K >> 6;
  // st_16x32 swizzle: phys = logical ^ (((logical>>9)&1)<<5); for frag reads bit9 = frow bit2
  const int fcol = (fq * 16) ^ (((frow >> 2) & 1) << 5);
  // staging: linear LDS dest (wave*1024 + j*8192 + lane*16); pre-swizzled global source
  int srow[2], scolb[2];
  #pragma unroll
  for (int j = 0; j < 2; ++j) {
    const int q = wave * 1024 + j * 8192 + lane * 16;
    const int qs = q ^ (((q >> 9) & 1) << 5);
    srow[j] = qs >> 7;
    scolb[j] = (qs & 127) >> 1;   // element col within 64
  }
  const int lofs = wave * 1024;

  f32x4 acc[8][4] = {};

  auto STAGE = [&](const bf16* __restrict__ G, int row0, int kcol, bf16* lhalf) {
    #pragma unroll
    for (int j = 0; j < 2; ++j)
      gload_lds16(G + (size_t)(row0 + srow[j]) * K + kcol + scolb[j],
                  (char*)lhalf + lofs + j * 8192);
  };

  // prologue: tile0 all 4 halves + tile1 A halves; leave tile1 A in flight
  STAGE(A,  m0,       0,  LA[0][0]);
  STAGE(A,  m0 + 128, 0,  LA[0][1]);
  STAGE(Bt, n0,       0,  LB[0][0]);
  STAGE(Bt, n0 + 128, 0,  LB[0][1]);
  STAGE(A,  m0,       64, LA[1][0]);
  STAGE(A,  m0 + 128, 64, LA[1][1]);
  asm volatile("s_waitcnt vmcnt(4)" ::: "memory");
  __builtin_amdgcn_s_barrier();

  const int brow0 = (wn & 1) * 64;
  #pragma unroll 1
  for (int t = 0; t < NTK; ++t) {
    const int par = t & 1;
    const bf16* lA = LA[par][wm];
    const bf16* lB = LB[par][wn >> 1];
    short8 aF[8][2], bF[2][2];
    // ---- phase 0: all A frags + B ni{0,1}; stage (t+1):B0 ----
    #pragma unroll
    for (int mi = 0; mi < 8; ++mi)
      #pragma unroll
      for (int kk = 0; kk < 2; ++kk)
        aF[mi][kk] = *(const short8*)((const char*)lA + (mi * 16 + frow) * 128 + kk * 64 + fcol);
    READ_B(0)
    if (t + 1 < NTK) STAGE(Bt, n0, (t + 1) * 64, LB[par ^ 1][0]);
    PH_OPEN();
    MFMA_Q(0, 0)
    PH_CLOSE();
    // ---- phase 1: B ni{2,3}; stage (t+1):B1, (t+2):A0 ----
    READ_B(2)
    if (t + 1 < NTK) STAGE(Bt, n0 + 128, (t + 1) * 64, LB[par ^ 1][1]);
    if (t + 2 < NTK) STAGE(A, m0, (t + 2) * 64, LA[par][0]);
    PH_OPEN();
    MFMA_Q(0, 2)
    PH_CLOSE();
    // ---- phase 2: B ni{0,1}; stage (t+2):A1 ----
    READ_B(0)
    if (t + 2 < NTK) STAGE(A, m0 + 128, (t + 2) * 64, LA[par][1]);
    PH_OPEN();
    MFMA_Q(4, 0)
    PH_CLOSE();
    // ---- phase 3: B ni{2,3}; boundary counted vmcnt ----
    READ_B(2)
    PH_OPEN();
    MFMA_Q(4, 2)
    __builtin_amdgcn_s_setprio(0);
    if (t + 1 < NTK) {
      if (t == NTK - 2) asm volatile("s_waitcnt vmcnt(0)" ::: "memory");
      else              asm volatile("s_waitcnt vmcnt(4)" ::: "memory");
      __builtin_amdgcn_s_barrier();
    }
  }

  // routed epilogue: seg 0/1 l2norm per 64-col head, 2 plain, 3 beta (stride 256)
  const int crow = fq * 4, ccol = frow;
  const int gn0w = n0 + wn * 64;
  const int seg = gn0w >> 11;
  bf16* o = (seg == 0) ? oq : (seg == 1) ? ok2 : (seg == 2) ? ov : ob;
  const int stride = (seg < 3) ? 2048 : 256;
  const int cb = (seg < 3) ? (gn0w & 2047) : (gn0w - 6144);
  if (seg <= 1) {
    #pragma unroll
    for (int mi = 0; mi < 8; ++mi)
      #pragma unroll
      for (int r = 0; r < 4; ++r) {
        float s = acc[mi][0][r] * acc[mi][0][r] + acc[mi][1][r] * acc[mi][1][r]
                + acc[mi][2][r] * acc[mi][2][r] + acc[mi][3][r] * acc[mi][3][r];
        s += __shfl_xor(s, 1, 64); s += __shfl_xor(s, 2, 64);
        s += __shfl_xor(s, 4, 64); s += __shfl_xor(s, 8, 64);
        const float inv = rsqrtf(s + 1e-6f);
        #pragma unroll
        for (int ni = 0; ni < 4; ++ni) acc[mi][ni][r] *= inv;
      }
  }
  const int rowb = m0 + wm * 128;
  #pragma unroll
  for (int mi = 0; mi < 8; ++mi)
    #pragma unroll
    for (int ni = 0; ni < 4; ++ni)
      #pragma unroll
      for (int r = 0; r < 4; ++r)
        o[(size_t)(rowb + mi * 16 + crow + r) * stride + cb + ni * 16 + ccol] =
          __float2bfloat16(acc[mi][ni][r]);
}

// ======================= fused-path chunk kernels =======================

template<int TB>
__device__ __forceinline__ void scan16(const float* __restrict__ Af,
                                       const bf16* __restrict__ vsrc,
                                       const float* __restrict__ Bsc,
                                       float (&u)[64], const int lane, const int wave,
                                       const float sgn,
                                       bf16* __restrict__ outT,
                                       bf16* __restrict__ gout) {
  constexpr int JM = (TB + 1) * 16;
  #pragma unroll
  for (int tt = 0; tt < 16; ++tt) {
    const int t = TB * 16 + tt;
    float pr0 = 0.f, pr1 = 0.f, pr2 = 0.f, pr3 = 0.f;
    #pragma unroll
    for (int i = 0; i < JM; i += 4) {
      const f32x4 a = *(const f32x4*)(Af + t * 64 + i);   // wave-uniform row read
      pr0 = __builtin_fmaf(a[0], u[i + 0], pr0);
      pr1 = __builtin_fmaf(a[1], u[i + 1], pr1);
      pr2 = __builtin_fmaf(a[2], u[i + 2], pr2);
      pr3 = __builtin_fmaf(a[3], u[i + 3], pr3);
    }
    const float ut = Bsc[t] * __bfloat162float(vsrc[t * 72 + lane])
                   - ((pr0 + pr1) + (pr2 + pr3));
    u[t] = ut;
    const bf16 sv = __float2bfloat16(sgn * ut);
    outT[lane * 72 + t] = sv;
    if (wave) gout[t * 64 + lane] = sv;
  }
}

// pass 1: A = beta*tril(K K^T) via MFMA (fp32 LDS), then two register forward substitutions.
__global__ __launch_bounds__(256) void chunk_scan(const bf16* __restrict__ k16,
                                                  bf16* __restrict__ v16,
                                                  const bf16* __restrict__ betab,
                                                  const void* __restrict__ bb,
                                                  const int* __restrict__ flag,
                                                  bf16* __restrict__ Gneg,
                                                  bf16* __restrict__ AcT,
                                                  bf16* __restrict__ Dc) {
  __shared__ bf16 Ks[64 * 72];
  __shared__ bf16 Vs[64 * 72];
  __shared__ bf16 GsT[64 * 72];
  __shared__ bf16 UsT[64 * 72];
  __shared__ float Af[64 * 64];
  __shared__ float Bsc[64];
  bf16* const KTs = (bf16*)Af;
  const int ch = blockIdx.x;
  const int c = ch & (NCH - 1), bh = ch >> 5;
  const int h = bh & (NH - 1), b = bh >> 5;
  const int tid = threadIdx.x, wave = tid >> 6, lane = tid & 63;
  const size_t rowb = ((size_t)b * NT + c * 64) * ND + (size_t)h * 64;

  short8 ktA0, ktB0, ktA1, ktB1;
  if (wave >= 2) {
    const int d0a = (wave - 2) * 16, d0b = d0a + 32;
    ktA0 = *(const short8*)(k16 + rowb + (size_t)lane * ND + d0a);
    ktB0 = *(const short8*)(k16 + rowb + (size_t)lane * ND + d0a + 8);
    ktA1 = *(const short8*)(k16 + rowb + (size_t)lane * ND + d0b);
    ktB1 = *(const short8*)(k16 + rowb + (size_t)lane * ND + d0b + 8);
  }
  {
    const int r0 = tid >> 3, sc = (tid & 7) * 8;
    #pragma unroll
    for (int rnd = 0; rnd < 2; ++rnd) {
      const int r = rnd * 32 + r0;
      *(short8*)(Ks + r * 72 + sc) = *(const short8*)(k16 + rowb + (size_t)r * ND + sc);
      *(short8*)(Vs + r * 72 + sc) = *(const short8*)(v16 + rowb + (size_t)r * ND + sc);
    }
  }
  if (tid < 64) {
    const float x = __bfloat162float(betab[((size_t)b * NT + c * 64 + tid) * 256 + h])
                    + loadf(bb, h, *flag);
    Bsc[tid] = 1.f / (1.f + expf(-x));
  }
  __syncthreads();

  const int frow = lane & 15, fk = (lane >> 4) * 8, cm = (lane >> 4) * 4;
  {
    short8 ma0 = *(const short8*)(Ks + (16 * wave + frow) * 72 + fk);
    short8 ma1 = *(const short8*)(Ks + (16 * wave + frow) * 72 + 32 + fk);
    #pragma unroll
    for (int n = 0; n < 4; ++n) {
      f32x4 m = {};
      m = __builtin_amdgcn_mfma_f32_16x16x32_bf16(ma0, *(const short8*)(Ks + (16 * n + frow) * 72 + fk), m, 0, 0, 0);
      m = __builtin_amdgcn_mfma_f32_16x16x32_bf16(ma1, *(const short8*)(Ks + (16 * n + frow) * 72 + 32 + fk), m, 0, 0, 0);
      #pragma unroll
      for (int r = 0; r < 4; ++r) {
        const int t = 16 * wave + cm + r, s = 16 * n + frow;
        Af[t * 64 + s] = (s < t) ? Bsc[t] * m[r] : 0.f;
      }
    }
  }
  __syncthreads();

  if (wave < 2) {
    float u[64];
    #pragma unroll
    for (int i = 0; i < 64; ++i) u[i] = 0.f;
    const bf16* vsrc = wave ? Ks : Vs;
    bf16* outT = wave ? GsT : UsT;
    bf16* gout = Gneg + (size_t)ch * 4096;
    const float sgn = wave ? -1.f : 1.f;
    scan16<0>(Af, vsrc, Bsc, u, lane, wave, sgn, outT, gout);
    scan16<1>(Af, vsrc, Bsc, u, lane, wave, sgn, outT, gout);
    scan16<2>(Af, vsrc, Bsc, u, lane, wave, sgn, outT, gout);
    scan16<3>(Af, vsrc, Bsc, u, lane, wave, sgn, outT, gout);
  }
  __syncthreads();

  if (wave >= 2) {
    const int d0a = (wave - 2) * 16, d0b = d0a + 32;
    #pragma unroll
    for (int j = 0; j < 8; ++j) {
      KTs[(d0a + j) * 72 + lane]     = ((const bf16*)&ktA0)[j];
      KTs[(d0a + 8 + j) * 72 + lane] = ((const bf16*)&ktB0)[j];
      KTs[(d0b + j) * 72 + lane]     = ((const bf16*)&ktA1)[j];
      KTs[(d0b + 8 + j) * 72 + lane] = ((const bf16*)&ktB1)[j];
    }
  }
  __syncthreads();

  short8 ka0 = *(const short8*)(KTs + (16 * wave + frow) * 72 + fk);
  short8 ka1 = *(const short8*)(KTs + (16 * wave + frow) * 72 + 32 + fk);
  short8 uu0 = *(const short8*)(UsT + (16 * wave + frow) * 72 + fk);
  short8 uu1 = *(const short8*)(UsT + (16 * wave + frow) * 72 + 32 + fk);
  #pragma unroll
  for (int n = 0; n < 4; ++n) {
    f32x4 aA = {}, aD = {};
    aA = __builtin_amdgcn_mfma_f32_16x16x32_bf16(ka0, *(const short8*)(GsT + (16 * n + frow) * 72 + fk), aA, 0, 0, 0);
    aA = __builtin_amdgcn_mfma_f32_16x16x32_bf16(ka1, *(const short8*)(GsT + (16 * n + frow) * 72 + 32 + fk), aA, 0, 0, 0);
    aD = __builtin_amdgcn_mfma_f32_16x16x32_bf16(uu0, *(const short8*)(KTs + (16 * n + frow) * 72 + fk), aD, 0, 0, 0);
    aD = __builtin_amdgcn_mfma_f32_16x16x32_bf16(uu1, *(const short8*)(KTs + (16 * n + frow) * 72 + 32 + fk), aD, 0, 0, 0);
    #pragma unroll
    for (int r = 0; r < 4; ++r) {
      Vs[(16 * wave + cm + r) * 64 + 16 * n + frow] = __float2bfloat16(aA[r]);
      Ks[(16 * wave + cm + r) * 64 + 16 * n + frow] = __float2bfloat16(aD[r]);
    }
  }
  __syncthreads();
  {
    const int r0 = tid >> 2, sc2 = (tid & 3) * 16;
    bf16* acg = AcT + (size_t)ch * 4096;
    bf16* dcg = Dc  + (size_t)ch * 4096;
    *(short8*)(acg + r0 * 64 + sc2)     = *(const short8*)(Vs + r0 * 64 + sc2);
    *(short8*)(acg + r0 * 64 + sc2 + 8) = *(const short8*)(Vs + r0 * 64 + sc2 + 8);
    *(short8*)(dcg + r0 * 64 + sc2)     = *(const short8*)(Ks + r0 * 64 + sc2);
    *(short8*)(dcg + r0 * 64 + sc2 + 8) = *(const short8*)(Ks + r0 * 64 + sc2 + 8);
    *(short8*)(v16 + rowb + (size_t)r0 * ND + sc2)     = *(const short8*)(UsT + r0 * 72 + sc2);
    *(short8*)(v16 + rowb + (size_t)r0 * ND + sc2 + 8) = *(const short8*)(UsT + r0 * 72 + sc2 + 8);
  }
}

// pass 2: minimal serial recurrence: sacc(fp32) += S_bf16 @ AcT^T + Dc, per chunk.
__global__ __launch_bounds__(256) void state_seq(const bf16* __restrict__ AcT,
                                                 const bf16* __restrict__ Dc,
                                                 bf16* __restrict__ Sbuf) {
  __shared__ bf16 ST[64 * 72];
  const int bh = blockIdx.x;
  const int wave = threadIdx.x >> 6, lane = threadIdx.x & 63;
  const int frow = lane & 15, fk = (lane >> 4) * 8, cm = (lane >> 4) * 4;
  for (int i = threadIdx.x; i < 64 * 72 / 2; i += 256) ((unsigned int*)ST)[i] = 0u;
  f32x4 sacc[4] = {};
  const bf16* ac = AcT + (size_t)bh * NCH * 4096;
  const bf16* dc = Dc  + (size_t)bh * NCH * 4096;
  bf16* sb = Sbuf + (size_t)bh * NCH * 4096;
  #pragma unroll
  for (int n = 0; n < 4; ++n)
    #pragma unroll
    for (int r = 0; r < 4; ++r)
      sb[(16 * wave + cm + r) * 64 + 16 * n + frow] = __float2bfloat16(0.f);
  short8 bpre[4][2];
  float dpre[16];
  #pragma unroll
  for (int n = 0; n < 4; ++n) {
    bpre[n][0] = *(const short8*)(ac + (16 * n + frow) * 64 + fk);
    bpre[n][1] = *(const short8*)(ac + (16 * n + frow) * 64 + 32 + fk);
    #pragma unroll
    for (int r = 0; r < 4; ++r)
      dpre[n * 4 + r] = __bfloat162float(dc[(16 * wave + cm + r) * 64 + 16 * n + frow]);
  }
  __syncthreads();
  #pragma unroll 1
  for (int c = 0; c < NCH; ++c) {
    short8 a0 = *(const short8*)(ST + (16 * wave + frow) * 72 + fk);
    short8 a1 = *(const short8*)(ST + (16 * wave + frow) * 72 + 32 + fk);
    short8 bcur[4][2];
    float dcur[16];
    #pragma unroll
    for (int n = 0; n < 4; ++n) {
      bcur[n][0] = bpre[n][0]; bcur[n][1] = bpre[n][1];
      #pragma unroll
      for (int r = 0; r < 4; ++r) dcur[n * 4 + r] = dpre[n * 4 + r];
    }
    if (c + 1 < NCH) {
      const bf16* acn = ac + (size_t)(c + 1) * 4096;
      const bf16* dcn = dc + (size_t)(c + 1) * 4096;
      #pragma unroll
      for (int n = 0; n < 4; ++n) {
        bpre[n][0] = *(const short8*)(acn + (16 * n + frow) * 64 + fk);
        bpre[n][1] = *(const short8*)(acn + (16 * n + frow) * 64 + 32 + fk);
        #pragma unroll
        for (int r = 0; r < 4; ++r)
          dpre[n * 4 + r] = __bfloat162float(dcn[(16 * wave + cm + r) * 64 + 16 * n + frow]);
      }
    }
    #pragma unroll
    for (int n = 0; n < 4; ++n) {
      sacc[n] = __builtin_amdgcn_mfma_f32_16x16x32_bf16(a0, bcur[n][0], sacc[n], 0, 0, 0);
      sacc[n] = __builtin_amdgcn_mfma_f32_16x16x32_bf16(a1, bcur[n][1], sacc[n], 0, 0, 0);
      #pragma unroll
      for (int r = 0; r < 4; ++r) sacc[n][r] += dcur[n * 4 + r];
    }
    __syncthreads();
    #pragma unroll
    for (int n = 0; n < 4; ++n)
      #pragma unroll
      for (int r = 0; r < 4; ++r) {
        const bf16 sv = __float2bfloat16(sacc[n][r]);
        ST[(16 * wave + cm + r) * 72 + 16 * n + frow] = sv;
        if (c + 1 < NCH)
          sb[(size_t)(c + 1) * 4096 + (16 * wave + cm + r) * 64 + 16 * n + frow] = sv;
      }
    __syncthreads();
  }
}

// pass 3: chunk-parallel outputs. O = Q*S_c + tril(QK^T)*U_c, in place over q16.
__global__ __launch_bounds__(256) void chunk_out(bf16* __restrict__ q16,
                                                 const bf16* __restrict__ k16,
                                                 const bf16* __restrict__ v16,
                                                 const bf16* __restrict__ Gneg,
                                                 const bf16* __restrict__ Sbuf) {
  __shared__ bf16 UTs[64 * 72];
  __shared__ bf16 Pt[64 * 72];
  const int ch = blockIdx.x;
  const int c = ch & (NCH - 1), bh = ch >> 5;
  const int h = bh & (NH - 1), b = bh >> 5;
  const int tid = threadIdx.x, wave = tid >> 6, lane = tid & 63;
  const int frow = lane & 15, fk = (lane >> 4) * 8, cm = (lane >> 4) * 4;
  const size_t qkb = ((size_t)b * NT + c * 64) * ND + (size_t)h * 64;
  const bf16* Sb = Sbuf + (size_t)ch * 4096;
  const bf16* Gc = Gneg + (size_t)ch * 4096;
  {
    const int r0 = tid >> 2, sc2 = (tid & 3) * 16;
    *(short8*)(UTs + r0 * 72 + sc2)     = *(const short8*)(v16 + qkb + (size_t)r0 * ND + sc2);
    *(short8*)(UTs + r0 * 72 + sc2 + 8) = *(const short8*)(v16 + qkb + (size_t)r0 * ND + sc2 + 8);
  }
  short8 qa0 = *(const short8*)(q16 + qkb + (size_t)(16 * wave + frow) * ND + fk);
  short8 qa1 = *(const short8*)(q16 + qkb + (size_t)(16 * wave + frow) * ND + 32 + fk);
  f32x4 pacc[4];
  #pragma unroll
  for (int n = 0; n < 4; ++n) {
    f32x4 a = {};
    a = __builtin_amdgcn_mfma_f32_16x16x32_bf16(qa0, *(const short8*)(k16 + qkb + (size_t)(16 * n + frow) * ND + fk), a, 0, 0, 0);
    a = __builtin_amdgcn_mfma_f32_16x16x32_bf16(qa1, *(const short8*)(k16 + qkb + (size_t)(16 * n + frow) * ND + 32 + fk), a, 0, 0, 0);
    pacc[n] = a;
  }
  __syncthreads();
  f32x4 uacc[4];
  #pragma unroll
  for (int n = 0; n < 4; ++n)
    #pragma unroll
    for (int r = 0; r < 4; ++r)
      uacc[n][r] = __bfloat162float(UTs[(16 * wave + cm + r) * 72 + 16 * n + frow]);
  #pragma unroll
  for (int n = 0; n < 4; ++n)
    #pragma unroll
    for (int r = 0; r < 4; ++r) {
      const int mg = 16 * wave + cm + r, ng = 16 * n + frow;
      Pt[mg * 72 + ng] = __float2bfloat16(ng <= mg ? pacc[n][r] : 0.f);
    }
  short8 sa0 = *(const short8*)(Sb + (16 * wave + frow) * 64 + fk);
  short8 sa1 = *(const short8*)(Sb + (16 * wave + frow) * 64 + 32 + fk);
  #pragma unroll
  for (int n = 0; n < 4; ++n) {
    uacc[n] = __builtin_amdgcn_mfma_f32_16x16x32_bf16(sa0, *(const short8*)(Gc + (16 * n + frow) * 64 + fk), uacc[n], 0, 0, 0);
    uacc[n] = __builtin_amdgcn_mfma_f32_16x16x32_bf16(sa1, *(const short8*)(Gc + (16 * n + frow) * 64 + 32 + fk), uacc[n], 0, 0, 0);
  }
  __syncthreads();
  #pragma unroll
  for (int n = 0; n < 4; ++n)
    #pragma unroll
    for (int r = 0; r < 4; ++r)
      UTs[(16 * wave + cm + r) * 72 + 16 * n + frow] = __float2bfloat16(uacc[n][r]);
  __syncthreads();
  short8 pa0 = *(const short8*)(Pt + (16 * wave + frow) * 72 + fk);
  short8 pa1 = *(const short8*)(Pt + (16 * wave + frow) * 72 + 32 + fk);
  #pragma unroll
  for (int n = 0; n < 4; ++n) {
    f32x4 o = {};
    o = __builtin_amdgcn_mfma_f32_16x16x32_bf16(qa0, *(const short8*)(Sb + (16 * n + frow) * 64 + fk), o, 0, 0, 0);
    o = __builtin_amdgcn_mfma_f32_16x16x32_bf16(qa1, *(const short8*)(Sb + (16 * n + frow) * 64 + 32 + fk), o, 0, 0, 0);
    o = __builtin_amdgcn_mfma_f32_16x16x32_bf16(pa0, *(const short8*)(UTs + (16 * n + frow) * 72 + fk), o, 0, 0, 0);
    o = __builtin_amdgcn_mfma_f32_16x16x32_bf16(pa1, *(const short8*)(UTs + (16 * n + frow) * 72 + 32 + fk), o, 0, 0, 0);
    #pragma unroll
    for (int r = 0; r < 4; ++r)
      q16[qkb + (size_t)(16 * wave + cm + r) * ND + 16 * n + frow] = __float2bfloat16(o[r]);
  }
}

// ======================= compact-fallback chunk kernels (round-4 proven) =======================

__global__ __launch_bounds__(128) void chunk_scan_c(const bf16* __restrict__ k16,
                                                    bf16* __restrict__ v16,
                                                    const bf16* __restrict__ betab,
                                                    const void* __restrict__ bb,
                                                    const int* __restrict__ flag,
                                                    bf16* __restrict__ Gneg) {
  __shared__ bf16 Ks[64 * 64];
  __shared__ bf16 Vs[64 * 64];
  __shared__ bf16 Gs[64 * 64];
  __shared__ float Bs[64];
  const int ch = blockIdx.x;
  const int c = ch & (NCH - 1), bh = ch >> 5;
  const int h = bh & (NH - 1), b = bh >> 5;
  const int tid = threadIdx.x;
  const int wave = tid >> 6, lane = tid & 63;
  const size_t rowb = ((size_t)b * NT + c * 64) * ND + (size_t)h * 64;
  const int sr = tid >> 3, sc = (tid & 7) * 8;
  #pragma unroll
  for (int rnd = 0; rnd < 4; ++rnd) {
    const int r = rnd * 16 + sr;
    *(short8*)(Ks + r * 64 + sc) = *(const short8*)(k16 + rowb + (size_t)r * ND + sc);
    *(short8*)(Vs + r * 64 + sc) = *(const short8*)(v16 + rowb + (size_t)r * ND + sc);
  }
  if (tid < 64) {
    const float x = __bfloat162float(betab[((size_t)b * NT + c * 64 + tid) * 128 + h])
                    + loadf(bb, h, *flag);
    Bs[tid] = 1.f / (1.f + expf(-x));
  }
  __syncthreads();
  float S[64];
  #pragma unroll
  for (int i = 0; i < 64; ++i) S[i] = 0.f;
  const bf16* val_src = wave ? Ks : Vs;
  #pragma unroll 1
  for (int t = 0; t < 64; ++t) {
    uint4 ku[8];
    #pragma unroll
    for (int i = 0; i < 8; ++i) ku[i] = ((const uint4*)(Ks + t * 64))[i];
    const float val = __bfloat162float(val_src[t * 64 + lane]);
    const float bt = Bs[t];
    float kvf[64];
    #pragma unroll
    for (int i = 0; i < 8; ++i) {
      kvf[8*i+0] = __uint_as_float(ku[i].x << 16);
      kvf[8*i+1] = __uint_as_float(ku[i].x & 0xffff0000u);
      kvf[8*i+2] = __uint_as_float(ku[i].y << 16);
      kvf[8*i+3] = __uint_as_float(ku[i].y & 0xffff0000u);
      kvf[8*i+4] = __uint_as_float(ku[i].z << 16);
      kvf[8*i+5] = __uint_as_float(ku[i].z & 0xffff0000u);
      kvf[8*i+6] = __uint_as_float(ku[i].w << 16);
      kvf[8*i+7] = __uint_as_float(ku[i].w & 0xffff0000u);
    }
    float p0 = 0, p1 = 0, p2 = 0, p3 = 0;
    #pragma unroll
    for (int i = 0; i < 16; ++i) {
      p0 += kvf[4*i+0] * S[4*i+0];
      p1 += kvf[4*i+1] * S[4*i+1];
      p2 += kvf[4*i+2] * S[4*i+2];
      p3 += kvf[4*i+3] * S[4*i+3];
    }
    const float u = bt * (val - ((p0 + p1) + (p2 + p3)));
    #pragma unroll
    for (int i = 0; i < 16; ++i) {
      S[4*i+0] += kvf[4*i+0] * u;
      S[4*i+1] += kvf[4*i+1] * u;
      S[4*i+2] += kvf[4*i+2] * u;
      S[4*i+3] += kvf[4*i+3] * u;
    }
    if (wave) Gs[t * 64 + lane] = __float2bfloat16(-u);
    else      Vs[t * 64 + lane] = __float2bfloat16(u);
  }
  __syncthreads();
  bf16* gout = Gneg + (size_t)ch * 4096;
  #pragma unroll
  for (int rnd = 0; rnd < 4; ++rnd) {
    const int r = rnd * 16 + sr;
    *(short8*)(v16 + rowb + (size_t)r * ND + sc) = *(const short8*)(Vs + r * 64 + sc);
    *(short8*)(gout + r * 64 + sc)               = *(const short8*)(Gs + r * 64 + sc);
  }
}

__global__ __launch_bounds__(256) void chunk_seq_mono(bf16* q16,
                                                      const bf16* __restrict__ k16,
                                                      const bf16* __restrict__ Ul,
                                                      const bf16* __restrict__ Gneg) {
  __shared__ bf16 ST[64 * 72];
  __shared__ bf16 Ubt[64 * 72];
  __shared__ bf16 Pt[64 * 72];
  __shared__ bf16 KTl[64 * 72];
  const int bh = blockIdx.x, h = bh & (NH - 1), b = bh >> 5;
  const int wave = threadIdx.x >> 6, lane = threadIdx.x & 63;
  const int frow = lane & 15, q4 = lane >> 4, fk = q4 * 8;
  const int cm = q4 * 4;
  for (int i = threadIdx.x; i < 64 * 72 / 2; i += 256) ((unsigned int*)ST)[i] = 0u;
  __syncthreads();
  f32x4 sacc[4] = {};
  #pragma unroll 1
  for (int c = 0; c < NCH; ++c) {
    const bf16* Gc = Gneg + ((size_t)bh * NCH + c) * 4096;
    const size_t qkb = ((size_t)b * NT + c * 64) * ND + (size_t)h * 64;
    {
      short8 r0 = *(const short8*)(k16 + qkb + (size_t)lane * ND + 16 * wave);
      short8 r1 = *(const short8*)(k16 + qkb + (size_t)lane * ND + 16 * wave + 8);
      #pragma unroll
      for (int j = 0; j < 8; ++j) {
        KTl[(16 * wave + j) * 72 + lane]     = ((const bf16*)&r0)[j];
        KTl[(16 * wave + 8 + j) * 72 + lane] = ((const bf16*)&r1)[j];
      }
    }
    short8 ga0 = *(const short8*)(Gc + (16 * wave + frow) * 64 + fk);
    short8 ga1 = *(const short8*)(Gc + (16 * wave + frow) * 64 + 32 + fk);
    #pragma unroll
    for (int n = 0; n < 4; ++n) {
      f32x4 acc;
      #pragma unroll
      for (int r = 0; r < 4; ++r)
        acc[r] = __bfloat162float(Ul[qkb + (size_t)(16 * wave + cm + r) * ND + 16 * n + frow]);
      acc = __builtin_amdgcn_mfma_f32_16x16x32_bf16(ga0, *(const short8*)(ST + (16 * n + frow) * 72 + fk), acc, 0, 0, 0);
      acc = __builtin_amdgcn_mfma_f32_16x16x32_bf16(ga1, *(const short8*)(ST + (16 * n + frow) * 72 + 32 + fk), acc, 0, 0, 0);
      #pragma unroll
      for (int r = 0; r < 4; ++r)
        Ubt[(16 * n + frow) * 72 + 16 * wave + cm + r] = __float2bfloat16(acc[r]);
    }
    __syncthreads();
    short8 qa0 = *(const short8*)(q16 + qkb + (size_t)(16 * wave + frow) * ND + fk);
    short8 qa1 = *(const short8*)(q16 + qkb + (size_t)(16 * wave + frow) * ND + 32 + fk);
    #pragma unroll
    for (int n = 0; n < 4; ++n) {
      f32x4 acc = {};
      acc = __builtin_amdgcn_mfma_f32_16x16x32_bf16(qa0, *(const short8*)(k16 + qkb + (size_t)(16 * n + frow) * ND + fk), acc, 0, 0, 0);
      acc = __builtin_amdgcn_mfma_f32_16x16x32_bf16(qa1, *(const short8*)(k16 + qkb + (size_t)(16 * n + frow) * ND + 32 + fk), acc, 0, 0, 0);
      #pragma unroll
      for (int r = 0; r < 4; ++r) {
        const int mg = 16 * wave + cm + r, ng = 16 * n + frow;
        Pt[mg * 72 + ng] = __float2bfloat16(ng <= mg ? acc[r] : 0.f);
      }
    }
    __syncthreads();
    short8 pa0 = *(const short8*)(Pt + (16 * wave + frow) * 72 + fk);
    short8 pa1 = *(const short8*)(Pt + (16 * wave + frow) * 72 + 32 + fk);
    #pragma unroll
    for (int n = 0; n < 4; ++n) {
      f32x4 acc = {};
      acc = __builtin_amdgcn_mfma_f32_16x16x32_bf16(qa0, *(const short8*)(ST + (16 * n + frow) * 72 + fk), acc, 0, 0, 0);
      acc = __builtin_amdgcn_mfma_f32_16x16x32_bf16(qa1, *(const short8*)(ST + (16 * n + frow) * 72 + 32 + fk), acc, 0, 0, 0);
      acc = __builtin_amdgcn_mfma_f32_16x16x32_bf16(pa0, *(const short8*)(Ubt + (16 * n + frow) * 72 + fk), acc, 0, 0, 0);
      acc = __builtin_amdgcn_mfma_f32_16x16x32_bf16(pa1, *(const short8*)(Ubt + (16 * n + frow) * 72 + 32 + fk), acc, 0, 0, 0);
      #pragma unroll
      for (int r = 0; r < 4; ++r)
        q16[qkb + (size_t)(16 * wave + cm + r) * ND + 16 * n + frow] = __float2bfloat16(acc[r]);
    }
    __syncthreads();
    short8 ua0 = *(const short8*)(Ubt + (16 * wave + frow) * 72 + fk);
    short8 ua1 = *(const short8*)(Ubt + (16 * wave + frow) * 72 + 32 + fk);
    #pragma unroll
    for (int n = 0; n < 4; ++n) {
      sacc[n] = __builtin_amdgcn_mfma_f32_16x16x32_bf16(ua0, *(const short8*)(KTl + (16 * n + frow) * 72 + fk), sacc[n], 0, 0, 0);
      sacc[n] = __builtin_amdgcn_mfma_f32_16x16x32_bf16(ua1, *(const short8*)(KTl + (16 * n + frow) * 72 + 32 + fk), sacc[n], 0, 0, 0);
      #pragma unroll
      for (int r = 0; r < 4; ++r)
        ST[(16 * wave + cm + r) * 72 + 16 * n + frow] = __float2bfloat16(sacc[n][r]);
    }
    __syncthreads();
  }
}

extern "C" void kernel_launch(void* const* d_in, const int* in_sizes, int n_in,
                              void* d_out, int out_size, void* d_ws, size_t ws_size,
                              hipStream_t stream) {
  const void* hs = d_in[0];
  const void* Wq = d_in[1];
  const void* Wk = d_in[2];
  const void* Wv = d_in[3];
  const void* Wb = d_in[4];
  const void* bb = d_in[5];
  const void* Wo = d_in[6];

  char* ws = (char*)d_ws;
  size_t off = 0;
  auto alloc = [&](size_t bytes) {
    void* p = ws + off;
    off += (bytes + 255) & ~(size_t)255;
    return p;
  };
  const size_t szW2 = (size_t)32 * 1024 * 1024;  // WT (26.2 MiB weights) + AcT alias region
  const size_t szM  = (size_t)NM * ND * 2;       // 16 MiB
  const size_t szB2 = (size_t)NM * 256 * 2;      // 2 MiB (beta logits, 256-padded)
  const size_t szB  = (size_t)NM * 128 * 2;      // fallback beta (128-padded)
  const size_t need_fused = 512 + szW2 + 4 * szM + szB2 + szM;   // ~119.6 MB

  if (ws_size >= need_fused) {
    // ---- fused path ----
    int*  flag  = (int*) alloc(256);
    bf16* WT    = (bf16*)alloc(szW2);  // weights [0,26.2Mi); later Gneg [0,16Mi) + AcT [16,32Mi)
    bf16* hs16  = (bf16*)alloc(szM);   // -> Sbuf after fused GEMM
    bf16* q16   = (bf16*)alloc(szM);   // O in place
    bf16* k16   = (bf16*)alloc(szM);
    bf16* v16   = (bf16*)alloc(szM);   // U^T (transposed-in-place)
    bf16* betab = (bf16*)alloc(szB2);
    bf16* Dc    = (bf16*)alloc(szM);
    bf16* Gneg  = WT;                                    // [0,16MiB) dead after fused GEMM
    bf16* AcT   = WT + (size_t)8 * 1024 * 1024;          // [16,32MiB)
    bf16* WoT   = AcT;                                   // reused after state_seq
    bf16* Sbuf  = hs16;

    detect_dtype<<<1, 64, 0, stream>>>((const unsigned short*)hs, flag);
    convert_bf16<<<(NM * ND) / (256 * 8), 256, 0, stream>>>(hs, hs16, (long)NM * ND, flag);

    transpose_qkvb<<<dim3(32, 32, 4), 256, 0, stream>>>(Wq, Wk, Wv, Wb, WT, flag);
    gemm256<<<400, 512, 0, stream>>>(hs16, WT, q16, k16, v16, betab, ND, 25);

    chunk_scan<<<NB * NH * NCH, 256, 0, stream>>>(k16, v16, betab, bb, flag, Gneg, AcT, Dc);
    state_seq<<<NB * NH, 256, 0, stream>>>(AcT, Dc, Sbuf);
    chunk_out<<<NB * NH * NCH, 256, 0, stream>>>(q16, k16, v16, Gneg, Sbuf);

    transpose_cvt<<<dim3(32, 32), 256, 0, stream>>>(Wo, WoT, 2048, 2048, flag);
    gemm_bt<<<dim3(16, 32), 256, 0, stream>>>(q16, WoT, nullptr, nullptr, nullptr, nullptr,
                                              d_out, flag, NM, ND, 0);
  } else {
    // ---- compact fallback (proven ~73 MB footprint) ----
    int*  flag  = (int*) alloc(256);
    bf16* Wt    = (bf16*)alloc((size_t)2048 * 2048 * 2);
    bf16* hs16  = (bf16*)alloc(szM);   // -> Gneg
    bf16* q16   = (bf16*)alloc(szM);
    bf16* k16   = (bf16*)alloc(szM);
    bf16* v16   = (bf16*)alloc(szM);
    bf16* betab = (bf16*)alloc(szB);
    bf16* Gneg  = hs16;

    detect_dtype<<<1, 64, 0, stream>>>((const unsigned short*)hs, flag);
    convert_bf16<<<(NM * ND) / (256 * 8), 256, 0, stream>>>(hs, hs16, (long)NM * ND, flag);

    transpose_cvt<<<dim3(32, 32), 256, 0, stream>>>(Wq, Wt, 2048, 2048, flag);
    gemm_bt<<<dim3(16, 32), 256, 0, stream>>>(hs16, Wt, q16, k16, v16, betab, nullptr, nullptr, NM, ND, 0);
    transpose_cvt<<<dim3(32, 32), 256, 0, stream>>>(Wk, Wt, 2048, 2048, flag);
    gemm_bt<<<dim3(16, 32), 256, 0, stream>>>(hs16, Wt, q16, k16, v16, betab, nullptr, nullptr, NM, ND, 2048);
    transpose_cvt<<<dim3(32, 32), 256, 0, stream>>>(Wv, Wt, 2048, 2048, flag);
    gemm_bt<<<dim3(16, 32), 256, 0, stream>>>(hs16, Wt, q16, k16, v16, betab, nullptr, nullptr, NM, ND, 4096);
    transpose_cvt<<<dim3(2, 32),  256, 0, stream>>>(Wb, Wt, 2048, 32, flag);
    gemm_bt<<<dim3(1, 32), 256, 0, stream>>>(hs16, Wt, q16, k16, v16, betab, nullptr, nullptr, NM, ND, 6144);

    chunk_scan_c<<<NB * NH * NCH, 128, 0, stream>>>(k16, v16, betab, bb, flag, Gneg);
    chunk_seq_mono<<<NB * NH, 256, 0, stream>>>(q16, k16, v16, Gneg);

    transpose_cvt<<<dim3(32, 32), 256, 0, stream>>>(Wo, Wt, 2048, 2048, flag);
    gemm_bt<<<dim3(16, 32), 256, 0, stream>>>(q16, Wt, nullptr, nullptr, nullptr, nullptr,
                                              d_out, flag, NM, ND, 0);
  }
}

// Round 3
// 581.771 us; speedup vs baseline: 1.0118x; 1.0118x over previous
//
#include <hip/hip_runtime.h>
#include <hip/hip_bf16.h>

typedef __hip_bfloat16 bf16;
typedef __attribute__((ext_vector_type(8))) short short8;   // 8 bf16 (4 VGPRs)
typedef __attribute__((ext_vector_type(4))) float f32x4;

#define NB 2
#define NT 2048
#define ND 2048
#define NH 32
#define NM (NB*NT)   // 4096 rows
#define NCH 32       // chunks per (b,h): NT/64

// ---- dtype hedge: inputs may be bf16 (harness-converted) or fp32 (per reference) ----
__global__ void detect_dtype(const unsigned short* __restrict__ hs, int* __restrict__ flag) {
  if (threadIdx.x == 0 && blockIdx.x == 0) {
    int cnt = 0;
    for (int i = 0; i < 2048; i += 2) {
      int e = (hs[i] >> 7) & 0xFF;
      if (e >= 141) ++cnt;
    }
    *flag = (cnt > 64) ? 1 : 0;   // 1 = fp32, 0 = bf16
  }
}

__device__ __forceinline__ float loadf(const void* p, size_t i, int isf32) {
  return isf32 ? ((const float*)p)[i] : __bfloat162float(((const bf16*)p)[i]);
}

__global__ __launch_bounds__(256) void convert_bf16(const void* __restrict__ src,
                                                    bf16* __restrict__ dst,
                                                    long n, const int* __restrict__ flag) {
  const long i0 = ((long)blockIdx.x * 256 + threadIdx.x) * 8;
  if (i0 >= n) return;
  if (*flag) {
    const float* s = (const float*)src;
    #pragma unroll
    for (int j = 0; j < 8; ++j) dst[i0 + j] = __float2bfloat16(s[i0 + j]);
  } else {
    *(short8*)(dst + i0) = *(const short8*)((const bf16*)src + i0);
  }
}

// ---- transpose + convert one matrix: dst[c][r] = bf16(src[r][c]); zero-pad cols ----
__global__ __launch_bounds__(256) void transpose_cvt(const void* __restrict__ src,
                                                     bf16* __restrict__ dst,
                                                     int src_rows, int src_cols,
                                                     const int* __restrict__ flag) {
  __shared__ bf16 tile[64][65];
  const int f = *flag;
  const int tb_r = blockIdx.y * 64, tb_c = blockIdx.x * 64;
  const int tx = threadIdx.x & 63, ty = threadIdx.x >> 6;
  #pragma unroll
  for (int i = 0; i < 64; i += 4) {
    const int cc = tb_c + tx;
    tile[i + ty][tx] = (cc < src_cols)
      ? __float2bfloat16(loadf(src, (size_t)(tb_r + i + ty) * src_cols + cc, f))
      : __float2bfloat16(0.f);
  }
  __syncthreads();
  #pragma unroll
  for (int i = 0; i < 64; i += 4)
    dst[(size_t)(tb_c + i + ty) * src_rows + tb_r + tx] = tile[tx][i + ty];
}

// ---- merged transpose of Wq/Wk/Wv/Wb into WT, z-sliced (beta block padded to 256 rows) ----
__global__ __launch_bounds__(256) void transpose_qkvb(const void* __restrict__ Wq,
                                                      const void* __restrict__ Wk,
                                                      const void* __restrict__ Wv,
                                                      const void* __restrict__ Wb,
                                                      bf16* __restrict__ WT,
                                                      const int* __restrict__ flag) {
  __shared__ bf16 tile[64][65];
  const int z = blockIdx.z;
  if (z == 3 && blockIdx.x >= 4) return;   // Wb^T: 256 padded rows
  const void* src = (z == 0) ? Wq : (z == 1) ? Wk : (z == 2) ? Wv : Wb;
  const int src_cols = (z == 3) ? 32 : 2048;
  bf16* dst = WT + (size_t)z * 2048 * 2048;
  const int f = *flag;
  const int tb_r = blockIdx.y * 64, tb_c = blockIdx.x * 64;
  const int tx = threadIdx.x & 63, ty = threadIdx.x >> 6;
  #pragma unroll
  for (int i = 0; i < 64; i += 4) {
    const int cc = tb_c + tx;
    tile[i + ty][tx] = (cc < src_cols)
      ? __float2bfloat16(loadf(src, (size_t)(tb_r + i + ty) * src_cols + cc, f))
      : __float2bfloat16(0.f);
  }
  __syncthreads();
  #pragma unroll
  for (int i = 0; i < 64; i += 4)
    dst[(size_t)(tb_c + i + ty) * 2048 + tb_r + tx] = tile[tx][i + ty];
}

// async 16B/lane global->LDS (wave-uniform LDS base + lane*16)
__device__ __forceinline__ void gload_lds16(const void* g, void* l) {
  __builtin_amdgcn_global_load_lds((__attribute__((address_space(1))) const void*)g,
                                   (__attribute__((address_space(3))) void*)l,
                                   16, 0, 0);
}

// ------------- legacy GEMM (fallback path only): C = A @ Bt^T -------------
__global__ __launch_bounds__(256) void gemm_bt(const bf16* __restrict__ A,
                                               const bf16* __restrict__ Bt,
                                               bf16* __restrict__ oq, bf16* __restrict__ ok2,
                                               bf16* __restrict__ ov, bf16* __restrict__ ob,
                                               void* __restrict__ outv,
                                               const int* __restrict__ outflag,
                                               int M, int K, int n_base) {
  __shared__ bf16 As[128 * 32];
  __shared__ bf16 Bs[128 * 32];
  const int tid = threadIdx.x;
  const int wave = tid >> 6, lane = tid & 63;
  const int m0 = blockIdx.y * 128, n0 = blockIdx.x * 128;
  const int wm = (wave >> 1) * 64, wn = (wave & 1) * 64;
  const int srow = lane >> 2, scol = (lane & 3) * 8;
  const int frow = lane & 15, fk = (lane >> 4) * 8;
  f32x4 acc[4][4] = {};

  for (int kb = 0; kb < K; kb += 32) {
    __syncthreads();
    #pragma unroll
    for (int j = 0; j < 2; ++j) {
      const int rbase = wave * 32 + j * 16;
      gload_lds16(A  + (size_t)(m0 + rbase + srow) * K + kb + scol, As + rbase * 32);
      gload_lds16(Bt + (size_t)(n0 + rbase + srow) * K + kb + scol, Bs + rbase * 32);
    }
    __syncthreads();
    short8 af[4], bfr[4];
    #pragma unroll
    for (int i = 0; i < 4; ++i)
      af[i] = *(const short8*)(As + (wm + i * 16 + frow) * 32 + fk);
    #pragma unroll
    for (int i = 0; i < 4; ++i)
      bfr[i] = *(const short8*)(Bs + (wn + i * 16 + frow) * 32 + fk);
    #pragma unroll
    for (int mi = 0; mi < 4; ++mi)
      #pragma unroll
      for (int ni = 0; ni < 4; ++ni)
        acc[mi][ni] = __builtin_amdgcn_mfma_f32_16x16x32_bf16(af[mi], bfr[ni], acc[mi][ni], 0, 0, 0);
  }

  const int crow = (lane >> 4) * 4, ccol = lane & 15;
  const int gn0 = n_base + n0;
  if (outflag) {
    const int f = *outflag;
    #pragma unroll
    for (int mi = 0; mi < 4; ++mi)
      #pragma unroll
      for (int ni = 0; ni < 4; ++ni)
        #pragma unroll
        for (int r = 0; r < 4; ++r) {
          const size_t idx = (size_t)(m0 + wm + mi * 16 + crow + r) * 2048 + gn0 + wn + ni * 16 + ccol;
          const float val = acc[mi][ni][r];
          if (f == 1) ((float*)outv)[idx] = val;
          else        ((bf16*)outv)[idx] = __float2bfloat16(val);
        }
  } else {
    const int seg = gn0 >> 11;
    bf16* o = (seg == 0) ? oq : (seg == 1) ? ok2 : (seg == 2) ? ov : ob;
    const int stride = (seg < 3) ? 2048 : 128;
    const int cb = (gn0 & 2047) + wn;
    if (seg <= 1) {
      #pragma unroll
      for (int mi = 0; mi < 4; ++mi)
        #pragma unroll
        for (int r = 0; r < 4; ++r) {
          float s = acc[mi][0][r] * acc[mi][0][r] + acc[mi][1][r] * acc[mi][1][r]
                  + acc[mi][2][r] * acc[mi][2][r] + acc[mi][3][r] * acc[mi][3][r];
          s += __shfl_xor(s, 1, 64); s += __shfl_xor(s, 2, 64);
          s += __shfl_xor(s, 4, 64); s += __shfl_xor(s, 8, 64);
          const float inv = rsqrtf(s + 1e-6f);
          #pragma unroll
          for (int ni = 0; ni < 4; ++ni) acc[mi][ni][r] *= inv;
        }
    }
    #pragma unroll
    for (int mi = 0; mi < 4; ++mi)
      #pragma unroll
      for (int ni = 0; ni < 4; ++ni)
        #pragma unroll
        for (int r = 0; r < 4; ++r)
          o[(size_t)(m0 + wm + mi * 16 + crow + r) * stride + cb + ni * 16 + ccol] =
            __float2bfloat16(acc[mi][ni][r]);
  }
}

// ============ 256x256 8-phase GEMM v2: 3-bit LDS swizzle + balanced phases ============
// C = A[M][K] @ Bt[N][K]^T. 8 waves (2M x 4N), BK=64, 128 KiB LDS double-buffer.
// Swizzle (both-sides involution): phys_byte = logical_byte ^ ((row&7)<<4) within a
// 128-byte row — spreads the 16-rows-same-column fragment read across 8 16B bank slots.
// Phases: p0 reads A-pair0 + ALL B (12 ds) then MFMA pair0 x ni0-3; p1-3 read one A-pair
// (4 ds) each. Staging skew: B0(t+1)@p0, B1(t+1)@p1 -> parity^1; A(t+2)@boundary (after
// p3-close barrier, provably after all parity reads). Steady-state vmcnt(4) at boundary
// drains exactly A(t+1)+B(t+1); final boundary vmcnt(0).

#define MFMA_PAIR(P)                                                             \
  _Pragma("unroll") for (int q2 = 0; q2 < 2; ++q2)                               \
    _Pragma("unroll") for (int ni2 = 0; ni2 < 4; ++ni2) {                        \
      acc[(P) * 2 + q2][ni2] = __builtin_amdgcn_mfma_f32_16x16x32_bf16(          \
          aF[q2][0], bF[ni2][0], acc[(P) * 2 + q2][ni2], 0, 0, 0);               \
      acc[(P) * 2 + q2][ni2] = __builtin_amdgcn_mfma_f32_16x16x32_bf16(          \
          aF[q2][1], bF[ni2][1], acc[(P) * 2 + q2][ni2], 0, 0, 0);               \
    }

#define READ_A(P)                                                                \
  _Pragma("unroll") for (int q2 = 0; q2 < 2; ++q2)                               \
    _Pragma("unroll") for (int kk = 0; kk < 2; ++kk)                             \
      aF[q2][kk] = *(const short8*)(lA + (((P) * 2 + q2) * 16 + frow) * 128      \
                                       + ((kk * 64 + fq * 16) ^ fswz));

#define READ_B_ALL()                                                             \
  _Pragma("unroll") for (int ni2 = 0; ni2 < 4; ++ni2)                            \
    _Pragma("unroll") for (int kk = 0; kk < 2; ++kk)                             \
      bF[ni2][kk] = *(const short8*)(lB + (brow0 + ni2 * 16 + frow) * 128        \
                                        + ((kk * 64 + fq * 16) ^ fswz));

#define PH_OPEN() do { __builtin_amdgcn_s_barrier();                             \
  asm volatile("s_waitcnt lgkmcnt(0)" ::: "memory");                             \
  __builtin_amdgcn_sched_barrier(0);                                             \
  __builtin_amdgcn_s_setprio(1); } while (0)

#define PH_CLOSE() do { __builtin_amdgcn_s_setprio(0);                           \
  __builtin_amdgcn_s_barrier(); } while (0)

__global__ __launch_bounds__(512, 2) void gemm256(const bf16* __restrict__ A,
                                                  const bf16* __restrict__ Bt,
                                                  bf16* __restrict__ oq, bf16* __restrict__ ok2,
                                                  bf16* __restrict__ ov, bf16* __restrict__ ob,
                                                  void* __restrict__ outv,
                                                  const int* __restrict__ outflag,
                                                  int K, int ntn) {
  __shared__ bf16 LA[2][2][8192];   // [parity][half(128 rows)][128*64]
  __shared__ bf16 LB[2][2][8192];
  const int tid = threadIdx.x;
  const int wave = tid >> 6, lane = tid & 63;
  const int wm = wave >> 2, wn = wave & 3;
  const int frow = lane & 15, fq = lane >> 4;
  // bijective XCD swizzle (gridDim.x % 8 == 0 by construction)
  const int cpx = (int)gridDim.x >> 3;
  const int wg = ((int)blockIdx.x & 7) * cpx + ((int)blockIdx.x >> 3);
  const int mtile = wg / ntn, ntile = wg % ntn;
  const int m0 = mtile * 256, n0 = ntile * 256;
  const int NTK = K >> 6;
  // 3-bit read swizzle: byte ^= (row&7)<<4 ; row&7 == frow&7 (16-row frag bases are 0 mod 8)
  const int fswz = (frow & 7) << 4;
  // staging: linear LDS dest (wave*1024 + j*8192 + lane*16); inverse-swizzled global source
  int srow[2], scolb[2];
  #pragma unroll
  for (int j = 0; j < 2; ++j) {
    const int q = wave * 1024 + j * 8192 + lane * 16;
    const int qs = q ^ (((q >> 7) & 7) << 4);
    srow[j]  = qs >> 7;          // row within the 128-row half
    scolb[j] = (qs & 127) >> 1;  // element col within 64
  }
  const int lofs = wave * 1024;

  f32x4 acc[8][4] = {};

  auto STAGE = [&](const bf16* __restrict__ G, int row0, int kcol, bf16* lhalf) {
    #pragma unroll
    for (int j = 0; j < 2; ++j)
      gload_lds16(G + (size_t)(row0 + srow[j]) * K + kcol + scolb[j],
                  (char*)lhalf + lofs + j * 8192);
  };

  // prologue: tile0 all 4 halves + tile1 A halves; leave tile1 A in flight
  STAGE(A,  m0,       0,  LA[0][0]);
  STAGE(A,  m0 + 128, 0,  LA[0][1]);
  STAGE(Bt, n0,       0,  LB[0][0]);
  STAGE(Bt, n0 + 128, 0,  LB[0][1]);
  STAGE(A,  m0,       64, LA[1][0]);
  STAGE(A,  m0 + 128, 64, LA[1][1]);
  asm volatile("s_waitcnt vmcnt(4)" ::: "memory");
  __builtin_amdgcn_s_barrier();

  const int brow0 = (wn & 1) * 64;
  #pragma unroll 1
  for (int t = 0; t < NTK; ++t) {
    const int par = t & 1;
    const char* lA = (const char*)LA[par][wm];
    const char* lB = (const char*)LB[par][wn >> 1];
    short8 aF[2][2], bF[4][2];
    // ---- phase 0: A pair0 + all B (12 ds); stage (t+1):B0 -> parity^1 ----
    READ_A(0)
    READ_B_ALL()
    if (t + 1 < NTK) STAGE(Bt, n0, (t + 1) * 64, LB[par ^ 1][0]);
    PH_OPEN();
    MFMA_PAIR(0)
    PH_CLOSE();
    // ---- phase 1: A pair1; stage (t+1):B1 -> parity^1 ----
    READ_A(1)
    if (t + 1 < NTK) STAGE(Bt, n0 + 128, (t + 1) * 64, LB[par ^ 1][1]);
    PH_OPEN();
    MFMA_PAIR(1)
    PH_CLOSE();
    // ---- phase 2: A pair2 ----
    READ_A(2)
    PH_OPEN();
    MFMA_PAIR(2)
    PH_CLOSE();
    // ---- phase 3: A pair3; boundary: stage A(t+2) -> same parity (all reads done) ----
    READ_A(3)
    PH_OPEN();
    MFMA_PAIR(3)
    __builtin_amdgcn_s_setprio(0);
    __builtin_amdgcn_s_barrier();   // p3 close: all waves' LA[par] reads complete
    if (t + 1 < NTK) {
      if (t + 2 < NTK) {
        STAGE(A, m0,       (t + 2) * 64, LA[par][0]);
        STAGE(A, m0 + 128, (t + 2) * 64, LA[par][1]);
      }
      if (t == NTK - 2) asm volatile("s_waitcnt vmcnt(0)" ::: "memory");
      else              asm volatile("s_waitcnt vmcnt(4)" ::: "memory");
      __builtin_amdgcn_s_barrier();  // boundary: next tile's operands resident
    }
  }

  // epilogue
  const int crow = fq * 4, ccol = frow;
  const int rowb = m0 + wm * 128;
  if (outv) {
    const int f = *outflag;
    const int cb = n0 + wn * 64;
    #pragma unroll
    for (int mi = 0; mi < 8; ++mi)
      #pragma unroll
      for (int ni = 0; ni < 4; ++ni)
        #pragma unroll
        for (int r = 0; r < 4; ++r) {
          const size_t idx = (size_t)(rowb + mi * 16 + crow + r) * 2048 + cb + ni * 16 + ccol;
          const float val = acc[mi][ni][r];
          if (f == 1) ((float*)outv)[idx] = val;
          else        ((bf16*)outv)[idx] = __float2bfloat16(val);
        }
    return;
  }
  // routed epilogue: seg 0/1 l2norm per 64-col head, 2 plain, 3 beta (stride 256)
  const int gn0w = n0 + wn * 64;
  const int seg = gn0w >> 11;
  bf16* o = (seg == 0) ? oq : (seg == 1) ? ok2 : (seg == 2) ? ov : ob;
  const int stride = (seg < 3) ? 2048 : 256;
  const int cb = (seg < 3) ? (gn0w & 2047) : (gn0w - 6144);
  if (seg <= 1) {
    #pragma unroll
    for (int mi = 0; mi < 8; ++mi)
      #pragma unroll
      for (int r = 0; r < 4; ++r) {
        float s = acc[mi][0][r] * acc[mi][0][r] + acc[mi][1][r] * acc[mi][1][r]
                + acc[mi][2][r] * acc[mi][2][r] + acc[mi][3][r] * acc[mi][3][r];
        s += __shfl_xor(s, 1, 64); s += __shfl_xor(s, 2, 64);
        s += __shfl_xor(s, 4, 64); s += __shfl_xor(s, 8, 64);
        const float inv = rsqrtf(s + 1e-6f);
        #pragma unroll
        for (int ni = 0; ni < 4; ++ni) acc[mi][ni][r] *= inv;
      }
  }
  #pragma unroll
  for (int mi = 0; mi < 8; ++mi)
    #pragma unroll
    for (int ni = 0; ni < 4; ++ni)
      #pragma unroll
      for (int r = 0; r < 4; ++r)
        o[(size_t)(rowb + mi * 16 + crow + r) * stride + cb + ni * 16 + ccol] =
          __float2bfloat16(acc[mi][ni][r]);
}

// ======================= fused-path chunk kernels =======================

template<int TB>
__device__ __forceinline__ void scan16(const float* __restrict__ Af,
                                       const bf16* __restrict__ vsrc,
                                       const float* __restrict__ Bsc,
                                       float (&u)[64], const int lane, const int wave,
                                       const float sgn,
                                       bf16* __restrict__ outT,
                                       bf16* __restrict__ gout) {
  constexpr int JM = (TB + 1) * 16;
  #pragma unroll
  for (int tt = 0; tt < 16; ++tt) {
    const int t = TB * 16 + tt;
    float pr0 = 0.f, pr1 = 0.f, pr2 = 0.f, pr3 = 0.f;
    #pragma unroll
    for (int i = 0; i < JM; i += 4) {
      const f32x4 a = *(const f32x4*)(Af + t * 64 + i);   // wave-uniform row read
      pr0 = __builtin_fmaf(a[0], u[i + 0], pr0);
      pr1 = __builtin_fmaf(a[1], u[i + 1], pr1);
      pr2 = __builtin_fmaf(a[2], u[i + 2], pr2);
      pr3 = __builtin_fmaf(a[3], u[i + 3], pr3);
    }
    const float ut = Bsc[t] * __bfloat162float(vsrc[t * 72 + lane])
                   - ((pr0 + pr1) + (pr2 + pr3));
    u[t] = ut;
    const bf16 sv = __float2bfloat16(sgn * ut);
    outT[lane * 72 + t] = sv;
    if (wave) gout[t * 64 + lane] = sv;
  }
}

// pass 1: A = beta*tril(K K^T) via MFMA (fp32 LDS), then two register forward substitutions.
__global__ __launch_bounds__(256) void chunk_scan(const bf16* __restrict__ k16,
                                                  bf16* __restrict__ v16,
                                                  const bf16* __restrict__ betab,
                                                  const void* __restrict__ bb,
                                                  const int* __restrict__ flag,
                                                  bf16* __restrict__ Gneg,
                                                  bf16* __restrict__ AcT,
                                                  bf16* __restrict__ Dc) {
  __shared__ bf16 Ks[64 * 72];
  __shared__ bf16 Vs[64 * 72];
  __shared__ bf16 GsT[64 * 72];
  __shared__ bf16 UsT[64 * 72];
  __shared__ float Af[64 * 64];
  __shared__ float Bsc[64];
  bf16* const KTs = (bf16*)Af;
  const int ch = blockIdx.x;
  const int c = ch & (NCH - 1), bh = ch >> 5;
  const int h = bh & (NH - 1), b = bh >> 5;
  const int tid = threadIdx.x, wave = tid >> 6, lane = tid & 63;
  const size_t rowb = ((size_t)b * NT + c * 64) * ND + (size_t)h * 64;

  short8 ktA0, ktB0, ktA1, ktB1;
  if (wave >= 2) {
    const int d0a = (wave - 2) * 16, d0b = d0a + 32;
    ktA0 = *(const short8*)(k16 + rowb + (size_t)lane * ND + d0a);
    ktB0 = *(const short8*)(k16 + rowb + (size_t)lane * ND + d0a + 8);
    ktA1 = *(const short8*)(k16 + rowb + (size_t)lane * ND + d0b);
    ktB1 = *(const short8*)(k16 + rowb + (size_t)lane * ND + d0b + 8);
  }
  {
    const int r0 = tid >> 3, sc = (tid & 7) * 8;
    #pragma unroll
    for (int rnd = 0; rnd < 2; ++rnd) {
      const int r = rnd * 32 + r0;
      *(short8*)(Ks + r * 72 + sc) = *(const short8*)(k16 + rowb + (size_t)r * ND + sc);
      *(short8*)(Vs + r * 72 + sc) = *(const short8*)(v16 + rowb + (size_t)r * ND + sc);
    }
  }
  if (tid < 64) {
    const float x = __bfloat162float(betab[((size_t)b * NT + c * 64 + tid) * 256 + h])
                    + loadf(bb, h, *flag);
    Bsc[tid] = 1.f / (1.f + expf(-x));
  }
  __syncthreads();

  const int frow = lane & 15, fk = (lane >> 4) * 8, cm = (lane >> 4) * 4;
  {
    short8 ma0 = *(const short8*)(Ks + (16 * wave + frow) * 72 + fk);
    short8 ma1 = *(const short8*)(Ks + (16 * wave + frow) * 72 + 32 + fk);
    #pragma unroll
    for (int n = 0; n < 4; ++n) {
      f32x4 m = {};
      m = __builtin_amdgcn_mfma_f32_16x16x32_bf16(ma0, *(const short8*)(Ks + (16 * n + frow) * 72 + fk), m, 0, 0, 0);
      m = __builtin_amdgcn_mfma_f32_16x16x32_bf16(ma1, *(const short8*)(Ks + (16 * n + frow) * 72 + 32 + fk), m, 0, 0, 0);
      #pragma unroll
      for (int r = 0; r < 4; ++r) {
        const int t = 16 * wave + cm + r, s = 16 * n + frow;
        Af[t * 64 + s] = (s < t) ? Bsc[t] * m[r] : 0.f;
      }
    }
  }
  __syncthreads();

  if (wave < 2) {
    float u[64];
    #pragma unroll
    for (int i = 0; i < 64; ++i) u[i] = 0.f;
    const bf16* vsrc = wave ? Ks : Vs;
    bf16* outT = wave ? GsT : UsT;
    bf16* gout = Gneg + (size_t)ch * 4096;
    const float sgn = wave ? -1.f : 1.f;
    scan16<0>(Af, vsrc, Bsc, u, lane, wave, sgn, outT, gout);
    scan16<1>(Af, vsrc, Bsc, u, lane, wave, sgn, outT, gout);
    scan16<2>(Af, vsrc, Bsc, u, lane, wave, sgn, outT, gout);
    scan16<3>(Af, vsrc, Bsc, u, lane, wave, sgn, outT, gout);
  }
  __syncthreads();

  if (wave >= 2) {
    const int d0a = (wave - 2) * 16, d0b = d0a + 32;
    #pragma unroll
    for (int j = 0; j < 8; ++j) {
      KTs[(d0a + j) * 72 + lane]     = ((const bf16*)&ktA0)[j];
      KTs[(d0a + 8 + j) * 72 + lane] = ((const bf16*)&ktB0)[j];
      KTs[(d0b + j) * 72 + lane]     = ((const bf16*)&ktA1)[j];
      KTs[(d0b + 8 + j) * 72 + lane] = ((const bf16*)&ktB1)[j];
    }
  }
  __syncthreads();

  short8 ka0 = *(const short8*)(KTs + (16 * wave + frow) * 72 + fk);
  short8 ka1 = *(const short8*)(KTs + (16 * wave + frow) * 72 + 32 + fk);
  short8 uu0 = *(const short8*)(UsT + (16 * wave + frow) * 72 + fk);
  short8 uu1 = *(const short8*)(UsT + (16 * wave + frow) * 72 + 32 + fk);
  #pragma unroll
  for (int n = 0; n < 4; ++n) {
    f32x4 aA = {}, aD = {};
    aA = __builtin_amdgcn_mfma_f32_16x16x32_bf16(ka0, *(const short8*)(GsT + (16 * n + frow) * 72 + fk), aA, 0, 0, 0);
    aA = __builtin_amdgcn_mfma_f32_16x16x32_bf16(ka1, *(const short8*)(GsT + (16 * n + frow) * 72 + 32 + fk), aA, 0, 0, 0);
    aD = __builtin_amdgcn_mfma_f32_16x16x32_bf16(uu0, *(const short8*)(KTs + (16 * n + frow) * 72 + fk), aD, 0, 0, 0);
    aD = __builtin_amdgcn_mfma_f32_16x16x32_bf16(uu1, *(const short8*)(KTs + (16 * n + frow) * 72 + 32 + fk), aD, 0, 0, 0);
    #pragma unroll
    for (int r = 0; r < 4; ++r) {
      Vs[(16 * wave + cm + r) * 64 + 16 * n + frow] = __float2bfloat16(aA[r]);
      Ks[(16 * wave + cm + r) * 64 + 16 * n + frow] = __float2bfloat16(aD[r]);
    }
  }
  __syncthreads();
  {
    const int r0 = tid >> 2, sc2 = (tid & 3) * 16;
    bf16* acg = AcT + (size_t)ch * 4096;
    bf16* dcg = Dc  + (size_t)ch * 4096;
    *(short8*)(acg + r0 * 64 + sc2)     = *(const short8*)(Vs + r0 * 64 + sc2);
    *(short8*)(acg + r0 * 64 + sc2 + 8) = *(const short8*)(Vs + r0 * 64 + sc2 + 8);
    *(short8*)(dcg + r0 * 64 + sc2)     = *(const short8*)(Ks + r0 * 64 + sc2);
    *(short8*)(dcg + r0 * 64 + sc2 + 8) = *(const short8*)(Ks + r0 * 64 + sc2 + 8);
    *(short8*)(v16 + rowb + (size_t)r0 * ND + sc2)     = *(const short8*)(UsT + r0 * 72 + sc2);
    *(short8*)(v16 + rowb + (size_t)r0 * ND + sc2 + 8) = *(const short8*)(UsT + r0 * 72 + sc2 + 8);
  }
}

// pass 2: minimal serial recurrence: sacc(fp32) += S_bf16 @ AcT^T + Dc, per chunk.
__global__ __launch_bounds__(256) void state_seq(const bf16* __restrict__ AcT,
                                                 const bf16* __restrict__ Dc,
                                                 bf16* __restrict__ Sbuf) {
  __shared__ bf16 ST[64 * 72];
  const int bh = blockIdx.x;
  const int wave = threadIdx.x >> 6, lane = threadIdx.x & 63;
  const int frow = lane & 15, fk = (lane >> 4) * 8, cm = (lane >> 4) * 4;
  for (int i = threadIdx.x; i < 64 * 72 / 2; i += 256) ((unsigned int*)ST)[i] = 0u;
  f32x4 sacc[4] = {};
  const bf16* ac = AcT + (size_t)bh * NCH * 4096;
  const bf16* dc = Dc  + (size_t)bh * NCH * 4096;
  bf16* sb = Sbuf + (size_t)bh * NCH * 4096;
  #pragma unroll
  for (int n = 0; n < 4; ++n)
    #pragma unroll
    for (int r = 0; r < 4; ++r)
      sb[(16 * wave + cm + r) * 64 + 16 * n + frow] = __float2bfloat16(0.f);
  short8 bpre[4][2];
  float dpre[16];
  #pragma unroll
  for (int n = 0; n < 4; ++n) {
    bpre[n][0] = *(const short8*)(ac + (16 * n + frow) * 64 + fk);
    bpre[n][1] = *(const short8*)(ac + (16 * n + frow) * 64 + 32 + fk);
    #pragma unroll
    for (int r = 0; r < 4; ++r)
      dpre[n * 4 + r] = __bfloat162float(dc[(16 * wave + cm + r) * 64 + 16 * n + frow]);
  }
  __syncthreads();
  #pragma unroll 1
  for (int c = 0; c < NCH; ++c) {
    short8 a0 = *(const short8*)(ST + (16 * wave + frow) * 72 + fk);
    short8 a1 = *(const short8*)(ST + (16 * wave + frow) * 72 + 32 + fk);
    short8 bcur[4][2];
    float dcur[16];
    #pragma unroll
    for (int n = 0; n < 4; ++n) {
      bcur[n][0] = bpre[n][0]; bcur[n][1] = bpre[n][1];
      #pragma unroll
      for (int r = 0; r < 4; ++r) dcur[n * 4 + r] = dpre[n * 4 + r];
    }
    if (c + 1 < NCH) {
      const bf16* acn = ac + (size_t)(c + 1) * 4096;
      const bf16* dcn = dc + (size_t)(c + 1) * 4096;
      #pragma unroll
      for (int n = 0; n < 4; ++n) {
        bpre[n][0] = *(const short8*)(acn + (16 * n + frow) * 64 + fk);
        bpre[n][1] = *(const short8*)(acn + (16 * n + frow) * 64 + 32 + fk);
        #pragma unroll
        for (int r = 0; r < 4; ++r)
          dpre[n * 4 + r] = __bfloat162float(dcn[(16 * wave + cm + r) * 64 + 16 * n + frow]);
      }
    }
    #pragma unroll
    for (int n = 0; n < 4; ++n) {
      sacc[n] = __builtin_amdgcn_mfma_f32_16x16x32_bf16(a0, bcur[n][0], sacc[n], 0, 0, 0);
      sacc[n] = __builtin_amdgcn_mfma_f32_16x16x32_bf16(a1, bcur[n][1], sacc[n], 0, 0, 0);
      #pragma unroll
      for (int r = 0; r < 4; ++r) sacc[n][r] += dcur[n * 4 + r];
    }
    __syncthreads();
    #pragma unroll
    for (int n = 0; n < 4; ++n)
      #pragma unroll
      for (int r = 0; r < 4; ++r) {
        const bf16 sv = __float2bfloat16(sacc[n][r]);
        ST[(16 * wave + cm + r) * 72 + 16 * n + frow] = sv;
        if (c + 1 < NCH)
          sb[(size_t)(c + 1) * 4096 + (16 * wave + cm + r) * 64 + 16 * n + frow] = sv;
      }
    __syncthreads();
  }
}

// pass 3: chunk-parallel outputs. O = Q*S_c + tril(QK^T)*U_c, in place over q16.
__global__ __launch_bounds__(256) void chunk_out(bf16* __restrict__ q16,
                                                 const bf16* __restrict__ k16,
                                                 const bf16* __restrict__ v16,
                                                 const bf16* __restrict__ Gneg,
                                                 const bf16* __restrict__ Sbuf) {
  __shared__ bf16 UTs[64 * 72];
  __shared__ bf16 Pt[64 * 72];
  const int ch = blockIdx.x;
  const int c = ch & (NCH - 1), bh = ch >> 5;
  const int h = bh & (NH - 1), b = bh >> 5;
  const int tid = threadIdx.x, wave = tid >> 6, lane = tid & 63;
  const int frow = lane & 15, fk = (lane >> 4) * 8, cm = (lane >> 4) * 4;
  const size_t qkb = ((size_t)b * NT + c * 64) * ND + (size_t)h * 64;
  const bf16* Sb = Sbuf + (size_t)ch * 4096;
  const bf16* Gc = Gneg + (size_t)ch * 4096;
  {
    const int r0 = tid >> 2, sc2 = (tid & 3) * 16;
    *(short8*)(UTs + r0 * 72 + sc2)     = *(const short8*)(v16 + qkb + (size_t)r0 * ND + sc2);
    *(short8*)(UTs + r0 * 72 + sc2 + 8) = *(const short8*)(v16 + qkb + (size_t)r0 * ND + sc2 + 8);
  }
  short8 qa0 = *(const short8*)(q16 + qkb + (size_t)(16 * wave + frow) * ND + fk);
  short8 qa1 = *(const short8*)(q16 + qkb + (size_t)(16 * wave + frow) * ND + 32 + fk);
  f32x4 pacc[4];
  #pragma unroll
  for (int n = 0; n < 4; ++n) {
    f32x4 a = {};
    a = __builtin_amdgcn_mfma_f32_16x16x32_bf16(qa0, *(const short8*)(k16 + qkb + (size_t)(16 * n + frow) * ND + fk), a, 0, 0, 0);
    a = __builtin_amdgcn_mfma_f32_16x16x32_bf16(qa1, *(const short8*)(k16 + qkb + (size_t)(16 * n + frow) * ND + 32 + fk), a, 0, 0, 0);
    pacc[n] = a;
  }
  __syncthreads();
  f32x4 uacc[4];
  #pragma unroll
  for (int n = 0; n < 4; ++n)
    #pragma unroll
    for (int r = 0; r < 4; ++r)
      uacc[n][r] = __bfloat162float(UTs[(16 * wave + cm + r) * 72 + 16 * n + frow]);
  #pragma unroll
  for (int n = 0; n < 4; ++n)
    #pragma unroll
    for (int r = 0; r < 4; ++r) {
      const int mg = 16 * wave + cm + r, ng = 16 * n + frow;
      Pt[mg * 72 + ng] = __float2bfloat16(ng <= mg ? pacc[n][r] : 0.f);
    }
  short8 sa0 = *(const short8*)(Sb + (16 * wave + frow) * 64 + fk);
  short8 sa1 = *(const short8*)(Sb + (16 * wave + frow) * 64 + 32 + fk);
  #pragma unroll
  for (int n = 0; n < 4; ++n) {
    uacc[n] = __builtin_amdgcn_mfma_f32_16x16x32_bf16(sa0, *(const short8*)(Gc + (16 * n + frow) * 64 + fk), uacc[n], 0, 0, 0);
    uacc[n] = __builtin_amdgcn_mfma_f32_16x16x32_bf16(sa1, *(const short8*)(Gc + (16 * n + frow) * 64 + 32 + fk), uacc[n], 0, 0, 0);
  }
  __syncthreads();
  #pragma unroll
  for (int n = 0; n < 4; ++n)
    #pragma unroll
    for (int r = 0; r < 4; ++r)
      UTs[(16 * wave + cm + r) * 72 + 16 * n + frow] = __float2bfloat16(uacc[n][r]);
  __syncthreads();
  short8 pa0 = *(const short8*)(Pt + (16 * wave + frow) * 72 + fk);
  short8 pa1 = *(const short8*)(Pt + (16 * wave + frow) * 72 + 32 + fk);
  #pragma unroll
  for (int n = 0; n < 4; ++n) {
    f32x4 o = {};
    o = __builtin_amdgcn_mfma_f32_16x16x32_bf16(qa0, *(const short8*)(Sb + (16 * n + frow) * 64 + fk), o, 0, 0, 0);
    o = __builtin_amdgcn_mfma_f32_16x16x32_bf16(qa1, *(const short8*)(Sb + (16 * n + frow) * 64 + 32 + fk), o, 0, 0, 0);
    o = __builtin_amdgcn_mfma_f32_16x16x32_bf16(pa0, *(const short8*)(UTs + (16 * n + frow) * 72 + fk), o, 0, 0, 0);
    o = __builtin_amdgcn_mfma_f32_16x16x32_bf16(pa1, *(const short8*)(UTs + (16 * n + frow) * 72 + 32 + fk), o, 0, 0, 0);
    #pragma unroll
    for (int r = 0; r < 4; ++r)
      q16[qkb + (size_t)(16 * wave + cm + r) * ND + 16 * n + frow] = __float2bfloat16(o[r]);
  }
}

// ======================= compact-fallback chunk kernels (round-4 proven) =======================

__global__ __launch_bounds__(128) void chunk_scan_c(const bf16* __restrict__ k16,
                                                    bf16* __restrict__ v16,
                                                    const bf16* __restrict__ betab,
                                                    const void* __restrict__ bb,
                                                    const int* __restrict__ flag,
                                                    bf16* __restrict__ Gneg) {
  __shared__ bf16 Ks[64 * 64];
  __shared__ bf16 Vs[64 * 64];
  __shared__ bf16 Gs[64 * 64];
  __shared__ float Bs[64];
  const int ch = blockIdx.x;
  const int c = ch & (NCH - 1), bh = ch >> 5;
  const int h = bh & (NH - 1), b = bh >> 5;
  const int tid = threadIdx.x;
  const int wave = tid >> 6, lane = tid & 63;
  const size_t rowb = ((size_t)b * NT + c * 64) * ND + (size_t)h * 64;
  const int sr = tid >> 3, sc = (tid & 7) * 8;
  #pragma unroll
  for (int rnd = 0; rnd < 4; ++rnd) {
    const int r = rnd * 16 + sr;
    *(short8*)(Ks + r * 64 + sc) = *(const short8*)(k16 + rowb + (size_t)r * ND + sc);
    *(short8*)(Vs + r * 64 + sc) = *(const short8*)(v16 + rowb + (size_t)r * ND + sc);
  }
  if (tid < 64) {
    const float x = __bfloat162float(betab[((size_t)b * NT + c * 64 + tid) * 128 + h])
                    + loadf(bb, h, *flag);
    Bs[tid] = 1.f / (1.f + expf(-x));
  }
  __syncthreads();
  float S[64];
  #pragma unroll
  for (int i = 0; i < 64; ++i) S[i] = 0.f;
  const bf16* val_src = wave ? Ks : Vs;
  #pragma unroll 1
  for (int t = 0; t < 64; ++t) {
    uint4 ku[8];
    #pragma unroll
    for (int i = 0; i < 8; ++i) ku[i] = ((const uint4*)(Ks + t * 64))[i];
    const float val = __bfloat162float(val_src[t * 64 + lane]);
    const float bt = Bs[t];
    float kvf[64];
    #pragma unroll
    for (int i = 0; i < 8; ++i) {
      kvf[8*i+0] = __uint_as_float(ku[i].x << 16);
      kvf[8*i+1] = __uint_as_float(ku[i].x & 0xffff0000u);
      kvf[8*i+2] = __uint_as_float(ku[i].y << 16);
      kvf[8*i+3] = __uint_as_float(ku[i].y & 0xffff0000u);
      kvf[8*i+4] = __uint_as_float(ku[i].z << 16);
      kvf[8*i+5] = __uint_as_float(ku[i].z & 0xffff0000u);
      kvf[8*i+6] = __uint_as_float(ku[i].w << 16);
      kvf[8*i+7] = __uint_as_float(ku[i].w & 0xffff0000u);
    }
    float p0 = 0, p1 = 0, p2 = 0, p3 = 0;
    #pragma unroll
    for (int i = 0; i < 16; ++i) {
      p0 += kvf[4*i+0] * S[4*i+0];
      p1 += kvf[4*i+1] * S[4*i+1];
      p2 += kvf[4*i+2] * S[4*i+2];
      p3 += kvf[4*i+3] * S[4*i+3];
    }
    const float u = bt * (val - ((p0 + p1) + (p2 + p3)));
    #pragma unroll
    for (int i = 0; i < 16; ++i) {
      S[4*i+0] += kvf[4*i+0] * u;
      S[4*i+1] += kvf[4*i+1] * u;
      S[4*i+2] += kvf[4*i+2] * u;
      S[4*i+3] += kvf[4*i+3] * u;
    }
    if (wave) Gs[t * 64 + lane] = __float2bfloat16(-u);
    else      Vs[t * 64 + lane] = __float2bfloat16(u);
  }
  __syncthreads();
  bf16* gout = Gneg + (size_t)ch * 4096;
  #pragma unroll
  for (int rnd = 0; rnd < 4; ++rnd) {
    const int r = rnd * 16 + sr;
    *(short8*)(v16 + rowb + (size_t)r * ND + sc) = *(const short8*)(Vs + r * 64 + sc);
    *(short8*)(gout + r * 64 + sc)               = *(const short8*)(Gs + r * 64 + sc);
  }
}

__global__ __launch_bounds__(256) void chunk_seq_mono(bf16* q16,
                                                      const bf16* __restrict__ k16,
                                                      const bf16* __restrict__ Ul,
                                                      const bf16* __restrict__ Gneg) {
  __shared__ bf16 ST[64 * 72];
  __shared__ bf16 Ubt[64 * 72];
  __shared__ bf16 Pt[64 * 72];
  __shared__ bf16 KTl[64 * 72];
  const int bh = blockIdx.x, h = bh & (NH - 1), b = bh >> 5;
  const int wave = threadIdx.x >> 6, lane = threadIdx.x & 63;
  const int frow = lane & 15, q4 = lane >> 4, fk = q4 * 8;
  const int cm = q4 * 4;
  for (int i = threadIdx.x; i < 64 * 72 / 2; i += 256) ((unsigned int*)ST)[i] = 0u;
  __syncthreads();
  f32x4 sacc[4] = {};
  #pragma unroll 1
  for (int c = 0; c < NCH; ++c) {
    const bf16* Gc = Gneg + ((size_t)bh * NCH + c) * 4096;
    const size_t qkb = ((size_t)b * NT + c * 64) * ND + (size_t)h * 64;
    {
      short8 r0 = *(const short8*)(k16 + qkb + (size_t)lane * ND + 16 * wave);
      short8 r1 = *(const short8*)(k16 + qkb + (size_t)lane * ND + 16 * wave + 8);
      #pragma unroll
      for (int j = 0; j < 8; ++j) {
        KTl[(16 * wave + j) * 72 + lane]     = ((const bf16*)&r0)[j];
        KTl[(16 * wave + 8 + j) * 72 + lane] = ((const bf16*)&r1)[j];
      }
    }
    short8 ga0 = *(const short8*)(Gc + (16 * wave + frow) * 64 + fk);
    short8 ga1 = *(const short8*)(Gc + (16 * wave + frow) * 64 + 32 + fk);
    #pragma unroll
    for (int n = 0; n < 4; ++n) {
      f32x4 acc;
      #pragma unroll
      for (int r = 0; r < 4; ++r)
        acc[r] = __bfloat162float(Ul[qkb + (size_t)(16 * wave + cm + r) * ND + 16 * n + frow]);
      acc = __builtin_amdgcn_mfma_f32_16x16x32_bf16(ga0, *(const short8*)(ST + (16 * n + frow) * 72 + fk), acc, 0, 0, 0);
      acc = __builtin_amdgcn_mfma_f32_16x16x32_bf16(ga1, *(const short8*)(ST + (16 * n + frow) * 72 + 32 + fk), acc, 0, 0, 0);
      #pragma unroll
      for (int r = 0; r < 4; ++r)
        Ubt[(16 * n + frow) * 72 + 16 * wave + cm + r] = __float2bfloat16(acc[r]);
    }
    __syncthreads();
    short8 qa0 = *(const short8*)(q16 + qkb + (size_t)(16 * wave + frow) * ND + fk);
    short8 qa1 = *(const short8*)(q16 + qkb + (size_t)(16 * wave + frow) * ND + 32 + fk);
    #pragma unroll
    for (int n = 0; n < 4; ++n) {
      f32x4 acc = {};
      acc = __builtin_amdgcn_mfma_f32_16x16x32_bf16(qa0, *(const short8*)(k16 + qkb + (size_t)(16 * n + frow) * ND + fk), acc, 0, 0, 0);
      acc = __builtin_amdgcn_mfma_f32_16x16x32_bf16(qa1, *(const short8*)(k16 + qkb + (size_t)(16 * n + frow) * ND + 32 + fk), acc, 0, 0, 0);
      #pragma unroll
      for (int r = 0; r < 4; ++r) {
        const int mg = 16 * wave + cm + r, ng = 16 * n + frow;
        Pt[mg * 72 + ng] = __float2bfloat16(ng <= mg ? acc[r] : 0.f);
      }
    }
    __syncthreads();
    short8 pa0 = *(const short8*)(Pt + (16 * wave + frow) * 72 + fk);
    short8 pa1 = *(const short8*)(Pt + (16 * wave + frow) * 72 + 32 + fk);
    #pragma unroll
    for (int n = 0; n < 4; ++n) {
      f32x4 acc = {};
      acc = __builtin_amdgcn_mfma_f32_16x16x32_bf16(qa0, *(const short8*)(ST + (16 * n + frow) * 72 + fk), acc, 0, 0, 0);
      acc = __builtin_amdgcn_mfma_f32_16x16x32_bf16(qa1, *(const short8*)(ST + (16 * n + frow) * 72 + 32 + fk), acc, 0, 0, 0);
      acc = __builtin_amdgcn_mfma_f32_16x16x32_bf16(pa0, *(const short8*)(Ubt + (16 * n + frow) * 72 + fk), acc, 0, 0, 0);
      acc = __builtin_amdgcn_mfma_f32_16x16x32_bf16(pa1, *(const short8*)(Ubt + (16 * n + frow) * 72 + 32 + fk), acc, 0, 0, 0);
      #pragma unroll
      for (int r = 0; r < 4; ++r)
        q16[qkb + (size_t)(16 * wave + cm + r) * ND + 16 * n + frow] = __float2bfloat16(acc[r]);
    }
    __syncthreads();
    short8 ua0 = *(const short8*)(Ubt + (16 * wave + frow) * 72 + fk);
    short8 ua1 = *(const short8*)(Ubt + (16 * wave + frow) * 72 + 32 + fk);
    #pragma unroll
    for (int n = 0; n < 4; ++n) {
      sacc[n] = __builtin_amdgcn_mfma_f32_16x16x32_bf16(ua0, *(const short8*)(KTl + (16 * n + frow) * 72 + fk), sacc[n], 0, 0, 0);
      sacc[n] = __builtin_amdgcn_mfma_f32_16x16x32_bf16(ua1, *(const short8*)(KTl + (16 * n + frow) * 72 + 32 + fk), sacc[n], 0, 0, 0);
      #pragma unroll
      for (int r = 0; r < 4; ++r)
        ST[(16 * wave + cm + r) * 72 + 16 * n + frow] = __float2bfloat16(sacc[n][r]);
    }
    __syncthreads();
  }
}

extern "C" void kernel_launch(void* const* d_in, const int* in_sizes, int n_in,
                              void* d_out, int out_size, void* d_ws, size_t ws_size,
                              hipStream_t stream) {
  const void* hs = d_in[0];
  const void* Wq = d_in[1];
  const void* Wk = d_in[2];
  const void* Wv = d_in[3];
  const void* Wb = d_in[4];
  const void* bb = d_in[5];
  const void* Wo = d_in[6];

  char* ws = (char*)d_ws;
  size_t off = 0;
  auto alloc = [&](size_t bytes) {
    void* p = ws + off;
    off += (bytes + 255) & ~(size_t)255;
    return p;
  };
  const size_t szW2 = (size_t)32 * 1024 * 1024;  // WT (26.2 MiB weights) + AcT alias region
  const size_t szM  = (size_t)NM * ND * 2;       // 16 MiB
  const size_t szB2 = (size_t)NM * 256 * 2;      // 2 MiB (beta logits, 256-padded)
  const size_t szB  = (size_t)NM * 128 * 2;      // fallback beta (128-padded)
  const size_t need_fused = 512 + szW2 + 4 * szM + szB2 + szM;   // ~119.6 MB

  if (ws_size >= need_fused) {
    // ---- fused path ----
    int*  flag  = (int*) alloc(256);
    bf16* WT    = (bf16*)alloc(szW2);  // weights [0,26.2Mi); later Gneg [0,16Mi) + AcT [16,32Mi)
    bf16* hs16  = (bf16*)alloc(szM);   // -> Sbuf after fused GEMM
    bf16* q16   = (bf16*)alloc(szM);   // O in place
    bf16* k16   = (bf16*)alloc(szM);
    bf16* v16   = (bf16*)alloc(szM);   // U^T (transposed-in-place)
    bf16* betab = (bf16*)alloc(szB2);
    bf16* Dc    = (bf16*)alloc(szM);
    bf16* Gneg  = WT;                                    // [0,16MiB) dead after fused GEMM
    bf16* AcT   = WT + (size_t)8 * 1024 * 1024;          // [16,32MiB)
    bf16* WoT   = AcT;                                   // reused after state_seq
    bf16* Sbuf  = hs16;

    detect_dtype<<<1, 64, 0, stream>>>((const unsigned short*)hs, flag);
    convert_bf16<<<(NM * ND) / (256 * 8), 256, 0, stream>>>(hs, hs16, (long)NM * ND, flag);

    transpose_qkvb<<<dim3(32, 32, 4), 256, 0, stream>>>(Wq, Wk, Wv, Wb, WT, flag);
    gemm256<<<400, 512, 0, stream>>>(hs16, WT, q16, k16, v16, betab,
                                     nullptr, nullptr, ND, 25);

    chunk_scan<<<NB * NH * NCH, 256, 0, stream>>>(k16, v16, betab, bb, flag, Gneg, AcT, Dc);
    state_seq<<<NB * NH, 256, 0, stream>>>(AcT, Dc, Sbuf);
    chunk_out<<<NB * NH * NCH, 256, 0, stream>>>(q16, k16, v16, Gneg, Sbuf);

    transpose_cvt<<<dim3(32, 32), 256, 0, stream>>>(Wo, WoT, 2048, 2048, flag);
    gemm256<<<128, 512, 0, stream>>>(q16, WoT, nullptr, nullptr, nullptr, nullptr,
                                     d_out, flag, ND, 8);
  } else {
    // ---- compact fallback (proven ~73 MB footprint) ----
    int*  flag  = (int*) alloc(256);
    bf16* Wt    = (bf16*)alloc((size_t)2048 * 2048 * 2);
    bf16* hs16  = (bf16*)alloc(szM);   // -> Gneg
    bf16* q16   = (bf16*)alloc(szM);
    bf16* k16   = (bf16*)alloc(szM);
    bf16* v16   = (bf16*)alloc(szM);
    bf16* betab = (bf16*)alloc(szB);
    bf16* Gneg  = hs16;

    detect_dtype<<<1, 64, 0, stream>>>((const unsigned short*)hs, flag);
    convert_bf16<<<(NM * ND) / (256 * 8), 256, 0, stream>>>(hs, hs16, (long)NM * ND, flag);

    transpose_cvt<<<dim3(32, 32), 256, 0, stream>>>(Wq, Wt, 2048, 2048, flag);
    gemm_bt<<<dim3(16, 32), 256, 0, stream>>>(hs16, Wt, q16, k16, v16, betab, nullptr, nullptr, NM, ND, 0);
    transpose_cvt<<<dim3(32, 32), 256, 0, stream>>>(Wk, Wt, 2048, 2048, flag);
    gemm_bt<<<dim3(16, 32), 256, 0, stream>>>(hs16, Wt, q16, k16, v16, betab, nullptr, nullptr, NM, ND, 2048);
    transpose_cvt<<<dim3(32, 32), 256, 0, stream>>>(Wv, Wt, 2048, 2048, flag);
    gemm_bt<<<dim3(16, 32), 256, 0, stream>>>(hs16, Wt, q16, k16, v16, betab, nullptr, nullptr, NM, ND, 4096);
    transpose_cvt<<<dim3(2, 32),  256, 0, stream>>>(Wb, Wt, 2048, 32, flag);
    gemm_bt<<<dim3(1, 32), 256, 0, stream>>>(hs16, Wt, q16, k16, v16, betab, nullptr, nullptr, NM, ND, 6144);

    chunk_scan_c<<<NB * NH * NCH, 128, 0, stream>>>(k16, v16, betab, bb, flag, Gneg);
    chunk_seq_mono<<<NB * NH, 256, 0, stream>>>(q16, k16, v16, Gneg);

    transpose_cvt<<<dim3(32, 32), 256, 0, stream>>>(Wo, Wt, 2048, 2048, flag);
    gemm_bt<<<dim3(16, 32), 256, 0, stream>>>(q16, Wt, nullptr, nullptr, nullptr, nullptr,
                                              d_out, flag, NM, ND, 0);
  }
}

// Round 4
// 573.986 us; speedup vs baseline: 1.0255x; 1.0136x over previous
//
#include <hip/hip_runtime.h>
#include <hip/hip_bf16.h>

typedef __hip_bfloat16 bf16;
typedef __attribute__((ext_vector_type(8))) short short8;   // 8 bf16 (4 VGPRs)
typedef __attribute__((ext_vector_type(4))) float f32x4;

#define NB 2
#define NT 2048
#define ND 2048
#define NH 32
#define NM (NB*NT)   // 4096 rows
#define NCH 32       // chunks per (b,h): NT/64

// ---- dtype hedge: inputs may be bf16 (harness-converted) or fp32 (per reference) ----
__global__ void detect_dtype(const unsigned short* __restrict__ hs, int* __restrict__ flag) {
  if (threadIdx.x == 0 && blockIdx.x == 0) {
    int cnt = 0;
    for (int i = 0; i < 2048; i += 2) {
      int e = (hs[i] >> 7) & 0xFF;
      if (e >= 141) ++cnt;
    }
    *flag = (cnt > 64) ? 1 : 0;   // 1 = fp32, 0 = bf16
  }
}

__device__ __forceinline__ float loadf(const void* p, size_t i, int isf32) {
  return isf32 ? ((const float*)p)[i] : __bfloat162float(((const bf16*)p)[i]);
}

__global__ __launch_bounds__(256) void convert_bf16(const void* __restrict__ src,
                                                    bf16* __restrict__ dst,
                                                    long n, const int* __restrict__ flag) {
  const long i0 = ((long)blockIdx.x * 256 + threadIdx.x) * 8;
  if (i0 >= n) return;
  if (*flag) {
    const float* s = (const float*)src;
    #pragma unroll
    for (int j = 0; j < 8; ++j) dst[i0 + j] = __float2bfloat16(s[i0 + j]);
  } else {
    *(short8*)(dst + i0) = *(const short8*)((const bf16*)src + i0);
  }
}

// ---- transpose + convert one matrix: dst[c][r] = bf16(src[r][c]); zero-pad cols ----
__global__ __launch_bounds__(256) void transpose_cvt(const void* __restrict__ src,
                                                     bf16* __restrict__ dst,
                                                     int src_rows, int src_cols,
                                                     const int* __restrict__ flag) {
  __shared__ bf16 tile[64][65];
  const int f = *flag;
  const int tb_r = blockIdx.y * 64, tb_c = blockIdx.x * 64;
  const int tx = threadIdx.x & 63, ty = threadIdx.x >> 6;
  #pragma unroll
  for (int i = 0; i < 64; i += 4) {
    const int cc = tb_c + tx;
    tile[i + ty][tx] = (cc < src_cols)
      ? __float2bfloat16(loadf(src, (size_t)(tb_r + i + ty) * src_cols + cc, f))
      : __float2bfloat16(0.f);
  }
  __syncthreads();
  #pragma unroll
  for (int i = 0; i < 64; i += 4)
    dst[(size_t)(tb_c + i + ty) * src_rows + tb_r + tx] = tile[tx][i + ty];
}

// ---- merged transpose of Wq/Wk/Wv/Wb into WT, z-sliced (beta block padded to 256 rows) ----
__global__ __launch_bounds__(256) void transpose_qkvb(const void* __restrict__ Wq,
                                                      const void* __restrict__ Wk,
                                                      const void* __restrict__ Wv,
                                                      const void* __restrict__ Wb,
                                                      bf16* __restrict__ WT,
                                                      const int* __restrict__ flag) {
  __shared__ bf16 tile[64][65];
  const int z = blockIdx.z;
  if (z == 3 && blockIdx.x >= 4) return;   // Wb^T: 256 padded rows
  const void* src = (z == 0) ? Wq : (z == 1) ? Wk : (z == 2) ? Wv : Wb;
  const int src_cols = (z == 3) ? 32 : 2048;
  bf16* dst = WT + (size_t)z * 2048 * 2048;
  const int f = *flag;
  const int tb_r = blockIdx.y * 64, tb_c = blockIdx.x * 64;
  const int tx = threadIdx.x & 63, ty = threadIdx.x >> 6;
  #pragma unroll
  for (int i = 0; i < 64; i += 4) {
    const int cc = tb_c + tx;
    tile[i + ty][tx] = (cc < src_cols)
      ? __float2bfloat16(loadf(src, (size_t)(tb_r + i + ty) * src_cols + cc, f))
      : __float2bfloat16(0.f);
  }
  __syncthreads();
  #pragma unroll
  for (int i = 0; i < 64; i += 4)
    dst[(size_t)(tb_c + i + ty) * 2048 + tb_r + tx] = tile[tx][i + ty];
}

// async 16B/lane global->LDS (wave-uniform LDS base + lane*16)
__device__ __forceinline__ void gload_lds16(const void* g, void* l) {
  __builtin_amdgcn_global_load_lds((__attribute__((address_space(1))) const void*)g,
                                   (__attribute__((address_space(3))) void*)l,
                                   16, 0, 0);
}

// ------------- legacy GEMM (out-projection + fallback): C = A @ Bt^T -------------
__global__ __launch_bounds__(256) void gemm_bt(const bf16* __restrict__ A,
                                               const bf16* __restrict__ Bt,
                                               bf16* __restrict__ oq, bf16* __restrict__ ok2,
                                               bf16* __restrict__ ov, bf16* __restrict__ ob,
                                               void* __restrict__ outv,
                                               const int* __restrict__ outflag,
                                               int M, int K, int n_base) {
  __shared__ bf16 As[128 * 32];
  __shared__ bf16 Bs[128 * 32];
  const int tid = threadIdx.x;
  const int wave = tid >> 6, lane = tid & 63;
  const int m0 = blockIdx.y * 128, n0 = blockIdx.x * 128;
  const int wm = (wave >> 1) * 64, wn = (wave & 1) * 64;
  const int srow = lane >> 2, scol = (lane & 3) * 8;
  const int frow = lane & 15, fk = (lane >> 4) * 8;
  f32x4 acc[4][4] = {};

  for (int kb = 0; kb < K; kb += 32) {
    __syncthreads();
    #pragma unroll
    for (int j = 0; j < 2; ++j) {
      const int rbase = wave * 32 + j * 16;
      gload_lds16(A  + (size_t)(m0 + rbase + srow) * K + kb + scol, As + rbase * 32);
      gload_lds16(Bt + (size_t)(n0 + rbase + srow) * K + kb + scol, Bs + rbase * 32);
    }
    __syncthreads();
    short8 af[4], bfr[4];
    #pragma unroll
    for (int i = 0; i < 4; ++i)
      af[i] = *(const short8*)(As + (wm + i * 16 + frow) * 32 + fk);
    #pragma unroll
    for (int i = 0; i < 4; ++i)
      bfr[i] = *(const short8*)(Bs + (wn + i * 16 + frow) * 32 + fk);
    #pragma unroll
    for (int mi = 0; mi < 4; ++mi)
      #pragma unroll
      for (int ni = 0; ni < 4; ++ni)
        acc[mi][ni] = __builtin_amdgcn_mfma_f32_16x16x32_bf16(af[mi], bfr[ni], acc[mi][ni], 0, 0, 0);
  }

  const int crow = (lane >> 4) * 4, ccol = lane & 15;
  const int gn0 = n_base + n0;
  if (outflag) {
    const int f = *outflag;
    #pragma unroll
    for (int mi = 0; mi < 4; ++mi)
      #pragma unroll
      for (int ni = 0; ni < 4; ++ni)
        #pragma unroll
        for (int r = 0; r < 4; ++r) {
          const size_t idx = (size_t)(m0 + wm + mi * 16 + crow + r) * 2048 + gn0 + wn + ni * 16 + ccol;
          const float val = acc[mi][ni][r];
          if (f == 1) ((float*)outv)[idx] = val;
          else        ((bf16*)outv)[idx] = __float2bfloat16(val);
        }
  } else {
    const int seg = gn0 >> 11;
    bf16* o = (seg == 0) ? oq : (seg == 1) ? ok2 : (seg == 2) ? ov : ob;
    const int stride = (seg < 3) ? 2048 : 128;
    const int cb = (gn0 & 2047) + wn;
    if (seg <= 1) {
      #pragma unroll
      for (int mi = 0; mi < 4; ++mi)
        #pragma unroll
        for (int r = 0; r < 4; ++r) {
          float s = acc[mi][0][r] * acc[mi][0][r] + acc[mi][1][r] * acc[mi][1][r]
                  + acc[mi][2][r] * acc[mi][2][r] + acc[mi][3][r] * acc[mi][3][r];
          s += __shfl_xor(s, 1, 64); s += __shfl_xor(s, 2, 64);
          s += __shfl_xor(s, 4, 64); s += __shfl_xor(s, 8, 64);
          const float inv = rsqrtf(s + 1e-6f);
          #pragma unroll
          for (int ni = 0; ni < 4; ++ni) acc[mi][ni][r] *= inv;
        }
    }
    #pragma unroll
    for (int mi = 0; mi < 4; ++mi)
      #pragma unroll
      for (int ni = 0; ni < 4; ++ni)
        #pragma unroll
        for (int r = 0; r < 4; ++r)
          o[(size_t)(m0 + wm + mi * 16 + crow + r) * stride + cb + ni * 16 + ccol] =
            __float2bfloat16(acc[mi][ni][r]);
  }
}

// ============ 256x256 8-phase GEMM v3: pipelined frag reads + counted lgkmcnt ============
// C = A[M][K] @ Bt[N][K]^T. 8 waves (2M x 4N), BK=64, 128 KiB LDS double-buffer,
// 3-bit both-sides LDS swizzle (bank-conflict-free, round-3 verified: SQ_LDS_BANK_CONFLICT=0).
// Frag reads are issued ONE PHASE AHEAD; each phase open waits s_waitcnt lgkmcnt(4)
// (DS completes in-order: <=4 outstanding => this phase's frags arrived, next phase's 4
// still in flight) so ds_read latency hides under the previous phase's MFMA cluster.
// A-frags ping-pong aFA (phases 0,2) / aFB (1,3); B-frags read once per tile.
// FRAG0 of tile t+1 issues in the boundary region (data resident by vmcnt accounting).

#define READ_PAIR(DST, P)                                                        \
  _Pragma("unroll") for (int q2 = 0; q2 < 2; ++q2)                               \
    _Pragma("unroll") for (int kk = 0; kk < 2; ++kk)                             \
      DST[q2][kk] = *(const short8*)(lA + (((P) * 2 + q2) * 16 + frow) * 128     \
                                        + ((kk * 64 + fq * 16) ^ fswz));

#define READ_BALL()                                                              \
  _Pragma("unroll") for (int ni2 = 0; ni2 < 4; ++ni2)                            \
    _Pragma("unroll") for (int kk = 0; kk < 2; ++kk)                             \
      bF[ni2][kk] = *(const short8*)(lB + (brow0 + ni2 * 16 + frow) * 128        \
                                        + ((kk * 64 + fq * 16) ^ fswz));

#define MFMA_P(SRC, P)                                                           \
  _Pragma("unroll") for (int q2 = 0; q2 < 2; ++q2)                               \
    _Pragma("unroll") for (int ni2 = 0; ni2 < 4; ++ni2) {                        \
      acc[(P) * 2 + q2][ni2] = __builtin_amdgcn_mfma_f32_16x16x32_bf16(          \
          SRC[q2][0], bF[ni2][0], acc[(P) * 2 + q2][ni2], 0, 0, 0);              \
      acc[(P) * 2 + q2][ni2] = __builtin_amdgcn_mfma_f32_16x16x32_bf16(          \
          SRC[q2][1], bF[ni2][1], acc[(P) * 2 + q2][ni2], 0, 0, 0);              \
    }

#define PH_OPEN_CNT(N) do { __builtin_amdgcn_s_barrier();                        \
  asm volatile("s_waitcnt lgkmcnt(" #N ")" ::: "memory");                        \
  __builtin_amdgcn_sched_barrier(0);                                             \
  __builtin_amdgcn_s_setprio(1); } while (0)

#define PH_CLOSE() do { __builtin_amdgcn_s_setprio(0);                           \
  __builtin_amdgcn_s_barrier(); } while (0)

__global__ __launch_bounds__(512, 2) void gemm256(const bf16* __restrict__ A,
                                                  const bf16* __restrict__ Bt,
                                                  bf16* __restrict__ oq, bf16* __restrict__ ok2,
                                                  bf16* __restrict__ ov, bf16* __restrict__ ob,
                                                  void* __restrict__ outv,
                                                  const int* __restrict__ outflag,
                                                  int K, int ntn) {
  __shared__ bf16 LA[2][2][8192];   // [parity][half(128 rows)][128*64]
  __shared__ bf16 LB[2][2][8192];
  const int tid = threadIdx.x;
  const int wave = tid >> 6, lane = tid & 63;
  const int wm = wave >> 2, wn = wave & 3;
  const int frow = lane & 15, fq = lane >> 4;
  // bijective XCD swizzle (gridDim.x % 8 == 0 by construction)
  const int cpx = (int)gridDim.x >> 3;
  const int wg = ((int)blockIdx.x & 7) * cpx + ((int)blockIdx.x >> 3);
  const int mtile = wg / ntn, ntile = wg % ntn;
  const int m0 = mtile * 256, n0 = ntile * 256;
  const int NTK = K >> 6;
  // 3-bit read swizzle: byte ^= (row&7)<<4 ; row&7 == frow&7 (16-row frag bases are 0 mod 8)
  const int fswz = (frow & 7) << 4;
  // staging: linear LDS dest (wave*1024 + j*8192 + lane*16); inverse-swizzled global source
  int srow[2], scolb[2];
  #pragma unroll
  for (int j = 0; j < 2; ++j) {
    const int q = wave * 1024 + j * 8192 + lane * 16;
    const int qs = q ^ (((q >> 7) & 7) << 4);
    srow[j]  = qs >> 7;          // row within the 128-row half
    scolb[j] = (qs & 127) >> 1;  // element col within 64
  }
  const int lofs = wave * 1024;

  f32x4 acc[8][4] = {};
  short8 aFA[2][2], aFB[2][2], bF[4][2];

  auto STAGE = [&](const bf16* __restrict__ G, int row0, int kcol, bf16* lhalf) {
    #pragma unroll
    for (int j = 0; j < 2; ++j)
      gload_lds16(G + (size_t)(row0 + srow[j]) * K + kcol + scolb[j],
                  (char*)lhalf + lofs + j * 8192);
  };

  // prologue: tile0 all 4 halves + tile1 A halves; leave tile1 A in flight
  STAGE(A,  m0,       0,  LA[0][0]);
  STAGE(A,  m0 + 128, 0,  LA[0][1]);
  STAGE(Bt, n0,       0,  LB[0][0]);
  STAGE(Bt, n0 + 128, 0,  LB[0][1]);
  STAGE(A,  m0,       64, LA[1][0]);
  STAGE(A,  m0 + 128, 64, LA[1][1]);
  asm volatile("s_waitcnt vmcnt(4)" ::: "memory");
  __builtin_amdgcn_s_barrier();

  const int brow0 = (wn & 1) * 64;
  {  // FRAG0(t=0): A pair0 + all B (12 ds_reads, left in flight into the loop)
    const char* lA = (const char*)LA[0][wm];
    const char* lB = (const char*)LB[0][wn >> 1];
    READ_PAIR(aFA, 0)
    READ_BALL()
    __builtin_amdgcn_sched_barrier(0);   // pin FRAG0 issue before FRAG1 (in-order lgkmcnt)
  }

  #pragma unroll 1
  for (int t = 0; t < NTK; ++t) {
    const int par = t & 1;
    const char* lA = (const char*)LA[par][wm];
    const char* lB = (const char*)LB[par][wn >> 1];
    // ---- phase 0: issue FRAG1; wait FRAG0 (lgkm<=4); MFMA pair0; stage (t+1):B0 ----
    READ_PAIR(aFB, 1)
    if (t + 1 < NTK) STAGE(Bt, n0, (t + 1) * 64, LB[par ^ 1][0]);
    PH_OPEN_CNT(4);
    MFMA_P(aFA, 0)
    PH_CLOSE();
    // ---- phase 1: issue FRAG2; wait FRAG1; MFMA pair1; stage (t+1):B1 ----
    READ_PAIR(aFA, 2)
    if (t + 1 < NTK) STAGE(Bt, n0 + 128, (t + 1) * 64, LB[par ^ 1][1]);
    PH_OPEN_CNT(4);
    MFMA_P(aFB, 1)
    PH_CLOSE();
    // ---- phase 2: issue FRAG3; wait FRAG2; MFMA pair2 ----
    READ_PAIR(aFB, 3)
    PH_OPEN_CNT(4);
    MFMA_P(aFA, 2)
    PH_CLOSE();
    // ---- phase 3: wait FRAG3 (drain); MFMA pair3 ----
    PH_OPEN_CNT(0);
    MFMA_P(aFB, 3)
    __builtin_amdgcn_s_setprio(0);
    __builtin_amdgcn_s_barrier();   // p3 close: all waves' LA[par] reads complete
    if (t + 1 < NTK) {
      if (t + 2 < NTK) {
        STAGE(A, m0,       (t + 2) * 64, LA[par][0]);
        STAGE(A, m0 + 128, (t + 2) * 64, LA[par][1]);
      }
      if (t == NTK - 2) asm volatile("s_waitcnt vmcnt(0)" ::: "memory");
      else              asm volatile("s_waitcnt vmcnt(4)" ::: "memory");
      __builtin_amdgcn_s_barrier();  // boundary: tile t+1 operands resident
      {  // FRAG0(t+1): A pair0 + all B from the next-parity buffers
        const char* lAn = (const char*)LA[par ^ 1][wm];
        const char* lBn = (const char*)LB[par ^ 1][wn >> 1];
        const char* lA = lAn;
        const char* lB = lBn;
        READ_PAIR(aFA, 0)
        READ_BALL()
        __builtin_amdgcn_sched_barrier(0);  // keep FRAG0 before next-iter FRAG1
      }
    }
  }

  // epilogue
  const int crow = fq * 4, ccol = frow;
  const int rowb = m0 + wm * 128;
  if (outv) {
    const int f = *outflag;
    const int cb = n0 + wn * 64;
    #pragma unroll
    for (int mi = 0; mi < 8; ++mi)
      #pragma unroll
      for (int ni = 0; ni < 4; ++ni)
        #pragma unroll
        for (int r = 0; r < 4; ++r) {
          const size_t idx = (size_t)(rowb + mi * 16 + crow + r) * 2048 + cb + ni * 16 + ccol;
          const float val = acc[mi][ni][r];
          if (f == 1) ((float*)outv)[idx] = val;
          else        ((bf16*)outv)[idx] = __float2bfloat16(val);
        }
    return;
  }
  // routed epilogue: seg 0/1 l2norm per 64-col head, 2 plain, 3 beta (stride 256)
  const int gn0w = n0 + wn * 64;
  const int seg = gn0w >> 11;
  bf16* o = (seg == 0) ? oq : (seg == 1) ? ok2 : (seg == 2) ? ov : ob;
  const int stride = (seg < 3) ? 2048 : 256;
  const int cb = (seg < 3) ? (gn0w & 2047) : (gn0w - 6144);
  if (seg <= 1) {
    #pragma unroll
    for (int mi = 0; mi < 8; ++mi)
      #pragma unroll
      for (int r = 0; r < 4; ++r) {
        float s = acc[mi][0][r] * acc[mi][0][r] + acc[mi][1][r] * acc[mi][1][r]
                + acc[mi][2][r] * acc[mi][2][r] + acc[mi][3][r] * acc[mi][3][r];
        s += __shfl_xor(s, 1, 64); s += __shfl_xor(s, 2, 64);
        s += __shfl_xor(s, 4, 64); s += __shfl_xor(s, 8, 64);
        const float inv = rsqrtf(s + 1e-6f);
        #pragma unroll
        for (int ni = 0; ni < 4; ++ni) acc[mi][ni][r] *= inv;
      }
  }
  #pragma unroll
  for (int mi = 0; mi < 8; ++mi)
    #pragma unroll
    for (int ni = 0; ni < 4; ++ni)
      #pragma unroll
      for (int r = 0; r < 4; ++r)
        o[(size_t)(rowb + mi * 16 + crow + r) * stride + cb + ni * 16 + ccol] =
          __float2bfloat16(acc[mi][ni][r]);
}

// ======================= fused-path chunk kernels =======================

template<int TB>
__device__ __forceinline__ void scan16(const float* __restrict__ Af,
                                       const bf16* __restrict__ vsrc,
                                       const float* __restrict__ Bsc,
                                       float (&u)[64], const int lane, const int wave,
                                       const float sgn,
                                       bf16* __restrict__ outT,
                                       bf16* __restrict__ gout) {
  constexpr int JM = (TB + 1) * 16;
  #pragma unroll
  for (int tt = 0; tt < 16; ++tt) {
    const int t = TB * 16 + tt;
    float pr0 = 0.f, pr1 = 0.f, pr2 = 0.f, pr3 = 0.f;
    #pragma unroll
    for (int i = 0; i < JM; i += 4) {
      const f32x4 a = *(const f32x4*)(Af + t * 64 + i);   // wave-uniform row read
      pr0 = __builtin_fmaf(a[0], u[i + 0], pr0);
      pr1 = __builtin_fmaf(a[1], u[i + 1], pr1);
      pr2 = __builtin_fmaf(a[2], u[i + 2], pr2);
      pr3 = __builtin_fmaf(a[3], u[i + 3], pr3);
    }
    const float ut = Bsc[t] * __bfloat162float(vsrc[t * 72 + lane])
                   - ((pr0 + pr1) + (pr2 + pr3));
    u[t] = ut;
    const bf16 sv = __float2bfloat16(sgn * ut);
    outT[lane * 72 + t] = sv;
    if (wave) gout[t * 64 + lane] = sv;
  }
}

// pass 1: A = beta*tril(K K^T) via MFMA (fp32 LDS), then two register forward substitutions.
__global__ __launch_bounds__(256) void chunk_scan(const bf16* __restrict__ k16,
                                                  bf16* __restrict__ v16,
                                                  const bf16* __restrict__ betab,
                                                  const void* __restrict__ bb,
                                                  const int* __restrict__ flag,
                                                  bf16* __restrict__ Gneg,
                                                  bf16* __restrict__ AcT,
                                                  bf16* __restrict__ Dc) {
  __shared__ bf16 Ks[64 * 72];
  __shared__ bf16 Vs[64 * 72];
  __shared__ bf16 GsT[64 * 72];
  __shared__ bf16 UsT[64 * 72];
  __shared__ float Af[64 * 64];
  __shared__ float Bsc[64];
  bf16* const KTs = (bf16*)Af;
  const int ch = blockIdx.x;
  const int c = ch & (NCH - 1), bh = ch >> 5;
  const int h = bh & (NH - 1), b = bh >> 5;
  const int tid = threadIdx.x, wave = tid >> 6, lane = tid & 63;
  const size_t rowb = ((size_t)b * NT + c * 64) * ND + (size_t)h * 64;

  short8 ktA0, ktB0, ktA1, ktB1;
  if (wave >= 2) {
    const int d0a = (wave - 2) * 16, d0b = d0a + 32;
    ktA0 = *(const short8*)(k16 + rowb + (size_t)lane * ND + d0a);
    ktB0 = *(const short8*)(k16 + rowb + (size_t)lane * ND + d0a + 8);
    ktA1 = *(const short8*)(k16 + rowb + (size_t)lane * ND + d0b);
    ktB1 = *(const short8*)(k16 + rowb + (size_t)lane * ND + d0b + 8);
  }
  {
    const int r0 = tid >> 3, sc = (tid & 7) * 8;
    #pragma unroll
    for (int rnd = 0; rnd < 2; ++rnd) {
      const int r = rnd * 32 + r0;
      *(short8*)(Ks + r * 72 + sc) = *(const short8*)(k16 + rowb + (size_t)r * ND + sc);
      *(short8*)(Vs + r * 72 + sc) = *(const short8*)(v16 + rowb + (size_t)r * ND + sc);
    }
  }
  if (tid < 64) {
    const float x = __bfloat162float(betab[((size_t)b * NT + c * 64 + tid) * 256 + h])
                    + loadf(bb, h, *flag);
    Bsc[tid] = 1.f / (1.f + expf(-x));
  }
  __syncthreads();

  const int frow = lane & 15, fk = (lane >> 4) * 8, cm = (lane >> 4) * 4;
  {
    short8 ma0 = *(const short8*)(Ks + (16 * wave + frow) * 72 + fk);
    short8 ma1 = *(const short8*)(Ks + (16 * wave + frow) * 72 + 32 + fk);
    #pragma unroll
    for (int n = 0; n < 4; ++n) {
      f32x4 m = {};
      m = __builtin_amdgcn_mfma_f32_16x16x32_bf16(ma0, *(const short8*)(Ks + (16 * n + frow) * 72 + fk), m, 0, 0, 0);
      m = __builtin_amdgcn_mfma_f32_16x16x32_bf16(ma1, *(const short8*)(Ks + (16 * n + frow) * 72 + 32 + fk), m, 0, 0, 0);
      #pragma unroll
      for (int r = 0; r < 4; ++r) {
        const int t = 16 * wave + cm + r, s = 16 * n + frow;
        Af[t * 64 + s] = (s < t) ? Bsc[t] * m[r] : 0.f;
      }
    }
  }
  __syncthreads();

  if (wave < 2) {
    float u[64];
    #pragma unroll
    for (int i = 0; i < 64; ++i) u[i] = 0.f;
    const bf16* vsrc = wave ? Ks : Vs;
    bf16* outT = wave ? GsT : UsT;
    bf16* gout = Gneg + (size_t)ch * 4096;
    const float sgn = wave ? -1.f : 1.f;
    scan16<0>(Af, vsrc, Bsc, u, lane, wave, sgn, outT, gout);
    scan16<1>(Af, vsrc, Bsc, u, lane, wave, sgn, outT, gout);
    scan16<2>(Af, vsrc, Bsc, u, lane, wave, sgn, outT, gout);
    scan16<3>(Af, vsrc, Bsc, u, lane, wave, sgn, outT, gout);
  }
  __syncthreads();

  if (wave >= 2) {
    const int d0a = (wave - 2) * 16, d0b = d0a + 32;
    #pragma unroll
    for (int j = 0; j < 8; ++j) {
      KTs[(d0a + j) * 72 + lane]     = ((const bf16*)&ktA0)[j];
      KTs[(d0a + 8 + j) * 72 + lane] = ((const bf16*)&ktB0)[j];
      KTs[(d0b + j) * 72 + lane]     = ((const bf16*)&ktA1)[j];
      KTs[(d0b + 8 + j) * 72 + lane] = ((const bf16*)&ktB1)[j];
    }
  }
  __syncthreads();

  short8 ka0 = *(const short8*)(KTs + (16 * wave + frow) * 72 + fk);
  short8 ka1 = *(const short8*)(KTs + (16 * wave + frow) * 72 + 32 + fk);
  short8 uu0 = *(const short8*)(UsT + (16 * wave + frow) * 72 + fk);
  short8 uu1 = *(const short8*)(UsT + (16 * wave + frow) * 72 + 32 + fk);
  #pragma unroll
  for (int n = 0; n < 4; ++n) {
    f32x4 aA = {}, aD = {};
    aA = __builtin_amdgcn_mfma_f32_16x16x32_bf16(ka0, *(const short8*)(GsT + (16 * n + frow) * 72 + fk), aA, 0, 0, 0);
    aA = __builtin_amdgcn_mfma_f32_16x16x32_bf16(ka1, *(const short8*)(GsT + (16 * n + frow) * 72 + 32 + fk), aA, 0, 0, 0);
    aD = __builtin_amdgcn_mfma_f32_16x16x32_bf16(uu0, *(const short8*)(KTs + (16 * n + frow) * 72 + fk), aD, 0, 0, 0);
    aD = __builtin_amdgcn_mfma_f32_16x16x32_bf16(uu1, *(const short8*)(KTs + (16 * n + frow) * 72 + 32 + fk), aD, 0, 0, 0);
    #pragma unroll
    for (int r = 0; r < 4; ++r) {
      Vs[(16 * wave + cm + r) * 64 + 16 * n + frow] = __float2bfloat16(aA[r]);
      Ks[(16 * wave + cm + r) * 64 + 16 * n + frow] = __float2bfloat16(aD[r]);
    }
  }
  __syncthreads();
  {
    const int r0 = tid >> 2, sc2 = (tid & 3) * 16;
    bf16* acg = AcT + (size_t)ch * 4096;
    bf16* dcg = Dc  + (size_t)ch * 4096;
    *(short8*)(acg + r0 * 64 + sc2)     = *(const short8*)(Vs + r0 * 64 + sc2);
    *(short8*)(acg + r0 * 64 + sc2 + 8) = *(const short8*)(Vs + r0 * 64 + sc2 + 8);
    *(short8*)(dcg + r0 * 64 + sc2)     = *(const short8*)(Ks + r0 * 64 + sc2);
    *(short8*)(dcg + r0 * 64 + sc2 + 8) = *(const short8*)(Ks + r0 * 64 + sc2 + 8);
    *(short8*)(v16 + rowb + (size_t)r0 * ND + sc2)     = *(const short8*)(UsT + r0 * 72 + sc2);
    *(short8*)(v16 + rowb + (size_t)r0 * ND + sc2 + 8) = *(const short8*)(UsT + r0 * 72 + sc2 + 8);
  }
}

// pass 2: minimal serial recurrence: sacc(fp32) += S_bf16 @ AcT^T + Dc, per chunk.
__global__ __launch_bounds__(256) void state_seq(const bf16* __restrict__ AcT,
                                                 const bf16* __restrict__ Dc,
                                                 bf16* __restrict__ Sbuf) {
  __shared__ bf16 ST[64 * 72];
  const int bh = blockIdx.x;
  const int wave = threadIdx.x >> 6, lane = threadIdx.x & 63;
  const int frow = lane & 15, fk = (lane >> 4) * 8, cm = (lane >> 4) * 4;
  for (int i = threadIdx.x; i < 64 * 72 / 2; i += 256) ((unsigned int*)ST)[i] = 0u;
  f32x4 sacc[4] = {};
  const bf16* ac = AcT + (size_t)bh * NCH * 4096;
  const bf16* dc = Dc  + (size_t)bh * NCH * 4096;
  bf16* sb = Sbuf + (size_t)bh * NCH * 4096;
  #pragma unroll
  for (int n = 0; n < 4; ++n)
    #pragma unroll
    for (int r = 0; r < 4; ++r)
      sb[(16 * wave + cm + r) * 64 + 16 * n + frow] = __float2bfloat16(0.f);
  short8 bpre[4][2];
  float dpre[16];
  #pragma unroll
  for (int n = 0; n < 4; ++n) {
    bpre[n][0] = *(const short8*)(ac + (16 * n + frow) * 64 + fk);
    bpre[n][1] = *(const short8*)(ac + (16 * n + frow) * 64 + 32 + fk);
    #pragma unroll
    for (int r = 0; r < 4; ++r)
      dpre[n * 4 + r] = __bfloat162float(dc[(16 * wave + cm + r) * 64 + 16 * n + frow]);
  }
  __syncthreads();
  #pragma unroll 1
  for (int c = 0; c < NCH; ++c) {
    short8 a0 = *(const short8*)(ST + (16 * wave + frow) * 72 + fk);
    short8 a1 = *(const short8*)(ST + (16 * wave + frow) * 72 + 32 + fk);
    short8 bcur[4][2];
    float dcur[16];
    #pragma unroll
    for (int n = 0; n < 4; ++n) {
      bcur[n][0] = bpre[n][0]; bcur[n][1] = bpre[n][1];
      #pragma unroll
      for (int r = 0; r < 4; ++r) dcur[n * 4 + r] = dpre[n * 4 + r];
    }
    if (c + 1 < NCH) {
      const bf16* acn = ac + (size_t)(c + 1) * 4096;
      const bf16* dcn = dc + (size_t)(c + 1) * 4096;
      #pragma unroll
      for (int n = 0; n < 4; ++n) {
        bpre[n][0] = *(const short8*)(acn + (16 * n + frow) * 64 + fk);
        bpre[n][1] = *(const short8*)(acn + (16 * n + frow) * 64 + 32 + fk);
        #pragma unroll
        for (int r = 0; r < 4; ++r)
          dpre[n * 4 + r] = __bfloat162float(dcn[(16 * wave + cm + r) * 64 + 16 * n + frow]);
      }
    }
    #pragma unroll
    for (int n = 0; n < 4; ++n) {
      sacc[n] = __builtin_amdgcn_mfma_f32_16x16x32_bf16(a0, bcur[n][0], sacc[n], 0, 0, 0);
      sacc[n] = __builtin_amdgcn_mfma_f32_16x16x32_bf16(a1, bcur[n][1], sacc[n], 0, 0, 0);
      #pragma unroll
      for (int r = 0; r < 4; ++r) sacc[n][r] += dcur[n * 4 + r];
    }
    __syncthreads();
    #pragma unroll
    for (int n = 0; n < 4; ++n)
      #pragma unroll
      for (int r = 0; r < 4; ++r) {
        const bf16 sv = __float2bfloat16(sacc[n][r]);
        ST[(16 * wave + cm + r) * 72 + 16 * n + frow] = sv;
        if (c + 1 < NCH)
          sb[(size_t)(c + 1) * 4096 + (16 * wave + cm + r) * 64 + 16 * n + frow] = sv;
      }
    __syncthreads();
  }
}

// pass 3: chunk-parallel outputs. O = Q*S_c + tril(QK^T)*U_c, in place over q16.
__global__ __launch_bounds__(256) void chunk_out(bf16* __restrict__ q16,
                                                 const bf16* __restrict__ k16,
                                                 const bf16* __restrict__ v16,
                                                 const bf16* __restrict__ Gneg,
                                                 const bf16* __restrict__ Sbuf) {
  __shared__ bf16 UTs[64 * 72];
  __shared__ bf16 Pt[64 * 72];
  const int ch = blockIdx.x;
  const int c = ch & (NCH - 1), bh = ch >> 5;
  const int h = bh & (NH - 1), b = bh >> 5;
  const int tid = threadIdx.x, wave = tid >> 6, lane = tid & 63;
  const int frow = lane & 15, fk = (lane >> 4) * 8, cm = (lane >> 4) * 4;
  const size_t qkb = ((size_t)b * NT + c * 64) * ND + (size_t)h * 64;
  const bf16* Sb = Sbuf + (size_t)ch * 4096;
  const bf16* Gc = Gneg + (size_t)ch * 4096;
  {
    const int r0 = tid >> 2, sc2 = (tid & 3) * 16;
    *(short8*)(UTs + r0 * 72 + sc2)     = *(const short8*)(v16 + qkb + (size_t)r0 * ND + sc2);
    *(short8*)(UTs + r0 * 72 + sc2 + 8) = *(const short8*)(v16 + qkb + (size_t)r0 * ND + sc2 + 8);
  }
  short8 qa0 = *(const short8*)(q16 + qkb + (size_t)(16 * wave + frow) * ND + fk);
  short8 qa1 = *(const short8*)(q16 + qkb + (size_t)(16 * wave + frow) * ND + 32 + fk);
  f32x4 pacc[4];
  #pragma unroll
  for (int n = 0; n < 4; ++n) {
    f32x4 a = {};
    a = __builtin_amdgcn_mfma_f32_16x16x32_bf16(qa0, *(const short8*)(k16 + qkb + (size_t)(16 * n + frow) * ND + fk), a, 0, 0, 0);
    a = __builtin_amdgcn_mfma_f32_16x16x32_bf16(qa1, *(const short8*)(k16 + qkb + (size_t)(16 * n + frow) * ND + 32 + fk), a, 0, 0, 0);
    pacc[n] = a;
  }
  __syncthreads();
  f32x4 uacc[4];
  #pragma unroll
  for (int n = 0; n < 4; ++n)
    #pragma unroll
    for (int r = 0; r < 4; ++r)
      uacc[n][r] = __bfloat162float(UTs[(16 * wave + cm + r) * 72 + 16 * n + frow]);
  #pragma unroll
  for (int n = 0; n < 4; ++n)
    #pragma unroll
    for (int r = 0; r < 4; ++r) {
      const int mg = 16 * wave + cm + r, ng = 16 * n + frow;
      Pt[mg * 72 + ng] = __float2bfloat16(ng <= mg ? pacc[n][r] : 0.f);
    }
  short8 sa0 = *(const short8*)(Sb + (16 * wave + frow) * 64 + fk);
  short8 sa1 = *(const short8*)(Sb + (16 * wave + frow) * 64 + 32 + fk);
  #pragma unroll
  for (int n = 0; n < 4; ++n) {
    uacc[n] = __builtin_amdgcn_mfma_f32_16x16x32_bf16(sa0, *(const short8*)(Gc + (16 * n + frow) * 64 + fk), uacc[n], 0, 0, 0);
    uacc[n] = __builtin_amdgcn_mfma_f32_16x16x32_bf16(sa1, *(const short8*)(Gc + (16 * n + frow) * 64 + 32 + fk), uacc[n], 0, 0, 0);
  }
  __syncthreads();
  #pragma unroll
  for (int n = 0; n < 4; ++n)
    #pragma unroll
    for (int r = 0; r < 4; ++r)
      UTs[(16 * wave + cm + r) * 72 + 16 * n + frow] = __float2bfloat16(uacc[n][r]);
  __syncthreads();
  short8 pa0 = *(const short8*)(Pt + (16 * wave + frow) * 72 + fk);
  short8 pa1 = *(const short8*)(Pt + (16 * wave + frow) * 72 + 32 + fk);
  #pragma unroll
  for (int n = 0; n < 4; ++n) {
    f32x4 o = {};
    o = __builtin_amdgcn_mfma_f32_16x16x32_bf16(qa0, *(const short8*)(Sb + (16 * n + frow) * 64 + fk), o, 0, 0, 0);
    o = __builtin_amdgcn_mfma_f32_16x16x32_bf16(qa1, *(const short8*)(Sb + (16 * n + frow) * 64 + 32 + fk), o, 0, 0, 0);
    o = __builtin_amdgcn_mfma_f32_16x16x32_bf16(pa0, *(const short8*)(UTs + (16 * n + frow) * 72 + fk), o, 0, 0, 0);
    o = __builtin_amdgcn_mfma_f32_16x16x32_bf16(pa1, *(const short8*)(UTs + (16 * n + frow) * 72 + 32 + fk), o, 0, 0, 0);
    #pragma unroll
    for (int r = 0; r < 4; ++r)
      q16[qkb + (size_t)(16 * wave + cm + r) * ND + 16 * n + frow] = __float2bfloat16(o[r]);
  }
}

// ======================= compact-fallback chunk kernels (round-4 proven) =======================

__global__ __launch_bounds__(128) void chunk_scan_c(const bf16* __restrict__ k16,
                                                    bf16* __restrict__ v16,
                                                    const bf16* __restrict__ betab,
                                                    const void* __restrict__ bb,
                                                    const int* __restrict__ flag,
                                                    bf16* __restrict__ Gneg) {
  __shared__ bf16 Ks[64 * 64];
  __shared__ bf16 Vs[64 * 64];
  __shared__ bf16 Gs[64 * 64];
  __shared__ float Bs[64];
  const int ch = blockIdx.x;
  const int c = ch & (NCH - 1), bh = ch >> 5;
  const int h = bh & (NH - 1), b = bh >> 5;
  const int tid = threadIdx.x;
  const int wave = tid >> 6, lane = tid & 63;
  const size_t rowb = ((size_t)b * NT + c * 64) * ND + (size_t)h * 64;
  const int sr = tid >> 3, sc = (tid & 7) * 8;
  #pragma unroll
  for (int rnd = 0; rnd < 4; ++rnd) {
    const int r = rnd * 16 + sr;
    *(short8*)(Ks + r * 64 + sc) = *(const short8*)(k16 + rowb + (size_t)r * ND + sc);
    *(short8*)(Vs + r * 64 + sc) = *(const short8*)(v16 + rowb + (size_t)r * ND + sc);
  }
  if (tid < 64) {
    const float x = __bfloat162float(betab[((size_t)b * NT + c * 64 + tid) * 128 + h])
                    + loadf(bb, h, *flag);
    Bs[tid] = 1.f / (1.f + expf(-x));
  }
  __syncthreads();
  float S[64];
  #pragma unroll
  for (int i = 0; i < 64; ++i) S[i] = 0.f;
  const bf16* val_src = wave ? Ks : Vs;
  #pragma unroll 1
  for (int t = 0; t < 64; ++t) {
    uint4 ku[8];
    #pragma unroll
    for (int i = 0; i < 8; ++i) ku[i] = ((const uint4*)(Ks + t * 64))[i];
    const float val = __bfloat162float(val_src[t * 64 + lane]);
    const float bt = Bs[t];
    float kvf[64];
    #pragma unroll
    for (int i = 0; i < 8; ++i) {
      kvf[8*i+0] = __uint_as_float(ku[i].x << 16);
      kvf[8*i+1] = __uint_as_float(ku[i].x & 0xffff0000u);
      kvf[8*i+2] = __uint_as_float(ku[i].y << 16);
      kvf[8*i+3] = __uint_as_float(ku[i].y & 0xffff0000u);
      kvf[8*i+4] = __uint_as_float(ku[i].z << 16);
      kvf[8*i+5] = __uint_as_float(ku[i].z & 0xffff0000u);
      kvf[8*i+6] = __uint_as_float(ku[i].w << 16);
      kvf[8*i+7] = __uint_as_float(ku[i].w & 0xffff0000u);
    }
    float p0 = 0, p1 = 0, p2 = 0, p3 = 0;
    #pragma unroll
    for (int i = 0; i < 16; ++i) {
      p0 += kvf[4*i+0] * S[4*i+0];
      p1 += kvf[4*i+1] * S[4*i+1];
      p2 += kvf[4*i+2] * S[4*i+2];
      p3 += kvf[4*i+3] * S[4*i+3];
    }
    const float u = bt * (val - ((p0 + p1) + (p2 + p3)));
    #pragma unroll
    for (int i = 0; i < 16; ++i) {
      S[4*i+0] += kvf[4*i+0] * u;
      S[4*i+1] += kvf[4*i+1] * u;
      S[4*i+2] += kvf[4*i+2] * u;
      S[4*i+3] += kvf[4*i+3] * u;
    }
    if (wave) Gs[t * 64 + lane] = __float2bfloat16(-u);
    else      Vs[t * 64 + lane] = __float2bfloat16(u);
  }
  __syncthreads();
  bf16* gout = Gneg + (size_t)ch * 4096;
  #pragma unroll
  for (int rnd = 0; rnd < 4; ++rnd) {
    const int r = rnd * 16 + sr;
    *(short8*)(v16 + rowb + (size_t)r * ND + sc) = *(const short8*)(Vs + r * 64 + sc);
    *(short8*)(gout + r * 64 + sc)               = *(const short8*)(Gs + r * 64 + sc);
  }
}

__global__ __launch_bounds__(256) void chunk_seq_mono(bf16* q16,
                                                      const bf16* __restrict__ k16,
                                                      const bf16* __restrict__ Ul,
                                                      const bf16* __restrict__ Gneg) {
  __shared__ bf16 ST[64 * 72];
  __shared__ bf16 Ubt[64 * 72];
  __shared__ bf16 Pt[64 * 72];
  __shared__ bf16 KTl[64 * 72];
  const int bh = blockIdx.x, h = bh & (NH - 1), b = bh >> 5;
  const int wave = threadIdx.x >> 6, lane = threadIdx.x & 63;
  const int frow = lane & 15, q4 = lane >> 4, fk = q4 * 8;
  const int cm = q4 * 4;
  for (int i = threadIdx.x; i < 64 * 72 / 2; i += 256) ((unsigned int*)ST)[i] = 0u;
  __syncthreads();
  f32x4 sacc[4] = {};
  #pragma unroll 1
  for (int c = 0; c < NCH; ++c) {
    const bf16* Gc = Gneg + ((size_t)bh * NCH + c) * 4096;
    const size_t qkb = ((size_t)b * NT + c * 64) * ND + (size_t)h * 64;
    {
      short8 r0 = *(const short8*)(k16 + qkb + (size_t)lane * ND + 16 * wave);
      short8 r1 = *(const short8*)(k16 + qkb + (size_t)lane * ND + 16 * wave + 8);
      #pragma unroll
      for (int j = 0; j < 8; ++j) {
        KTl[(16 * wave + j) * 72 + lane]     = ((const bf16*)&r0)[j];
        KTl[(16 * wave + 8 + j) * 72 + lane] = ((const bf16*)&r1)[j];
      }
    }
    short8 ga0 = *(const short8*)(Gc + (16 * wave + frow) * 64 + fk);
    short8 ga1 = *(const short8*)(Gc + (16 * wave + frow) * 64 + 32 + fk);
    #pragma unroll
    for (int n = 0; n < 4; ++n) {
      f32x4 acc;
      #pragma unroll
      for (int r = 0; r < 4; ++r)
        acc[r] = __bfloat162float(Ul[qkb + (size_t)(16 * wave + cm + r) * ND + 16 * n + frow]);
      acc = __builtin_amdgcn_mfma_f32_16x16x32_bf16(ga0, *(const short8*)(ST + (16 * n + frow) * 72 + fk), acc, 0, 0, 0);
      acc = __builtin_amdgcn_mfma_f32_16x16x32_bf16(ga1, *(const short8*)(ST + (16 * n + frow) * 72 + 32 + fk), acc, 0, 0, 0);
      #pragma unroll
      for (int r = 0; r < 4; ++r)
        Ubt[(16 * n + frow) * 72 + 16 * wave + cm + r] = __float2bfloat16(acc[r]);
    }
    __syncthreads();
    short8 qa0 = *(const short8*)(q16 + qkb + (size_t)(16 * wave + frow) * ND + fk);
    short8 qa1 = *(const short8*)(q16 + qkb + (size_t)(16 * wave + frow) * ND + 32 + fk);
    #pragma unroll
    for (int n = 0; n < 4; ++n) {
      f32x4 acc = {};
      acc = __builtin_amdgcn_mfma_f32_16x16x32_bf16(qa0, *(const short8*)(k16 + qkb + (size_t)(16 * n + frow) * ND + fk), acc, 0, 0, 0);
      acc = __builtin_amdgcn_mfma_f32_16x16x32_bf16(qa1, *(const short8*)(k16 + qkb + (size_t)(16 * n + frow) * ND + 32 + fk), acc, 0, 0, 0);
      #pragma unroll
      for (int r = 0; r < 4; ++r) {
        const int mg = 16 * wave + cm + r, ng = 16 * n + frow;
        Pt[mg * 72 + ng] = __float2bfloat16(ng <= mg ? acc[r] : 0.f);
      }
    }
    __syncthreads();
    short8 pa0 = *(const short8*)(Pt + (16 * wave + frow) * 72 + fk);
    short8 pa1 = *(const short8*)(Pt + (16 * wave + frow) * 72 + 32 + fk);
    #pragma unroll
    for (int n = 0; n < 4; ++n) {
      f32x4 acc = {};
      acc = __builtin_amdgcn_mfma_f32_16x16x32_bf16(qa0, *(const short8*)(ST + (16 * n + frow) * 72 + fk), acc, 0, 0, 0);
      acc = __builtin_amdgcn_mfma_f32_16x16x32_bf16(qa1, *(const short8*)(ST + (16 * n + frow) * 72 + 32 + fk), acc, 0, 0, 0);
      acc = __builtin_amdgcn_mfma_f32_16x16x32_bf16(pa0, *(const short8*)(Ubt + (16 * n + frow) * 72 + fk), acc, 0, 0, 0);
      acc = __builtin_amdgcn_mfma_f32_16x16x32_bf16(pa1, *(const short8*)(Ubt + (16 * n + frow) * 72 + 32 + fk), acc, 0, 0, 0);
      #pragma unroll
      for (int r = 0; r < 4; ++r)
        q16[qkb + (size_t)(16 * wave + cm + r) * ND + 16 * n + frow] = __float2bfloat16(acc[r]);
    }
    __syncthreads();
    short8 ua0 = *(const short8*)(Ubt + (16 * wave + frow) * 72 + fk);
    short8 ua1 = *(const short8*)(Ubt + (16 * wave + frow) * 72 + 32 + fk);
    #pragma unroll
    for (int n = 0; n < 4; ++n) {
      sacc[n] = __builtin_amdgcn_mfma_f32_16x16x32_bf16(ua0, *(const short8*)(KTl + (16 * n + frow) * 72 + fk), sacc[n], 0, 0, 0);
      sacc[n] = __builtin_amdgcn_mfma_f32_16x16x32_bf16(ua1, *(const short8*)(KTl + (16 * n + frow) * 72 + 32 + fk), sacc[n], 0, 0, 0);
      #pragma unroll
      for (int r = 0; r < 4; ++r)
        ST[(16 * wave + cm + r) * 72 + 16 * n + frow] = __float2bfloat16(sacc[n][r]);
    }
    __syncthreads();
  }
}

extern "C" void kernel_launch(void* const* d_in, const int* in_sizes, int n_in,
                              void* d_out, int out_size, void* d_ws, size_t ws_size,
                              hipStream_t stream) {
  const void* hs = d_in[0];
  const void* Wq = d_in[1];
  const void* Wk = d_in[2];
  const void* Wv = d_in[3];
  const void* Wb = d_in[4];
  const void* bb = d_in[5];
  const void* Wo = d_in[6];

  char* ws = (char*)d_ws;
  size_t off = 0;
  auto alloc = [&](size_t bytes) {
    void* p = ws + off;
    off += (bytes + 255) & ~(size_t)255;
    return p;
  };
  const size_t szW2 = (size_t)32 * 1024 * 1024;  // WT (26.2 MiB weights) + AcT alias region
  const size_t szM  = (size_t)NM * ND * 2;       // 16 MiB
  const size_t szB2 = (size_t)NM * 256 * 2;      // 2 MiB (beta logits, 256-padded)
  const size_t szB  = (size_t)NM * 128 * 2;      // fallback beta (128-padded)
  const size_t need_fused = 512 + szW2 + 4 * szM + szB2 + szM;   // ~119.6 MB

  if (ws_size >= need_fused) {
    // ---- fused path ----
    int*  flag  = (int*) alloc(256);
    bf16* WT    = (bf16*)alloc(szW2);  // weights [0,26.2Mi); later Gneg [0,16Mi) + AcT [16,32Mi)
    bf16* hs16  = (bf16*)alloc(szM);   // -> Sbuf after fused GEMM
    bf16* q16   = (bf16*)alloc(szM);   // O in place
    bf16* k16   = (bf16*)alloc(szM);
    bf16* v16   = (bf16*)alloc(szM);   // U^T (transposed-in-place)
    bf16* betab = (bf16*)alloc(szB2);
    bf16* Dc    = (bf16*)alloc(szM);
    bf16* Gneg  = WT;                                    // [0,16MiB) dead after fused GEMM
    bf16* AcT   = WT + (size_t)8 * 1024 * 1024;          // [16,32MiB)
    bf16* WoT   = AcT;                                   // reused after state_seq
    bf16* Sbuf  = hs16;

    detect_dtype<<<1, 64, 0, stream>>>((const unsigned short*)hs, flag);
    convert_bf16<<<(NM * ND) / (256 * 8), 256, 0, stream>>>(hs, hs16, (long)NM * ND, flag);

    transpose_qkvb<<<dim3(32, 32, 4), 256, 0, stream>>>(Wq, Wk, Wv, Wb, WT, flag);
    gemm256<<<400, 512, 0, stream>>>(hs16, WT, q16, k16, v16, betab,
                                     nullptr, nullptr, ND, 25);

    chunk_scan<<<NB * NH * NCH, 256, 0, stream>>>(k16, v16, betab, bb, flag, Gneg, AcT, Dc);
    state_seq<<<NB * NH, 256, 0, stream>>>(AcT, Dc, Sbuf);
    chunk_out<<<NB * NH * NCH, 256, 0, stream>>>(q16, k16, v16, Gneg, Sbuf);

    transpose_cvt<<<dim3(32, 32), 256, 0, stream>>>(Wo, WoT, 2048, 2048, flag);
    gemm_bt<<<dim3(16, 32), 256, 0, stream>>>(q16, WoT, nullptr, nullptr, nullptr, nullptr,
                                              d_out, flag, NM, ND, 0);
  } else {
    // ---- compact fallback (proven ~73 MB footprint) ----
    int*  flag  = (int*) alloc(256);
    bf16* Wt    = (bf16*)alloc((size_t)2048 * 2048 * 2);
    bf16* hs16  = (bf16*)alloc(szM);   // -> Gneg
    bf16* q16   = (bf16*)alloc(szM);
    bf16* k16   = (bf16*)alloc(szM);
    bf16* v16   = (bf16*)alloc(szM);
    bf16* betab = (bf16*)alloc(szB);
    bf16* Gneg  = hs16;

    detect_dtype<<<1, 64, 0, stream>>>((const unsigned short*)hs, flag);
    convert_bf16<<<(NM * ND) / (256 * 8), 256, 0, stream>>>(hs, hs16, (long)NM * ND, flag);

    transpose_cvt<<<dim3(32, 32), 256, 0, stream>>>(Wq, Wt, 2048, 2048, flag);
    gemm_bt<<<dim3(16, 32), 256, 0, stream>>>(hs16, Wt, q16, k16, v16, betab, nullptr, nullptr, NM, ND, 0);
    transpose_cvt<<<dim3(32, 32), 256, 0, stream>>>(Wk, Wt, 2048, 2048, flag);
    gemm_bt<<<dim3(16, 32), 256, 0, stream>>>(hs16, Wt, q16, k16, v16, betab, nullptr, nullptr, NM, ND, 2048);
    transpose_cvt<<<dim3(32, 32), 256, 0, stream>>>(Wv, Wt, 2048, 2048, flag);
    gemm_bt<<<dim3(16, 32), 256, 0, stream>>>(hs16, Wt, q16, k16, v16, betab, nullptr, nullptr, NM, ND, 4096);
    transpose_cvt<<<dim3(2, 32),  256, 0, stream>>>(Wb, Wt, 2048, 32, flag);
    gemm_bt<<<dim3(1, 32), 256, 0, stream>>>(hs16, Wt, q16, k16, v16, betab, nullptr, nullptr, NM, ND, 6144);

    chunk_scan_c<<<NB * NH * NCH, 128, 0, stream>>>(k16, v16, betab, bb, flag, Gneg);
    chunk_seq_mono<<<NB * NH, 256, 0, stream>>>(q16, k16, v16, Gneg);

    transpose_cvt<<<dim3(32, 32), 256, 0, stream>>>(Wo, Wt, 2048, 2048, flag);
    gemm_bt<<<dim3(16, 32), 256, 0, stream>>>(q16, Wt, nullptr, nullptr, nullptr, nullptr,
                                              d_out, flag, NM, ND, 0);
  }
}

// Round 5
// 567.991 us; speedup vs baseline: 1.0364x; 1.0106x over previous
//
#include <hip/hip_runtime.h>
#include <hip/hip_bf16.h>

typedef __hip_bfloat16 bf16;
typedef __attribute__((ext_vector_type(8))) short short8;   // 8 bf16 (4 VGPRs)
typedef __attribute__((ext_vector_type(4))) float f32x4;

#define NB 2
#define NT 2048
#define ND 2048
#define NH 32
#define NM (NB*NT)   // 4096 rows
#define NCH 32       // chunks per (b,h): NT/64

// ---- dtype hedge: inputs may be bf16 (harness-converted) or fp32 (per reference) ----
__global__ void detect_dtype(const unsigned short* __restrict__ hs, int* __restrict__ flag) {
  if (threadIdx.x == 0 && blockIdx.x == 0) {
    int cnt = 0;
    for (int i = 0; i < 2048; i += 2) {
      int e = (hs[i] >> 7) & 0xFF;
      if (e >= 141) ++cnt;
    }
    *flag = (cnt > 64) ? 1 : 0;   // 1 = fp32, 0 = bf16
  }
}

__device__ __forceinline__ float loadf(const void* p, size_t i, int isf32) {
  return isf32 ? ((const float*)p)[i] : __bfloat162float(((const bf16*)p)[i]);
}

__global__ __launch_bounds__(256) void convert_bf16(const void* __restrict__ src,
                                                    bf16* __restrict__ dst,
                                                    long n, const int* __restrict__ flag) {
  const long i0 = ((long)blockIdx.x * 256 + threadIdx.x) * 8;
  if (i0 >= n) return;
  if (*flag) {
    const float* s = (const float*)src;
    #pragma unroll
    for (int j = 0; j < 8; ++j) dst[i0 + j] = __float2bfloat16(s[i0 + j]);
  } else {
    *(short8*)(dst + i0) = *(const short8*)((const bf16*)src + i0);
  }
}

// ---- transpose + convert one matrix: dst[c][r] = bf16(src[r][c]); zero-pad cols ----
__global__ __launch_bounds__(256) void transpose_cvt(const void* __restrict__ src,
                                                     bf16* __restrict__ dst,
                                                     int src_rows, int src_cols,
                                                     const int* __restrict__ flag) {
  __shared__ bf16 tile[64][65];
  const int f = *flag;
  const int tb_r = blockIdx.y * 64, tb_c = blockIdx.x * 64;
  const int tx = threadIdx.x & 63, ty = threadIdx.x >> 6;
  #pragma unroll
  for (int i = 0; i < 64; i += 4) {
    const int cc = tb_c + tx;
    tile[i + ty][tx] = (cc < src_cols)
      ? __float2bfloat16(loadf(src, (size_t)(tb_r + i + ty) * src_cols + cc, f))
      : __float2bfloat16(0.f);
  }
  __syncthreads();
  #pragma unroll
  for (int i = 0; i < 64; i += 4)
    dst[(size_t)(tb_c + i + ty) * src_rows + tb_r + tx] = tile[tx][i + ty];
}

// ---- merged transpose of Wq/Wk/Wv/Wb into WT, z-sliced (beta block padded to 256 rows) ----
__global__ __launch_bounds__(256) void transpose_qkvb(const void* __restrict__ Wq,
                                                      const void* __restrict__ Wk,
                                                      const void* __restrict__ Wv,
                                                      const void* __restrict__ Wb,
                                                      bf16* __restrict__ WT,
                                                      const int* __restrict__ flag) {
  __shared__ bf16 tile[64][65];
  const int z = blockIdx.z;
  if (z == 3 && blockIdx.x >= 4) return;   // Wb^T: 256 padded rows
  const void* src = (z == 0) ? Wq : (z == 1) ? Wk : (z == 2) ? Wv : Wb;
  const int src_cols = (z == 3) ? 32 : 2048;
  bf16* dst = WT + (size_t)z * 2048 * 2048;
  const int f = *flag;
  const int tb_r = blockIdx.y * 64, tb_c = blockIdx.x * 64;
  const int tx = threadIdx.x & 63, ty = threadIdx.x >> 6;
  #pragma unroll
  for (int i = 0; i < 64; i += 4) {
    const int cc = tb_c + tx;
    tile[i + ty][tx] = (cc < src_cols)
      ? __float2bfloat16(loadf(src, (size_t)(tb_r + i + ty) * src_cols + cc, f))
      : __float2bfloat16(0.f);
  }
  __syncthreads();
  #pragma unroll
  for (int i = 0; i < 64; i += 4)
    dst[(size_t)(tb_c + i + ty) * 2048 + tb_r + tx] = tile[tx][i + ty];
}

// async 16B/lane global->LDS (wave-uniform LDS base + lane*16)
__device__ __forceinline__ void gload_lds16(const void* g, void* l) {
  __builtin_amdgcn_global_load_lds((__attribute__((address_space(1))) const void*)g,
                                   (__attribute__((address_space(3))) void*)l,
                                   16, 0, 0);
}

// ------------- legacy GEMM (out-projection + fallback): C = A @ Bt^T -------------
__global__ __launch_bounds__(256) void gemm_bt(const bf16* __restrict__ A,
                                               const bf16* __restrict__ Bt,
                                               bf16* __restrict__ oq, bf16* __restrict__ ok2,
                                               bf16* __restrict__ ov, bf16* __restrict__ ob,
                                               void* __restrict__ outv,
                                               const int* __restrict__ outflag,
                                               int M, int K, int n_base) {
  __shared__ bf16 As[128 * 32];
  __shared__ bf16 Bs[128 * 32];
  const int tid = threadIdx.x;
  const int wave = tid >> 6, lane = tid & 63;
  const int m0 = blockIdx.y * 128, n0 = blockIdx.x * 128;
  const int wm = (wave >> 1) * 64, wn = (wave & 1) * 64;
  const int srow = lane >> 2, scol = (lane & 3) * 8;
  const int frow = lane & 15, fk = (lane >> 4) * 8;
  f32x4 acc[4][4] = {};

  for (int kb = 0; kb < K; kb += 32) {
    __syncthreads();
    #pragma unroll
    for (int j = 0; j < 2; ++j) {
      const int rbase = wave * 32 + j * 16;
      gload_lds16(A  + (size_t)(m0 + rbase + srow) * K + kb + scol, As + rbase * 32);
      gload_lds16(Bt + (size_t)(n0 + rbase + srow) * K + kb + scol, Bs + rbase * 32);
    }
    __syncthreads();
    short8 af[4], bfr[4];
    #pragma unroll
    for (int i = 0; i < 4; ++i)
      af[i] = *(const short8*)(As + (wm + i * 16 + frow) * 32 + fk);
    #pragma unroll
    for (int i = 0; i < 4; ++i)
      bfr[i] = *(const short8*)(Bs + (wn + i * 16 + frow) * 32 + fk);
    #pragma unroll
    for (int mi = 0; mi < 4; ++mi)
      #pragma unroll
      for (int ni = 0; ni < 4; ++ni)
        acc[mi][ni] = __builtin_amdgcn_mfma_f32_16x16x32_bf16(af[mi], bfr[ni], acc[mi][ni], 0, 0, 0);
  }

  const int crow = (lane >> 4) * 4, ccol = lane & 15;
  const int gn0 = n_base + n0;
  if (outflag) {
    const int f = *outflag;
    #pragma unroll
    for (int mi = 0; mi < 4; ++mi)
      #pragma unroll
      for (int ni = 0; ni < 4; ++ni)
        #pragma unroll
        for (int r = 0; r < 4; ++r) {
          const size_t idx = (size_t)(m0 + wm + mi * 16 + crow + r) * 2048 + gn0 + wn + ni * 16 + ccol;
          const float val = acc[mi][ni][r];
          if (f == 1) ((float*)outv)[idx] = val;
          else        ((bf16*)outv)[idx] = __float2bfloat16(val);
        }
  } else {
    const int seg = gn0 >> 11;
    bf16* o = (seg == 0) ? oq : (seg == 1) ? ok2 : (seg == 2) ? ov : ob;
    const int stride = (seg < 3) ? 2048 : 128;
    const int cb = (gn0 & 2047) + wn;
    if (seg <= 1) {
      #pragma unroll
      for (int mi = 0; mi < 4; ++mi)
        #pragma unroll
        for (int r = 0; r < 4; ++r) {
          float s = acc[mi][0][r] * acc[mi][0][r] + acc[mi][1][r] * acc[mi][1][r]
                  + acc[mi][2][r] * acc[mi][2][r] + acc[mi][3][r] * acc[mi][3][r];
          s += __shfl_xor(s, 1, 64); s += __shfl_xor(s, 2, 64);
          s += __shfl_xor(s, 4, 64); s += __shfl_xor(s, 8, 64);
          const float inv = rsqrtf(s + 1e-6f);
          #pragma unroll
          for (int ni = 0; ni < 4; ++ni) acc[mi][ni][r] *= inv;
        }
    }
    #pragma unroll
    for (int mi = 0; mi < 4; ++mi)
      #pragma unroll
      for (int ni = 0; ni < 4; ++ni)
        #pragma unroll
        for (int r = 0; r < 4; ++r)
          o[(size_t)(m0 + wm + mi * 16 + crow + r) * stride + cb + ni * 16 + ccol] =
            __float2bfloat16(acc[mi][ni][r]);
  }
}

// ============ 256x256 8-phase GEMM v4: supertile XCD locality + full-tile load slack ============
// C = A[M][K] @ Bt[N][K]^T. 8 waves (2M x 4N), BK=64, 128 KiB LDS double-buffer,
// 3-bit both-sides LDS swizzle (bank-conflict-free). Frag reads pipelined one phase ahead
// (lgkmcnt(4)). Staging (all for tile t+2, full-tile latency slack): B0@p1, B1@p2
// (LB[par] free after p0-close: tile t's B reads serviced by p0-open lgkm wait),
// A both halves @boundary (LA[par] free after p3-close). Boundary waits vmcnt(8):
// in-flight = tile t+2's 8 loads; everything for t+1 forced complete (>=4 phases slack).
// Supertile mapping (ntn==25): XCDs = 2 m-groups x 4 n-groups; per-XCD patch 8 mtiles x
// 6-7 ntiles -> per-K-step L2 working set ~480KB (fits 4MB) -> K-slices fetched once/XCD.

#define READ_PAIR(DST, P)                                                        \
  _Pragma("unroll") for (int q2 = 0; q2 < 2; ++q2)                               \
    _Pragma("unroll") for (int kk = 0; kk < 2; ++kk)                             \
      DST[q2][kk] = *(const short8*)(lA + (((P) * 2 + q2) * 16 + frow) * 128     \
                                        + ((kk * 64 + fq * 16) ^ fswz));

#define READ_BALL()                                                              \
  _Pragma("unroll") for (int ni2 = 0; ni2 < 4; ++ni2)                            \
    _Pragma("unroll") for (int kk = 0; kk < 2; ++kk)                             \
      bF[ni2][kk] = *(const short8*)(lB + (brow0 + ni2 * 16 + frow) * 128        \
                                        + ((kk * 64 + fq * 16) ^ fswz));

#define MFMA_P(SRC, P)                                                           \
  _Pragma("unroll") for (int q2 = 0; q2 < 2; ++q2)                               \
    _Pragma("unroll") for (int ni2 = 0; ni2 < 4; ++ni2) {                        \
      acc[(P) * 2 + q2][ni2] = __builtin_amdgcn_mfma_f32_16x16x32_bf16(          \
          SRC[q2][0], bF[ni2][0], acc[(P) * 2 + q2][ni2], 0, 0, 0);              \
      acc[(P) * 2 + q2][ni2] = __builtin_amdgcn_mfma_f32_16x16x32_bf16(          \
          SRC[q2][1], bF[ni2][1], acc[(P) * 2 + q2][ni2], 0, 0, 0);              \
    }

#define PH_OPEN_CNT(N) do { __builtin_amdgcn_s_barrier();                        \
  asm volatile("s_waitcnt lgkmcnt(" #N ")" ::: "memory");                        \
  __builtin_amdgcn_sched_barrier(0);                                             \
  __builtin_amdgcn_s_setprio(1); } while (0)

#define PH_CLOSE() do { __builtin_amdgcn_s_setprio(0);                           \
  __builtin_amdgcn_s_barrier(); } while (0)

__global__ __launch_bounds__(512, 2) void gemm256(const bf16* __restrict__ A,
                                                  const bf16* __restrict__ Bt,
                                                  bf16* __restrict__ oq, bf16* __restrict__ ok2,
                                                  bf16* __restrict__ ov, bf16* __restrict__ ob,
                                                  void* __restrict__ outv,
                                                  const int* __restrict__ outflag,
                                                  int K, int ntn) {
  __shared__ bf16 LA[2][2][8192];   // [parity][half(128 rows)][128*64]
  __shared__ bf16 LB[2][2][8192];
  const int tid = threadIdx.x;
  const int wave = tid >> 6, lane = tid & 63;
  const int wm = wave >> 2, wn = wave & 3;
  const int frow = lane & 15, fq = lane >> 4;
  // tile mapping
  int mtile, ntile;
  if (ntn == 25) {
    // supertile XCD mapping for the 16x25 QKVB grid (bijective; blockIdx%8 ~ XCD)
    const int x = (int)blockIdx.x & 7, r = (int)blockIdx.x >> 3;
    const int mg = x >> 2, ng = x & 3;
    const int w = (ng == 0) ? 7 : 6;
    const int nb0 = (ng == 0) ? 0 : 1 + ng * 6;   // 0,7,13,19
    const int cap = 8 * w;
    if (r < cap) { mtile = mg * 8 + (r & 7); ntile = nb0 + (r >> 3); }
    else {   // overflow (ng>0, r in {48,49}) -> region (mg,0) slots 50..55
      const int r2 = 50 + (ng - 1) * 2 + (r - 48);
      mtile = mg * 8 + (r2 & 7); ntile = r2 >> 3;
    }
  } else {
    const int cpx = (int)gridDim.x >> 3;
    const int wg = ((int)blockIdx.x & 7) * cpx + ((int)blockIdx.x >> 3);
    mtile = wg / ntn; ntile = wg % ntn;
  }
  const int m0 = mtile * 256, n0 = ntile * 256;
  const int NTK = K >> 6;
  // 3-bit read swizzle: byte ^= (row&7)<<4 ; row&7 == frow&7 (16-row frag bases are 0 mod 8)
  const int fswz = (frow & 7) << 4;
  // staging: linear LDS dest (wave*1024 + j*8192 + lane*16); inverse-swizzled global source
  int srow[2], scolb[2];
  #pragma unroll
  for (int j = 0; j < 2; ++j) {
    const int q = wave * 1024 + j * 8192 + lane * 16;
    const int qs = q ^ (((q >> 7) & 7) << 4);
    srow[j]  = qs >> 7;          // row within the 128-row half
    scolb[j] = (qs & 127) >> 1;  // element col within 64
  }
  const int lofs = wave * 1024;

  f32x4 acc[8][4] = {};
  short8 aFA[2][2], aFB[2][2], bF[4][2];

  auto STAGE = [&](const bf16* __restrict__ G, int row0, int kcol, bf16* lhalf) {
    #pragma unroll
    for (int j = 0; j < 2; ++j)
      gload_lds16(G + (size_t)(row0 + srow[j]) * K + kcol + scolb[j],
                  (char*)lhalf + lofs + j * 8192);
  };

  // prologue: stage tile0 AND tile1 fully (16 loads); wait for tile0 (vmcnt(8))
  STAGE(A,  m0,       0,  LA[0][0]);
  STAGE(A,  m0 + 128, 0,  LA[0][1]);
  STAGE(Bt, n0,       0,  LB[0][0]);
  STAGE(Bt, n0 + 128, 0,  LB[0][1]);
  if (NTK > 1) {
    STAGE(A,  m0,       64, LA[1][0]);
    STAGE(A,  m0 + 128, 64, LA[1][1]);
    STAGE(Bt, n0,       64, LB[1][0]);
    STAGE(Bt, n0 + 128, 64, LB[1][1]);
    asm volatile("s_waitcnt vmcnt(8)" ::: "memory");
  } else {
    asm volatile("s_waitcnt vmcnt(0)" ::: "memory");
  }
  __builtin_amdgcn_s_barrier();

  const int brow0 = (wn & 1) * 64;
  {  // FRAG0(t=0): A pair0 + all B (12 ds_reads, left in flight into the loop)
    const char* lA = (const char*)LA[0][wm];
    const char* lB = (const char*)LB[0][wn >> 1];
    READ_PAIR(aFA, 0)
    READ_BALL()
    __builtin_amdgcn_sched_barrier(0);   // pin FRAG0 issue before FRAG1 (in-order lgkmcnt)
  }

  #pragma unroll 1
  for (int t = 0; t < NTK; ++t) {
    const int par = t & 1;
    const char* lA = (const char*)LA[par][wm];
    const char* lB = (const char*)LB[par][wn >> 1];
    // ---- phase 0: issue FRAG1; wait FRAG0 (lgkm<=4); MFMA pair0 ----
    READ_PAIR(aFB, 1)
    PH_OPEN_CNT(4);
    MFMA_P(aFA, 0)
    PH_CLOSE();
    // ---- phase 1: issue FRAG2; stage (t+2):B0 (LB[par] free after p0-close); MFMA pair1 ----
    READ_PAIR(aFA, 2)
    if (t + 2 < NTK) STAGE(Bt, n0, (t + 2) * 64, LB[par][0]);
    PH_OPEN_CNT(4);
    MFMA_P(aFB, 1)
    PH_CLOSE();
    // ---- phase 2: issue FRAG3; stage (t+2):B1; MFMA pair2 ----
    READ_PAIR(aFB, 3)
    if (t + 2 < NTK) STAGE(Bt, n0 + 128, (t + 2) * 64, LB[par][1]);
    PH_OPEN_CNT(4);
    MFMA_P(aFA, 2)
    PH_CLOSE();
    // ---- phase 3: wait FRAG3 (drain); MFMA pair3 ----
    PH_OPEN_CNT(0);
    MFMA_P(aFB, 3)
    __builtin_amdgcn_s_setprio(0);
    __builtin_amdgcn_s_barrier();   // p3 close: all waves' LA[par] reads complete
    if (t + 1 < NTK) {
      if (t + 2 < NTK) {
        STAGE(A, m0,       (t + 2) * 64, LA[par][0]);
        STAGE(A, m0 + 128, (t + 2) * 64, LA[par][1]);
        asm volatile("s_waitcnt vmcnt(8)" ::: "memory");   // tile t+1 resident; t+2 in flight
      } else {
        asm volatile("s_waitcnt vmcnt(0)" ::: "memory");   // tail: drain everything
      }
      __builtin_amdgcn_s_barrier();  // boundary: tile t+1 operands resident for all waves
      {  // FRAG0(t+1): A pair0 + all B from the next-parity buffers
        const char* lA = (const char*)LA[par ^ 1][wm];
        const char* lB = (const char*)LB[par ^ 1][wn >> 1];
        READ_PAIR(aFA, 0)
        READ_BALL()
        __builtin_amdgcn_sched_barrier(0);  // keep FRAG0 before next-iter FRAG1
      }
    }
  }

  // epilogue
  const int crow = fq * 4, ccol = frow;
  const int rowb = m0 + wm * 128;
  if (outv) {
    const int f = *outflag;
    const int cb = n0 + wn * 64;
    #pragma unroll
    for (int mi = 0; mi < 8; ++mi)
      #pragma unroll
      for (int ni = 0; ni < 4; ++ni)
        #pragma unroll
        for (int r = 0; r < 4; ++r) {
          const size_t idx = (size_t)(rowb + mi * 16 + crow + r) * 2048 + cb + ni * 16 + ccol;
          const float val = acc[mi][ni][r];
          if (f == 1) ((float*)outv)[idx] = val;
          else        ((bf16*)outv)[idx] = __float2bfloat16(val);
        }
    return;
  }
  // routed epilogue: seg 0/1 l2norm per 64-col head, 2 plain, 3 beta (stride 256)
  const int gn0w = n0 + wn * 64;
  const int seg = gn0w >> 11;
  bf16* o = (seg == 0) ? oq : (seg == 1) ? ok2 : (seg == 2) ? ov : ob;
  const int stride = (seg < 3) ? 2048 : 256;
  const int cb = (seg < 3) ? (gn0w & 2047) : (gn0w - 6144);
  if (seg <= 1) {
    #pragma unroll
    for (int mi = 0; mi < 8; ++mi)
      #pragma unroll
      for (int r = 0; r < 4; ++r) {
        float s = acc[mi][0][r] * acc[mi][0][r] + acc[mi][1][r] * acc[mi][1][r]
                + acc[mi][2][r] * acc[mi][2][r] + acc[mi][3][r] * acc[mi][3][r];
        s += __shfl_xor(s, 1, 64); s += __shfl_xor(s, 2, 64);
        s += __shfl_xor(s, 4, 64); s += __shfl_xor(s, 8, 64);
        const float inv = rsqrtf(s + 1e-6f);
        #pragma unroll
        for (int ni = 0; ni < 4; ++ni) acc[mi][ni][r] *= inv;
      }
  }
  #pragma unroll
  for (int mi = 0; mi < 8; ++mi)
    #pragma unroll
    for (int ni = 0; ni < 4; ++ni)
      #pragma unroll
      for (int r = 0; r < 4; ++r)
        o[(size_t)(rowb + mi * 16 + crow + r) * stride + cb + ni * 16 + ccol] =
          __float2bfloat16(acc[mi][ni][r]);
}

// ======================= fused-path chunk kernels =======================

template<int TB>
__device__ __forceinline__ void scan16(const float* __restrict__ Af,
                                       const bf16* __restrict__ vsrc,
                                       const float* __restrict__ Bsc,
                                       float (&u)[64], const int lane, const int wave,
                                       const float sgn,
                                       bf16* __restrict__ outT,
                                       bf16* __restrict__ gout) {
  constexpr int JM = (TB + 1) * 16;
  #pragma unroll
  for (int tt = 0; tt < 16; ++tt) {
    const int t = TB * 16 + tt;
    float pr0 = 0.f, pr1 = 0.f, pr2 = 0.f, pr3 = 0.f;
    #pragma unroll
    for (int i = 0; i < JM; i += 4) {
      const f32x4 a = *(const f32x4*)(Af + t * 64 + i);   // wave-uniform row read
      pr0 = __builtin_fmaf(a[0], u[i + 0], pr0);
      pr1 = __builtin_fmaf(a[1], u[i + 1], pr1);
      pr2 = __builtin_fmaf(a[2], u[i + 2], pr2);
      pr3 = __builtin_fmaf(a[3], u[i + 3], pr3);
    }
    const float ut = Bsc[t] * __bfloat162float(vsrc[t * 72 + lane])
                   - ((pr0 + pr1) + (pr2 + pr3));
    u[t] = ut;
    const bf16 sv = __float2bfloat16(sgn * ut);
    outT[lane * 72 + t] = sv;
    if (wave) gout[t * 64 + lane] = sv;
  }
}

// pass 1: A = beta*tril(K K^T) via MFMA (fp32 LDS), then two register forward substitutions.
__global__ __launch_bounds__(256) void chunk_scan(const bf16* __restrict__ k16,
                                                  bf16* __restrict__ v16,
                                                  const bf16* __restrict__ betab,
                                                  const void* __restrict__ bb,
                                                  const int* __restrict__ flag,
                                                  bf16* __restrict__ Gneg,
                                                  bf16* __restrict__ AcT,
                                                  bf16* __restrict__ Dc) {
  __shared__ bf16 Ks[64 * 72];
  __shared__ bf16 Vs[64 * 72];
  __shared__ bf16 GsT[64 * 72];
  __shared__ bf16 UsT[64 * 72];
  __shared__ float Af[64 * 64];
  __shared__ float Bsc[64];
  bf16* const KTs = (bf16*)Af;
  const int ch = blockIdx.x;
  const int c = ch & (NCH - 1), bh = ch >> 5;
  const int h = bh & (NH - 1), b = bh >> 5;
  const int tid = threadIdx.x, wave = tid >> 6, lane = tid & 63;
  const size_t rowb = ((size_t)b * NT + c * 64) * ND + (size_t)h * 64;

  short8 ktA0, ktB0, ktA1, ktB1;
  if (wave >= 2) {
    const int d0a = (wave - 2) * 16, d0b = d0a + 32;
    ktA0 = *(const short8*)(k16 + rowb + (size_t)lane * ND + d0a);
    ktB0 = *(const short8*)(k16 + rowb + (size_t)lane * ND + d0a + 8);
    ktA1 = *(const short8*)(k16 + rowb + (size_t)lane * ND + d0b);
    ktB1 = *(const short8*)(k16 + rowb + (size_t)lane * ND + d0b + 8);
  }
  {
    const int r0 = tid >> 3, sc = (tid & 7) * 8;
    #pragma unroll
    for (int rnd = 0; rnd < 2; ++rnd) {
      const int r = rnd * 32 + r0;
      *(short8*)(Ks + r * 72 + sc) = *(const short8*)(k16 + rowb + (size_t)r * ND + sc);
      *(short8*)(Vs + r * 72 + sc) = *(const short8*)(v16 + rowb + (size_t)r * ND + sc);
    }
  }
  if (tid < 64) {
    const float x = __bfloat162float(betab[((size_t)b * NT + c * 64 + tid) * 256 + h])
                    + loadf(bb, h, *flag);
    Bsc[tid] = 1.f / (1.f + expf(-x));
  }
  __syncthreads();

  const int frow = lane & 15, fk = (lane >> 4) * 8, cm = (lane >> 4) * 4;
  {
    short8 ma0 = *(const short8*)(Ks + (16 * wave + frow) * 72 + fk);
    short8 ma1 = *(const short8*)(Ks + (16 * wave + frow) * 72 + 32 + fk);
    #pragma unroll
    for (int n = 0; n < 4; ++n) {
      f32x4 m = {};
      m = __builtin_amdgcn_mfma_f32_16x16x32_bf16(ma0, *(const short8*)(Ks + (16 * n + frow) * 72 + fk), m, 0, 0, 0);
      m = __builtin_amdgcn_mfma_f32_16x16x32_bf16(ma1, *(const short8*)(Ks + (16 * n + frow) * 72 + 32 + fk), m, 0, 0, 0);
      #pragma unroll
      for (int r = 0; r < 4; ++r) {
        const int t = 16 * wave + cm + r, s = 16 * n + frow;
        Af[t * 64 + s] = (s < t) ? Bsc[t] * m[r] : 0.f;
      }
    }
  }
  __syncthreads();

  if (wave < 2) {
    float u[64];
    #pragma unroll
    for (int i = 0; i < 64; ++i) u[i] = 0.f;
    const bf16* vsrc = wave ? Ks : Vs;
    bf16* outT = wave ? GsT : UsT;
    bf16* gout = Gneg + (size_t)ch * 4096;
    const float sgn = wave ? -1.f : 1.f;
    scan16<0>(Af, vsrc, Bsc, u, lane, wave, sgn, outT, gout);
    scan16<1>(Af, vsrc, Bsc, u, lane, wave, sgn, outT, gout);
    scan16<2>(Af, vsrc, Bsc, u, lane, wave, sgn, outT, gout);
    scan16<3>(Af, vsrc, Bsc, u, lane, wave, sgn, outT, gout);
  }
  __syncthreads();

  if (wave >= 2) {
    const int d0a = (wave - 2) * 16, d0b = d0a + 32;
    #pragma unroll
    for (int j = 0; j < 8; ++j) {
      KTs[(d0a + j) * 72 + lane]     = ((const bf16*)&ktA0)[j];
      KTs[(d0a + 8 + j) * 72 + lane] = ((const bf16*)&ktB0)[j];
      KTs[(d0b + j) * 72 + lane]     = ((const bf16*)&ktA1)[j];
      KTs[(d0b + 8 + j) * 72 + lane] = ((const bf16*)&ktB1)[j];
    }
  }
  __syncthreads();

  short8 ka0 = *(const short8*)(KTs + (16 * wave + frow) * 72 + fk);
  short8 ka1 = *(const short8*)(KTs + (16 * wave + frow) * 72 + 32 + fk);
  short8 uu0 = *(const short8*)(UsT + (16 * wave + frow) * 72 + fk);
  short8 uu1 = *(const short8*)(UsT + (16 * wave + frow) * 72 + 32 + fk);
  #pragma unroll
  for (int n = 0; n < 4; ++n) {
    f32x4 aA = {}, aD = {};
    aA = __builtin_amdgcn_mfma_f32_16x16x32_bf16(ka0, *(const short8*)(GsT + (16 * n + frow) * 72 + fk), aA, 0, 0, 0);
    aA = __builtin_amdgcn_mfma_f32_16x16x32_bf16(ka1, *(const short8*)(GsT + (16 * n + frow) * 72 + 32 + fk), aA, 0, 0, 0);
    aD = __builtin_amdgcn_mfma_f32_16x16x32_bf16(uu0, *(const short8*)(KTs + (16 * n + frow) * 72 + fk), aD, 0, 0, 0);
    aD = __builtin_amdgcn_mfma_f32_16x16x32_bf16(uu1, *(const short8*)(KTs + (16 * n + frow) * 72 + 32 + fk), aD, 0, 0, 0);
    #pragma unroll
    for (int r = 0; r < 4; ++r) {
      Vs[(16 * wave + cm + r) * 64 + 16 * n + frow] = __float2bfloat16(aA[r]);
      Ks[(16 * wave + cm + r) * 64 + 16 * n + frow] = __float2bfloat16(aD[r]);
    }
  }
  __syncthreads();
  {
    const int r0 = tid >> 2, sc2 = (tid & 3) * 16;
    bf16* acg = AcT + (size_t)ch * 4096;
    bf16* dcg = Dc  + (size_t)ch * 4096;
    *(short8*)(acg + r0 * 64 + sc2)     = *(const short8*)(Vs + r0 * 64 + sc2);
    *(short8*)(acg + r0 * 64 + sc2 + 8) = *(const short8*)(Vs + r0 * 64 + sc2 + 8);
    *(short8*)(dcg + r0 * 64 + sc2)     = *(const short8*)(Ks + r0 * 64 + sc2);
    *(short8*)(dcg + r0 * 64 + sc2 + 8) = *(const short8*)(Ks + r0 * 64 + sc2 + 8);
    *(short8*)(v16 + rowb + (size_t)r0 * ND + sc2)     = *(const short8*)(UsT + r0 * 72 + sc2);
    *(short8*)(v16 + rowb + (size_t)r0 * ND + sc2 + 8) = *(const short8*)(UsT + r0 * 72 + sc2 + 8);
  }
}

// pass 2: minimal serial recurrence: sacc(fp32) += S_bf16 @ AcT^T + Dc, per chunk.
__global__ __launch_bounds__(256) void state_seq(const bf16* __restrict__ AcT,
                                                 const bf16* __restrict__ Dc,
                                                 bf16* __restrict__ Sbuf) {
  __shared__ bf16 ST[64 * 72];
  const int bh = blockIdx.x;
  const int wave = threadIdx.x >> 6, lane = threadIdx.x & 63;
  const int frow = lane & 15, fk = (lane >> 4) * 8, cm = (lane >> 4) * 4;
  for (int i = threadIdx.x; i < 64 * 72 / 2; i += 256) ((unsigned int*)ST)[i] = 0u;
  f32x4 sacc[4] = {};
  const bf16* ac = AcT + (size_t)bh * NCH * 4096;
  const bf16* dc = Dc  + (size_t)bh * NCH * 4096;
  bf16* sb = Sbuf + (size_t)bh * NCH * 4096;
  #pragma unroll
  for (int n = 0; n < 4; ++n)
    #pragma unroll
    for (int r = 0; r < 4; ++r)
      sb[(16 * wave + cm + r) * 64 + 16 * n + frow] = __float2bfloat16(0.f);
  short8 bpre[4][2];
  float dpre[16];
  #pragma unroll
  for (int n = 0; n < 4; ++n) {
    bpre[n][0] = *(const short8*)(ac + (16 * n + frow) * 64 + fk);
    bpre[n][1] = *(const short8*)(ac + (16 * n + frow) * 64 + 32 + fk);
    #pragma unroll
    for (int r = 0; r < 4; ++r)
      dpre[n * 4 + r] = __bfloat162float(dc[(16 * wave + cm + r) * 64 + 16 * n + frow]);
  }
  __syncthreads();
  #pragma unroll 1
  for (int c = 0; c < NCH; ++c) {
    short8 a0 = *(const short8*)(ST + (16 * wave + frow) * 72 + fk);
    short8 a1 = *(const short8*)(ST + (16 * wave + frow) * 72 + 32 + fk);
    short8 bcur[4][2];
    float dcur[16];
    #pragma unroll
    for (int n = 0; n < 4; ++n) {
      bcur[n][0] = bpre[n][0]; bcur[n][1] = bpre[n][1];
      #pragma unroll
      for (int r = 0; r < 4; ++r) dcur[n * 4 + r] = dpre[n * 4 + r];
    }
    if (c + 1 < NCH) {
      const bf16* acn = ac + (size_t)(c + 1) * 4096;
      const bf16* dcn = dc + (size_t)(c + 1) * 4096;
      #pragma unroll
      for (int n = 0; n < 4; ++n) {
        bpre[n][0] = *(const short8*)(acn + (16 * n + frow) * 64 + fk);
        bpre[n][1] = *(const short8*)(acn + (16 * n + frow) * 64 + 32 + fk);
        #pragma unroll
        for (int r = 0; r < 4; ++r)
          dpre[n * 4 + r] = __bfloat162float(dcn[(16 * wave + cm + r) * 64 + 16 * n + frow]);
      }
    }
    #pragma unroll
    for (int n = 0; n < 4; ++n) {
      sacc[n] = __builtin_amdgcn_mfma_f32_16x16x32_bf16(a0, bcur[n][0], sacc[n], 0, 0, 0);
      sacc[n] = __builtin_amdgcn_mfma_f32_16x16x32_bf16(a1, bcur[n][1], sacc[n], 0, 0, 0);
      #pragma unroll
      for (int r = 0; r < 4; ++r) sacc[n][r] += dcur[n * 4 + r];
    }
    __syncthreads();
    #pragma unroll
    for (int n = 0; n < 4; ++n)
      #pragma unroll
      for (int r = 0; r < 4; ++r) {
        const bf16 sv = __float2bfloat16(sacc[n][r]);
        ST[(16 * wave + cm + r) * 72 + 16 * n + frow] = sv;
        if (c + 1 < NCH)
          sb[(size_t)(c + 1) * 4096 + (16 * wave + cm + r) * 64 + 16 * n + frow] = sv;
      }
    __syncthreads();
  }
}

// pass 3: chunk-parallel outputs. O = Q*S_c + tril(QK^T)*U_c, in place over q16.
__global__ __launch_bounds__(256) void chunk_out(bf16* __restrict__ q16,
                                                 const bf16* __restrict__ k16,
                                                 const bf16* __restrict__ v16,
                                                 const bf16* __restrict__ Gneg,
                                                 const bf16* __restrict__ Sbuf) {
  __shared__ bf16 UTs[64 * 72];
  __shared__ bf16 Pt[64 * 72];
  const int ch = blockIdx.x;
  const int c = ch & (NCH - 1), bh = ch >> 5;
  const int h = bh & (NH - 1), b = bh >> 5;
  const int tid = threadIdx.x, wave = tid >> 6, lane = tid & 63;
  const int frow = lane & 15, fk = (lane >> 4) * 8, cm = (lane >> 4) * 4;
  const size_t qkb = ((size_t)b * NT + c * 64) * ND + (size_t)h * 64;
  const bf16* Sb = Sbuf + (size_t)ch * 4096;
  const bf16* Gc = Gneg + (size_t)ch * 4096;
  {
    const int r0 = tid >> 2, sc2 = (tid & 3) * 16;
    *(short8*)(UTs + r0 * 72 + sc2)     = *(const short8*)(v16 + qkb + (size_t)r0 * ND + sc2);
    *(short8*)(UTs + r0 * 72 + sc2 + 8) = *(const short8*)(v16 + qkb + (size_t)r0 * ND + sc2 + 8);
  }
  short8 qa0 = *(const short8*)(q16 + qkb + (size_t)(16 * wave + frow) * ND + fk);
  short8 qa1 = *(const short8*)(q16 + qkb + (size_t)(16 * wave + frow) * ND + 32 + fk);
  f32x4 pacc[4];
  #pragma unroll
  for (int n = 0; n < 4; ++n) {
    f32x4 a = {};
    a = __builtin_amdgcn_mfma_f32_16x16x32_bf16(qa0, *(const short8*)(k16 + qkb + (size_t)(16 * n + frow) * ND + fk), a, 0, 0, 0);
    a = __builtin_amdgcn_mfma_f32_16x16x32_bf16(qa1, *(const short8*)(k16 + qkb + (size_t)(16 * n + frow) * ND + 32 + fk), a, 0, 0, 0);
    pacc[n] = a;
  }
  __syncthreads();
  f32x4 uacc[4];
  #pragma unroll
  for (int n = 0; n < 4; ++n)
    #pragma unroll
    for (int r = 0; r < 4; ++r)
      uacc[n][r] = __bfloat162float(UTs[(16 * wave + cm + r) * 72 + 16 * n + frow]);
  #pragma unroll
  for (int n = 0; n < 4; ++n)
    #pragma unroll
    for (int r = 0; r < 4; ++r) {
      const int mg = 16 * wave + cm + r, ng = 16 * n + frow;
      Pt[mg * 72 + ng] = __float2bfloat16(ng <= mg ? pacc[n][r] : 0.f);
    }
  short8 sa0 = *(const short8*)(Sb + (16 * wave + frow) * 64 + fk);
  short8 sa1 = *(const short8*)(Sb + (16 * wave + frow) * 64 + 32 + fk);
  #pragma unroll
  for (int n = 0; n < 4; ++n) {
    uacc[n] = __builtin_amdgcn_mfma_f32_16x16x32_bf16(sa0, *(const short8*)(Gc + (16 * n + frow) * 64 + fk), uacc[n], 0, 0, 0);
    uacc[n] = __builtin_amdgcn_mfma_f32_16x16x32_bf16(sa1, *(const short8*)(Gc + (16 * n + frow) * 64 + 32 + fk), uacc[n], 0, 0, 0);
  }
  __syncthreads();
  #pragma unroll
  for (int n = 0; n < 4; ++n)
    #pragma unroll
    for (int r = 0; r < 4; ++r)
      UTs[(16 * wave + cm + r) * 72 + 16 * n + frow] = __float2bfloat16(uacc[n][r]);
  __syncthreads();
  short8 pa0 = *(const short8*)(Pt + (16 * wave + frow) * 72 + fk);
  short8 pa1 = *(const short8*)(Pt + (16 * wave + frow) * 72 + 32 + fk);
  #pragma unroll
  for (int n = 0; n < 4; ++n) {
    f32x4 o = {};
    o = __builtin_amdgcn_mfma_f32_16x16x32_bf16(qa0, *(const short8*)(Sb + (16 * n + frow) * 64 + fk), o, 0, 0, 0);
    o = __builtin_amdgcn_mfma_f32_16x16x32_bf16(qa1, *(const short8*)(Sb + (16 * n + frow) * 64 + 32 + fk), o, 0, 0, 0);
    o = __builtin_amdgcn_mfma_f32_16x16x32_bf16(pa0, *(const short8*)(UTs + (16 * n + frow) * 72 + fk), o, 0, 0, 0);
    o = __builtin_amdgcn_mfma_f32_16x16x32_bf16(pa1, *(const short8*)(UTs + (16 * n + frow) * 72 + 32 + fk), o, 0, 0, 0);
    #pragma unroll
    for (int r = 0; r < 4; ++r)
      q16[qkb + (size_t)(16 * wave + cm + r) * ND + 16 * n + frow] = __float2bfloat16(o[r]);
  }
}

// ======================= compact-fallback chunk kernels (round-4 proven) =======================

__global__ __launch_bounds__(128) void chunk_scan_c(const bf16* __restrict__ k16,
                                                    bf16* __restrict__ v16,
                                                    const bf16* __restrict__ betab,
                                                    const void* __restrict__ bb,
                                                    const int* __restrict__ flag,
                                                    bf16* __restrict__ Gneg) {
  __shared__ bf16 Ks[64 * 64];
  __shared__ bf16 Vs[64 * 64];
  __shared__ bf16 Gs[64 * 64];
  __shared__ float Bs[64];
  const int ch = blockIdx.x;
  const int c = ch & (NCH - 1), bh = ch >> 5;
  const int h = bh & (NH - 1), b = bh >> 5;
  const int tid = threadIdx.x;
  const int wave = tid >> 6, lane = tid & 63;
  const size_t rowb = ((size_t)b * NT + c * 64) * ND + (size_t)h * 64;
  const int sr = tid >> 3, sc = (tid & 7) * 8;
  #pragma unroll
  for (int rnd = 0; rnd < 4; ++rnd) {
    const int r = rnd * 16 + sr;
    *(short8*)(Ks + r * 64 + sc) = *(const short8*)(k16 + rowb + (size_t)r * ND + sc);
    *(short8*)(Vs + r * 64 + sc) = *(const short8*)(v16 + rowb + (size_t)r * ND + sc);
  }
  if (tid < 64) {
    const float x = __bfloat162float(betab[((size_t)b * NT + c * 64 + tid) * 128 + h])
                    + loadf(bb, h, *flag);
    Bs[tid] = 1.f / (1.f + expf(-x));
  }
  __syncthreads();
  float S[64];
  #pragma unroll
  for (int i = 0; i < 64; ++i) S[i] = 0.f;
  const bf16* val_src = wave ? Ks : Vs;
  #pragma unroll 1
  for (int t = 0; t < 64; ++t) {
    uint4 ku[8];
    #pragma unroll
    for (int i = 0; i < 8; ++i) ku[i] = ((const uint4*)(Ks + t * 64))[i];
    const float val = __bfloat162float(val_src[t * 64 + lane]);
    const float bt = Bs[t];
    float kvf[64];
    #pragma unroll
    for (int i = 0; i < 8; ++i) {
      kvf[8*i+0] = __uint_as_float(ku[i].x << 16);
      kvf[8*i+1] = __uint_as_float(ku[i].x & 0xffff0000u);
      kvf[8*i+2] = __uint_as_float(ku[i].y << 16);
      kvf[8*i+3] = __uint_as_float(ku[i].y & 0xffff0000u);
      kvf[8*i+4] = __uint_as_float(ku[i].z << 16);
      kvf[8*i+5] = __uint_as_float(ku[i].z & 0xffff0000u);
      kvf[8*i+6] = __uint_as_float(ku[i].w << 16);
      kvf[8*i+7] = __uint_as_float(ku[i].w & 0xffff0000u);
    }
    float p0 = 0, p1 = 0, p2 = 0, p3 = 0;
    #pragma unroll
    for (int i = 0; i < 16; ++i) {
      p0 += kvf[4*i+0] * S[4*i+0];
      p1 += kvf[4*i+1] * S[4*i+1];
      p2 += kvf[4*i+2] * S[4*i+2];
      p3 += kvf[4*i+3] * S[4*i+3];
    }
    const float u = bt * (val - ((p0 + p1) + (p2 + p3)));
    #pragma unroll
    for (int i = 0; i < 16; ++i) {
      S[4*i+0] += kvf[4*i+0] * u;
      S[4*i+1] += kvf[4*i+1] * u;
      S[4*i+2] += kvf[4*i+2] * u;
      S[4*i+3] += kvf[4*i+3] * u;
    }
    if (wave) Gs[t * 64 + lane] = __float2bfloat16(-u);
    else      Vs[t * 64 + lane] = __float2bfloat16(u);
  }
  __syncthreads();
  bf16* gout = Gneg + (size_t)ch * 4096;
  #pragma unroll
  for (int rnd = 0; rnd < 4; ++rnd) {
    const int r = rnd * 16 + sr;
    *(short8*)(v16 + rowb + (size_t)r * ND + sc) = *(const short8*)(Vs + r * 64 + sc);
    *(short8*)(gout + r * 64 + sc)               = *(const short8*)(Gs + r * 64 + sc);
  }
}

__global__ __launch_bounds__(256) void chunk_seq_mono(bf16* q16,
                                                      const bf16* __restrict__ k16,
                                                      const bf16* __restrict__ Ul,
                                                      const bf16* __restrict__ Gneg) {
  __shared__ bf16 ST[64 * 72];
  __shared__ bf16 Ubt[64 * 72];
  __shared__ bf16 Pt[64 * 72];
  __shared__ bf16 KTl[64 * 72];
  const int bh = blockIdx.x, h = bh & (NH - 1), b = bh >> 5;
  const int wave = threadIdx.x >> 6, lane = threadIdx.x & 63;
  const int frow = lane & 15, q4 = lane >> 4, fk = q4 * 8;
  const int cm = q4 * 4;
  for (int i = threadIdx.x; i < 64 * 72 / 2; i += 256) ((unsigned int*)ST)[i] = 0u;
  __syncthreads();
  f32x4 sacc[4] = {};
  #pragma unroll 1
  for (int c = 0; c < NCH; ++c) {
    const bf16* Gc = Gneg + ((size_t)bh * NCH + c) * 4096;
    const size_t qkb = ((size_t)b * NT + c * 64) * ND + (size_t)h * 64;
    {
      short8 r0 = *(const short8*)(k16 + qkb + (size_t)lane * ND + 16 * wave);
      short8 r1 = *(const short8*)(k16 + qkb + (size_t)lane * ND + 16 * wave + 8);
      #pragma unroll
      for (int j = 0; j < 8; ++j) {
        KTl[(16 * wave + j) * 72 + lane]     = ((const bf16*)&r0)[j];
        KTl[(16 * wave + 8 + j) * 72 + lane] = ((const bf16*)&r1)[j];
      }
    }
    short8 ga0 = *(const short8*)(Gc + (16 * wave + frow) * 64 + fk);
    short8 ga1 = *(const short8*)(Gc + (16 * wave + frow) * 64 + 32 + fk);
    #pragma unroll
    for (int n = 0; n < 4; ++n) {
      f32x4 acc;
      #pragma unroll
      for (int r = 0; r < 4; ++r)
        acc[r] = __bfloat162float(Ul[qkb + (size_t)(16 * wave + cm + r) * ND + 16 * n + frow]);
      acc = __builtin_amdgcn_mfma_f32_16x16x32_bf16(ga0, *(const short8*)(ST + (16 * n + frow) * 72 + fk), acc, 0, 0, 0);
      acc = __builtin_amdgcn_mfma_f32_16x16x32_bf16(ga1, *(const short8*)(ST + (16 * n + frow) * 72 + 32 + fk), acc, 0, 0, 0);
      #pragma unroll
      for (int r = 0; r < 4; ++r)
        Ubt[(16 * n + frow) * 72 + 16 * wave + cm + r] = __float2bfloat16(acc[r]);
    }
    __syncthreads();
    short8 qa0 = *(const short8*)(q16 + qkb + (size_t)(16 * wave + frow) * ND + fk);
    short8 qa1 = *(const short8*)(q16 + qkb + (size_t)(16 * wave + frow) * ND + 32 + fk);
    #pragma unroll
    for (int n = 0; n < 4; ++n) {
      f32x4 acc = {};
      acc = __builtin_amdgcn_mfma_f32_16x16x32_bf16(qa0, *(const short8*)(k16 + qkb + (size_t)(16 * n + frow) * ND + fk), acc, 0, 0, 0);
      acc = __builtin_amdgcn_mfma_f32_16x16x32_bf16(qa1, *(const short8*)(k16 + qkb + (size_t)(16 * n + frow) * ND + 32 + fk), acc, 0, 0, 0);
      #pragma unroll
      for (int r = 0; r < 4; ++r) {
        const int mg = 16 * wave + cm + r, ng = 16 * n + frow;
        Pt[mg * 72 + ng] = __float2bfloat16(ng <= mg ? acc[r] : 0.f);
      }
    }
    __syncthreads();
    short8 pa0 = *(const short8*)(Pt + (16 * wave + frow) * 72 + fk);
    short8 pa1 = *(const short8*)(Pt + (16 * wave + frow) * 72 + 32 + fk);
    #pragma unroll
    for (int n = 0; n < 4; ++n) {
      f32x4 acc = {};
      acc = __builtin_amdgcn_mfma_f32_16x16x32_bf16(qa0, *(const short8*)(ST + (16 * n + frow) * 72 + fk), acc, 0, 0, 0);
      acc = __builtin_amdgcn_mfma_f32_16x16x32_bf16(qa1, *(const short8*)(ST + (16 * n + frow) * 72 + 32 + fk), acc, 0, 0, 0);
      acc = __builtin_amdgcn_mfma_f32_16x16x32_bf16(pa0, *(const short8*)(Ubt + (16 * n + frow) * 72 + fk), acc, 0, 0, 0);
      acc = __builtin_amdgcn_mfma_f32_16x16x32_bf16(pa1, *(const short8*)(Ubt + (16 * n + frow) * 72 + 32 + fk), acc, 0, 0, 0);
      #pragma unroll
      for (int r = 0; r < 4; ++r)
        q16[qkb + (size_t)(16 * wave + cm + r) * ND + 16 * n + frow] = __float2bfloat16(acc[r]);
    }
    __syncthreads();
    short8 ua0 = *(const short8*)(Ubt + (16 * wave + frow) * 72 + fk);
    short8 ua1 = *(const short8*)(Ubt + (16 * wave + frow) * 72 + 32 + fk);
    #pragma unroll
    for (int n = 0; n < 4; ++n) {
      sacc[n] = __builtin_amdgcn_mfma_f32_16x16x32_bf16(ua0, *(const short8*)(KTl + (16 * n + frow) * 72 + fk), sacc[n], 0, 0, 0);
      sacc[n] = __builtin_amdgcn_mfma_f32_16x16x32_bf16(ua1, *(const short8*)(KTl + (16 * n + frow) * 72 + 32 + fk), sacc[n], 0, 0, 0);
      #pragma unroll
      for (int r = 0; r < 4; ++r)
        ST[(16 * wave + cm + r) * 72 + 16 * n + frow] = __float2bfloat16(sacc[n][r]);
    }
    __syncthreads();
  }
}

extern "C" void kernel_launch(void* const* d_in, const int* in_sizes, int n_in,
                              void* d_out, int out_size, void* d_ws, size_t ws_size,
                              hipStream_t stream) {
  const void* hs = d_in[0];
  const void* Wq = d_in[1];
  const void* Wk = d_in[2];
  const void* Wv = d_in[3];
  const void* Wb = d_in[4];
  const void* bb = d_in[5];
  const void* Wo = d_in[6];

  char* ws = (char*)d_ws;
  size_t off = 0;
  auto alloc = [&](size_t bytes) {
    void* p = ws + off;
    off += (bytes + 255) & ~(size_t)255;
    return p;
  };
  const size_t szW2 = (size_t)32 * 1024 * 1024;  // WT (26.2 MiB weights) + AcT alias region
  const size_t szM  = (size_t)NM * ND * 2;       // 16 MiB
  const size_t szB2 = (size_t)NM * 256 * 2;      // 2 MiB (beta logits, 256-padded)
  const size_t szB  = (size_t)NM * 128 * 2;      // fallback beta (128-padded)
  const size_t need_fused = 512 + szW2 + 4 * szM + szB2 + szM;   // ~119.6 MB

  if (ws_size >= need_fused) {
    // ---- fused path ----
    int*  flag  = (int*) alloc(256);
    bf16* WT    = (bf16*)alloc(szW2);  // weights [0,26.2Mi); later Gneg [0,16Mi) + AcT [16,32Mi)
    bf16* hs16  = (bf16*)alloc(szM);   // -> Sbuf after fused GEMM
    bf16* q16   = (bf16*)alloc(szM);   // O in place
    bf16* k16   = (bf16*)alloc(szM);
    bf16* v16   = (bf16*)alloc(szM);   // U^T (transposed-in-place)
    bf16* betab = (bf16*)alloc(szB2);
    bf16* Dc    = (bf16*)alloc(szM);
    bf16* Gneg  = WT;                                    // [0,16MiB) dead after fused GEMM
    bf16* AcT   = WT + (size_t)8 * 1024 * 1024;          // [16,32MiB)
    bf16* WoT   = AcT;                                   // reused after state_seq
    bf16* Sbuf  = hs16;

    detect_dtype<<<1, 64, 0, stream>>>((const unsigned short*)hs, flag);
    convert_bf16<<<(NM * ND) / (256 * 8), 256, 0, stream>>>(hs, hs16, (long)NM * ND, flag);

    transpose_qkvb<<<dim3(32, 32, 4), 256, 0, stream>>>(Wq, Wk, Wv, Wb, WT, flag);
    gemm256<<<400, 512, 0, stream>>>(hs16, WT, q16, k16, v16, betab,
                                     nullptr, nullptr, ND, 25);

    chunk_scan<<<NB * NH * NCH, 256, 0, stream>>>(k16, v16, betab, bb, flag, Gneg, AcT, Dc);
    state_seq<<<NB * NH, 256, 0, stream>>>(AcT, Dc, Sbuf);
    chunk_out<<<NB * NH * NCH, 256, 0, stream>>>(q16, k16, v16, Gneg, Sbuf);

    transpose_cvt<<<dim3(32, 32), 256, 0, stream>>>(Wo, WoT, 2048, 2048, flag);
    gemm_bt<<<dim3(16, 32), 256, 0, stream>>>(q16, WoT, nullptr, nullptr, nullptr, nullptr,
                                              d_out, flag, NM, ND, 0);
  } else {
    // ---- compact fallback (proven ~73 MB footprint) ----
    int*  flag  = (int*) alloc(256);
    bf16* Wt    = (bf16*)alloc((size_t)2048 * 2048 * 2);
    bf16* hs16  = (bf16*)alloc(szM);   // -> Gneg
    bf16* q16   = (bf16*)alloc(szM);
    bf16* k16   = (bf16*)alloc(szM);
    bf16* v16   = (bf16*)alloc(szM);
    bf16* betab = (bf16*)alloc(szB);
    bf16* Gneg  = hs16;

    detect_dtype<<<1, 64, 0, stream>>>((const unsigned short*)hs, flag);
    convert_bf16<<<(NM * ND) / (256 * 8), 256, 0, stream>>>(hs, hs16, (long)NM * ND, flag);

    transpose_cvt<<<dim3(32, 32), 256, 0, stream>>>(Wq, Wt, 2048, 2048, flag);
    gemm_bt<<<dim3(16, 32), 256, 0, stream>>>(hs16, Wt, q16, k16, v16, betab, nullptr, nullptr, NM, ND, 0);
    transpose_cvt<<<dim3(32, 32), 256, 0, stream>>>(Wk, Wt, 2048, 2048, flag);
    gemm_bt<<<dim3(16, 32), 256, 0, stream>>>(hs16, Wt, q16, k16, v16, betab, nullptr, nullptr, NM, ND, 2048);
    transpose_cvt<<<dim3(32, 32), 256, 0, stream>>>(Wv, Wt, 2048, 2048, flag);
    gemm_bt<<<dim3(16, 32), 256, 0, stream>>>(hs16, Wt, q16, k16, v16, betab, nullptr, nullptr, NM, ND, 4096);
    transpose_cvt<<<dim3(2, 32),  256, 0, stream>>>(Wb, Wt, 2048, 32, flag);
    gemm_bt<<<dim3(1, 32), 256, 0, stream>>>(hs16, Wt, q16, k16, v16, betab, nullptr, nullptr, NM, ND, 6144);

    chunk_scan_c<<<NB * NH * NCH, 128, 0, stream>>>(k16, v16, betab, bb, flag, Gneg);
    chunk_seq_mono<<<NB * NH, 256, 0, stream>>>(q16, k16, v16, Gneg);

    transpose_cvt<<<dim3(32, 32), 256, 0, stream>>>(Wo, Wt, 2048, 2048, flag);
    gemm_bt<<<dim3(16, 32), 256, 0, stream>>>(q16, Wt, nullptr, nullptr, nullptr, nullptr,
                                              d_out, flag, NM, ND, 0);
  }
}

// Round 6
// 552.351 us; speedup vs baseline: 1.0657x; 1.0283x over previous
//
#include <hip/hip_runtime.h>
#include <hip/hip_bf16.h>

typedef __hip_bfloat16 bf16;
typedef __attribute__((ext_vector_type(8))) short short8;   // 8 bf16 (4 VGPRs)
typedef __attribute__((ext_vector_type(4))) float f32x4;

#define NB 2
#define NT 2048
#define ND 2048
#define NH 32
#define NM (NB*NT)   // 4096 rows
#define NCH 32       // chunks per (b,h): NT/64

// ---- dtype hedge: inputs may be bf16 (harness-converted) or fp32 (per reference) ----
__global__ void detect_dtype(const unsigned short* __restrict__ hs, int* __restrict__ flag) {
  if (threadIdx.x == 0 && blockIdx.x == 0) {
    int cnt = 0;
    for (int i = 0; i < 2048; i += 2) {
      int e = (hs[i] >> 7) & 0xFF;
      if (e >= 141) ++cnt;
    }
    *flag = (cnt > 64) ? 1 : 0;   // 1 = fp32, 0 = bf16
  }
}

__device__ __forceinline__ float loadf(const void* p, size_t i, int isf32) {
  return isf32 ? ((const float*)p)[i] : __bfloat162float(((const bf16*)p)[i]);
}

__global__ __launch_bounds__(256) void convert_bf16(const void* __restrict__ src,
                                                    bf16* __restrict__ dst,
                                                    long n, const int* __restrict__ flag) {
  const long i0 = ((long)blockIdx.x * 256 + threadIdx.x) * 8;
  if (i0 >= n) return;
  if (*flag) {
    const float* s = (const float*)src;
    #pragma unroll
    for (int j = 0; j < 8; ++j) dst[i0 + j] = __float2bfloat16(s[i0 + j]);
  } else {
    *(short8*)(dst + i0) = *(const short8*)((const bf16*)src + i0);
  }
}

// ---- transpose + convert one matrix: dst[c][r] = bf16(src[r][c]); zero-pad cols ----
__global__ __launch_bounds__(256) void transpose_cvt(const void* __restrict__ src,
                                                     bf16* __restrict__ dst,
                                                     int src_rows, int src_cols,
                                                     const int* __restrict__ flag) {
  __shared__ bf16 tile[64][65];
  const int f = *flag;
  const int tb_r = blockIdx.y * 64, tb_c = blockIdx.x * 64;
  const int tx = threadIdx.x & 63, ty = threadIdx.x >> 6;
  #pragma unroll
  for (int i = 0; i < 64; i += 4) {
    const int cc = tb_c + tx;
    tile[i + ty][tx] = (cc < src_cols)
      ? __float2bfloat16(loadf(src, (size_t)(tb_r + i + ty) * src_cols + cc, f))
      : __float2bfloat16(0.f);
  }
  __syncthreads();
  #pragma unroll
  for (int i = 0; i < 64; i += 4)
    dst[(size_t)(tb_c + i + ty) * src_rows + tb_r + tx] = tile[tx][i + ty];
}

// ---- merged transpose of Wq/Wk/Wv/Wb into WT, z-sliced (beta block padded to 256 rows) ----
__global__ __launch_bounds__(256) void transpose_qkvb(const void* __restrict__ Wq,
                                                      const void* __restrict__ Wk,
                                                      const void* __restrict__ Wv,
                                                      const void* __restrict__ Wb,
                                                      bf16* __restrict__ WT,
                                                      const int* __restrict__ flag) {
  __shared__ bf16 tile[64][65];
  const int z = blockIdx.z;
  if (z == 3 && blockIdx.x >= 4) return;   // Wb^T: 256 padded rows
  const void* src = (z == 0) ? Wq : (z == 1) ? Wk : (z == 2) ? Wv : Wb;
  const int src_cols = (z == 3) ? 32 : 2048;
  bf16* dst = WT + (size_t)z * 2048 * 2048;
  const int f = *flag;
  const int tb_r = blockIdx.y * 64, tb_c = blockIdx.x * 64;
  const int tx = threadIdx.x & 63, ty = threadIdx.x >> 6;
  #pragma unroll
  for (int i = 0; i < 64; i += 4) {
    const int cc = tb_c + tx;
    tile[i + ty][tx] = (cc < src_cols)
      ? __float2bfloat16(loadf(src, (size_t)(tb_r + i + ty) * src_cols + cc, f))
      : __float2bfloat16(0.f);
  }
  __syncthreads();
  #pragma unroll
  for (int i = 0; i < 64; i += 4)
    dst[(size_t)(tb_c + i + ty) * 2048 + tb_r + tx] = tile[tx][i + ty];
}

// async 16B/lane global->LDS (wave-uniform LDS base + lane*16)
__device__ __forceinline__ void gload_lds16(const void* g, void* l) {
  __builtin_amdgcn_global_load_lds((__attribute__((address_space(1))) const void*)g,
                                   (__attribute__((address_space(3))) void*)l,
                                   16, 0, 0);
}

// ------------- legacy GEMM (fallback path only): C = A @ Bt^T -------------
__global__ __launch_bounds__(256) void gemm_bt(const bf16* __restrict__ A,
                                               const bf16* __restrict__ Bt,
                                               bf16* __restrict__ oq, bf16* __restrict__ ok2,
                                               bf16* __restrict__ ov, bf16* __restrict__ ob,
                                               void* __restrict__ outv,
                                               const int* __restrict__ outflag,
                                               int M, int K, int n_base) {
  __shared__ bf16 As[128 * 32];
  __shared__ bf16 Bs[128 * 32];
  const int tid = threadIdx.x;
  const int wave = tid >> 6, lane = tid & 63;
  const int m0 = blockIdx.y * 128, n0 = blockIdx.x * 128;
  const int wm = (wave >> 1) * 64, wn = (wave & 1) * 64;
  const int srow = lane >> 2, scol = (lane & 3) * 8;
  const int frow = lane & 15, fk = (lane >> 4) * 8;
  f32x4 acc[4][4] = {};

  for (int kb = 0; kb < K; kb += 32) {
    __syncthreads();
    #pragma unroll
    for (int j = 0; j < 2; ++j) {
      const int rbase = wave * 32 + j * 16;
      gload_lds16(A  + (size_t)(m0 + rbase + srow) * K + kb + scol, As + rbase * 32);
      gload_lds16(Bt + (size_t)(n0 + rbase + srow) * K + kb + scol, Bs + rbase * 32);
    }
    __syncthreads();
    short8 af[4], bfr[4];
    #pragma unroll
    for (int i = 0; i < 4; ++i)
      af[i] = *(const short8*)(As + (wm + i * 16 + frow) * 32 + fk);
    #pragma unroll
    for (int i = 0; i < 4; ++i)
      bfr[i] = *(const short8*)(Bs + (wn + i * 16 + frow) * 32 + fk);
    #pragma unroll
    for (int mi = 0; mi < 4; ++mi)
      #pragma unroll
      for (int ni = 0; ni < 4; ++ni)
        acc[mi][ni] = __builtin_amdgcn_mfma_f32_16x16x32_bf16(af[mi], bfr[ni], acc[mi][ni], 0, 0, 0);
  }

  const int crow = (lane >> 4) * 4, ccol = lane & 15;
  const int gn0 = n_base + n0;
  if (outflag) {
    const int f = *outflag;
    #pragma unroll
    for (int mi = 0; mi < 4; ++mi)
      #pragma unroll
      for (int ni = 0; ni < 4; ++ni)
        #pragma unroll
        for (int r = 0; r < 4; ++r) {
          const size_t idx = (size_t)(m0 + wm + mi * 16 + crow + r) * 2048 + gn0 + wn + ni * 16 + ccol;
          const float val = acc[mi][ni][r];
          if (f == 1) ((float*)outv)[idx] = val;
          else        ((bf16*)outv)[idx] = __float2bfloat16(val);
        }
  } else {
    const int seg = gn0 >> 11;
    bf16* o = (seg == 0) ? oq : (seg == 1) ? ok2 : (seg == 2) ? ov : ob;
    const int stride = (seg < 3) ? 2048 : 128;
    const int cb = (gn0 & 2047) + wn;
    if (seg <= 1) {
      #pragma unroll
      for (int mi = 0; mi < 4; ++mi)
        #pragma unroll
        for (int r = 0; r < 4; ++r) {
          float s = acc[mi][0][r] * acc[mi][0][r] + acc[mi][1][r] * acc[mi][1][r]
                  + acc[mi][2][r] * acc[mi][2][r] + acc[mi][3][r] * acc[mi][3][r];
          s += __shfl_xor(s, 1, 64); s += __shfl_xor(s, 2, 64);
          s += __shfl_xor(s, 4, 64); s += __shfl_xor(s, 8, 64);
          const float inv = rsqrtf(s + 1e-6f);
          #pragma unroll
          for (int ni = 0; ni < 4; ++ni) acc[mi][ni][r] *= inv;
        }
    }
    #pragma unroll
    for (int mi = 0; mi < 4; ++mi)
      #pragma unroll
      for (int ni = 0; ni < 4; ++ni)
        #pragma unroll
        for (int r = 0; r < 4; ++r)
          o[(size_t)(m0 + wm + mi * 16 + crow + r) * stride + cb + ni * 16 + ccol] =
            __float2bfloat16(acc[mi][ni][r]);
  }
}

// ============ 128x256 GEMM, 2 blocks/CU (occupancy-overlap variant) ============
// C = A[M][K] @ Bt[N][K]^T. 8 waves (2M x 4N), per-wave output 64x64 (acc = 64 regs),
// BK=32, double-buffered LDS = 48 KB, __launch_bounds__(512,4) caps regs at 128 ->
// 2 INDEPENDENT blocks per CU. K-loop is the minimal double-buffered form (one
// __syncthreads per tile); all latency hiding comes from cross-block overlap (m97/m114).
// 2-bit both-sides LDS swizzle: byte ^= ((byte>>6)&3)<<4 (4 slots per 64B row) reduces
// the 16-row fragment read from 8-way to 4-way bank aliasing.
__global__ __launch_bounds__(512, 4) void gemm128(const bf16* __restrict__ A,
                                                  const bf16* __restrict__ Bt,
                                                  bf16* __restrict__ oq, bf16* __restrict__ ok2,
                                                  bf16* __restrict__ ov, bf16* __restrict__ ob,
                                                  void* __restrict__ outv,
                                                  const int* __restrict__ outflag,
                                                  int K, int ntn) {
  __shared__ __align__(16) bf16 LA[2][128 * 32];   // 2 x 8 KB
  __shared__ __align__(16) bf16 LB[2][256 * 32];   // 2 x 16 KB
  const int tid = threadIdx.x;
  const int wave = tid >> 6, lane = tid & 63;
  const int wm = wave >> 2, wn = wave & 3;          // 2M x 4N
  const int frow = lane & 15, fq = lane >> 4;
  // ---- tile mapping ----
  int mtile, ntile;
  if (ntn == 25) {
    // supertile XCD mapping for the 32x25 grid (800 blocks; bijective, verified):
    // XCDs = 2 m-groups(16 mtiles) x 4 n-groups (widths 7,6,6,6; nb0 = 0,7,13,19).
    // ng==0 region has 112 slots: 100 own + 12 overflow from ng>0 groups.
    const int x = (int)blockIdx.x & 7, r = (int)blockIdx.x >> 3;   // r in 0..99
    const int mg = x >> 2, ng = x & 3;
    if (ng == 0)      { mtile = mg * 16 + (r & 15);  ntile = r >> 4; }
    else if (r < 96)  { mtile = mg * 16 + (r & 15);  ntile = 1 + ng * 6 + (r >> 4); }
    else { const int r2 = 100 + (ng - 1) * 4 + (r - 96);
           mtile = mg * 16 + (r2 & 15); ntile = r2 >> 4; }
  } else {
    const int cpx = (int)gridDim.x >> 3;
    const int wg = ((int)blockIdx.x & 7) * cpx + ((int)blockIdx.x >> 3);
    mtile = wg / ntn; ntile = wg % ntn;
  }
  const int m0 = mtile * 128, n0 = ntile * 256;
  const int NTK = K >> 5;
  // read-side swizzle: byte col = (fq*16) ^ ((row&3)<<4); frag base rows are 16-multiples
  const int fcol = (fq * 16) ^ ((frow & 3) << 4);
  // staging: linear LDS dest (tid*16); inverse-swizzled global source (same involution)
  const int q  = tid * 16;
  const int qs = q ^ (((q >> 6) & 3) << 4);
  const int sr = qs >> 6;            // row 0..127
  const int sc = (qs & 63) >> 1;     // elem col 0..31
  const int wofs = wave * 1024;      // per-wave linear LDS byte base

  f32x4 acc[4][4] = {};

  #define STAGE128(T, BUF)                                                          \
    do { const int kc = (T) * 32;                                                   \
      gload_lds16(A  + (size_t)(m0 + sr) * K + kc + sc,       (char*)LA[BUF] + wofs);\
      gload_lds16(Bt + (size_t)(n0 + sr) * K + kc + sc,       (char*)LB[BUF] + wofs);\
      gload_lds16(Bt + (size_t)(n0 + 128 + sr) * K + kc + sc, (char*)LB[BUF] + 8192 + wofs);\
    } while (0)

  // prologue: stage tile 0
  STAGE128(0, 0);
  asm volatile("s_waitcnt vmcnt(0)" ::: "memory");
  __syncthreads();

  #pragma unroll 1
  for (int t = 0; t < NTK; ++t) {
    const int cur = t & 1;
    if (t + 1 < NTK) STAGE128(t + 1, cur ^ 1);
    const char* lA = (const char*)LA[cur];
    const char* lB = (const char*)LB[cur];
    short8 af[4], bfr[4];
    #pragma unroll
    for (int i = 0; i < 4; ++i)
      af[i] = *(const short8*)(lA + (wm * 64 + i * 16 + frow) * 64 + fcol);
    #pragma unroll
    for (int i = 0; i < 4; ++i)
      bfr[i] = *(const short8*)(lB + (wn * 64 + i * 16 + frow) * 64 + fcol);
    #pragma unroll
    for (int mi = 0; mi < 4; ++mi)
      #pragma unroll
      for (int ni = 0; ni < 4; ++ni)
        acc[mi][ni] = __builtin_amdgcn_mfma_f32_16x16x32_bf16(af[mi], bfr[ni], acc[mi][ni], 0, 0, 0);
    __syncthreads();   // drains staging (vmcnt) + all LDS reads of buf[cur^1] done
  }
  #undef STAGE128

  // epilogue
  const int crow = fq * 4, ccol = frow;
  const int rowb = m0 + wm * 64;
  if (outv) {
    const int f = *outflag;
    const int cb = n0 + wn * 64;
    #pragma unroll
    for (int mi = 0; mi < 4; ++mi)
      #pragma unroll
      for (int ni = 0; ni < 4; ++ni)
        #pragma unroll
        for (int r = 0; r < 4; ++r) {
          const size_t idx = (size_t)(rowb + mi * 16 + crow + r) * 2048 + cb + ni * 16 + ccol;
          const float val = acc[mi][ni][r];
          if (f == 1) ((float*)outv)[idx] = val;
          else        ((bf16*)outv)[idx] = __float2bfloat16(val);
        }
    return;
  }
  // routed epilogue: seg 0/1 l2norm per 64-col head, 2 plain, 3 beta (stride 256)
  const int gn0w = n0 + wn * 64;
  const int seg = gn0w >> 11;
  bf16* o = (seg == 0) ? oq : (seg == 1) ? ok2 : (seg == 2) ? ov : ob;
  const int stride = (seg < 3) ? 2048 : 256;
  const int cb = (seg < 3) ? (gn0w & 2047) : (gn0w - 6144);
  if (seg <= 1) {
    #pragma unroll
    for (int mi = 0; mi < 4; ++mi)
      #pragma unroll
      for (int r = 0; r < 4; ++r) {
        float s = acc[mi][0][r] * acc[mi][0][r] + acc[mi][1][r] * acc[mi][1][r]
                + acc[mi][2][r] * acc[mi][2][r] + acc[mi][3][r] * acc[mi][3][r];
        s += __shfl_xor(s, 1, 64); s += __shfl_xor(s, 2, 64);
        s += __shfl_xor(s, 4, 64); s += __shfl_xor(s, 8, 64);
        const float inv = rsqrtf(s + 1e-6f);
        #pragma unroll
        for (int ni = 0; ni < 4; ++ni) acc[mi][ni][r] *= inv;
      }
  }
  #pragma unroll
  for (int mi = 0; mi < 4; ++mi)
    #pragma unroll
    for (int ni = 0; ni < 4; ++ni)
      #pragma unroll
      for (int r = 0; r < 4; ++r)
        o[(size_t)(rowb + mi * 16 + crow + r) * stride + cb + ni * 16 + ccol] =
          __float2bfloat16(acc[mi][ni][r]);
}

// ======================= fused-path chunk kernels =======================

template<int TB>
__device__ __forceinline__ void scan16(const float* __restrict__ Af,
                                       const bf16* __restrict__ vsrc,
                                       const float* __restrict__ Bsc,
                                       float (&u)[64], const int lane, const int wave,
                                       const float sgn,
                                       bf16* __restrict__ outT,
                                       bf16* __restrict__ gout) {
  constexpr int JM = (TB + 1) * 16;
  #pragma unroll
  for (int tt = 0; tt < 16; ++tt) {
    const int t = TB * 16 + tt;
    float pr0 = 0.f, pr1 = 0.f, pr2 = 0.f, pr3 = 0.f;
    #pragma unroll
    for (int i = 0; i < JM; i += 4) {
      const f32x4 a = *(const f32x4*)(Af + t * 64 + i);   // wave-uniform row read
      pr0 = __builtin_fmaf(a[0], u[i + 0], pr0);
      pr1 = __builtin_fmaf(a[1], u[i + 1], pr1);
      pr2 = __builtin_fmaf(a[2], u[i + 2], pr2);
      pr3 = __builtin_fmaf(a[3], u[i + 3], pr3);
    }
    const float ut = Bsc[t] * __bfloat162float(vsrc[t * 72 + lane])
                   - ((pr0 + pr1) + (pr2 + pr3));
    u[t] = ut;
    const bf16 sv = __float2bfloat16(sgn * ut);
    outT[lane * 72 + t] = sv;
    if (wave) gout[t * 64 + lane] = sv;
  }
}

// pass 1: A = beta*tril(K K^T) via MFMA (fp32 LDS), then two register forward substitutions.
__global__ __launch_bounds__(256) void chunk_scan(const bf16* __restrict__ k16,
                                                  bf16* __restrict__ v16,
                                                  const bf16* __restrict__ betab,
                                                  const void* __restrict__ bb,
                                                  const int* __restrict__ flag,
                                                  bf16* __restrict__ Gneg,
                                                  bf16* __restrict__ AcT,
                                                  bf16* __restrict__ Dc) {
  __shared__ bf16 Ks[64 * 72];
  __shared__ bf16 Vs[64 * 72];
  __shared__ bf16 GsT[64 * 72];
  __shared__ bf16 UsT[64 * 72];
  __shared__ float Af[64 * 64];
  __shared__ float Bsc[64];
  bf16* const KTs = (bf16*)Af;
  const int ch = blockIdx.x;
  const int c = ch & (NCH - 1), bh = ch >> 5;
  const int h = bh & (NH - 1), b = bh >> 5;
  const int tid = threadIdx.x, wave = tid >> 6, lane = tid & 63;
  const size_t rowb = ((size_t)b * NT + c * 64) * ND + (size_t)h * 64;

  short8 ktA0, ktB0, ktA1, ktB1;
  if (wave >= 2) {
    const int d0a = (wave - 2) * 16, d0b = d0a + 32;
    ktA0 = *(const short8*)(k16 + rowb + (size_t)lane * ND + d0a);
    ktB0 = *(const short8*)(k16 + rowb + (size_t)lane * ND + d0a + 8);
    ktA1 = *(const short8*)(k16 + rowb + (size_t)lane * ND + d0b);
    ktB1 = *(const short8*)(k16 + rowb + (size_t)lane * ND + d0b + 8);
  }
  {
    const int r0 = tid >> 3, sc = (tid & 7) * 8;
    #pragma unroll
    for (int rnd = 0; rnd < 2; ++rnd) {
      const int r = rnd * 32 + r0;
      *(short8*)(Ks + r * 72 + sc) = *(const short8*)(k16 + rowb + (size_t)r * ND + sc);
      *(short8*)(Vs + r * 72 + sc) = *(const short8*)(v16 + rowb + (size_t)r * ND + sc);
    }
  }
  if (tid < 64) {
    const float x = __bfloat162float(betab[((size_t)b * NT + c * 64 + tid) * 256 + h])
                    + loadf(bb, h, *flag);
    Bsc[tid] = 1.f / (1.f + expf(-x));
  }
  __syncthreads();

  const int frow = lane & 15, fk = (lane >> 4) * 8, cm = (lane >> 4) * 4;
  {
    short8 ma0 = *(const short8*)(Ks + (16 * wave + frow) * 72 + fk);
    short8 ma1 = *(const short8*)(Ks + (16 * wave + frow) * 72 + 32 + fk);
    #pragma unroll
    for (int n = 0; n < 4; ++n) {
      f32x4 m = {};
      m = __builtin_amdgcn_mfma_f32_16x16x32_bf16(ma0, *(const short8*)(Ks + (16 * n + frow) * 72 + fk), m, 0, 0, 0);
      m = __builtin_amdgcn_mfma_f32_16x16x32_bf16(ma1, *(const short8*)(Ks + (16 * n + frow) * 72 + 32 + fk), m, 0, 0, 0);
      #pragma unroll
      for (int r = 0; r < 4; ++r) {
        const int t = 16 * wave + cm + r, s = 16 * n + frow;
        Af[t * 64 + s] = (s < t) ? Bsc[t] * m[r] : 0.f;
      }
    }
  }
  __syncthreads();

  if (wave < 2) {
    float u[64];
    #pragma unroll
    for (int i = 0; i < 64; ++i) u[i] = 0.f;
    const bf16* vsrc = wave ? Ks : Vs;
    bf16* outT = wave ? GsT : UsT;
    bf16* gout = Gneg + (size_t)ch * 4096;
    const float sgn = wave ? -1.f : 1.f;
    scan16<0>(Af, vsrc, Bsc, u, lane, wave, sgn, outT, gout);
    scan16<1>(Af, vsrc, Bsc, u, lane, wave, sgn, outT, gout);
    scan16<2>(Af, vsrc, Bsc, u, lane, wave, sgn, outT, gout);
    scan16<3>(Af, vsrc, Bsc, u, lane, wave, sgn, outT, gout);
  }
  __syncthreads();

  if (wave >= 2) {
    const int d0a = (wave - 2) * 16, d0b = d0a + 32;
    #pragma unroll
    for (int j = 0; j < 8; ++j) {
      KTs[(d0a + j) * 72 + lane]     = ((const bf16*)&ktA0)[j];
      KTs[(d0a + 8 + j) * 72 + lane] = ((const bf16*)&ktB0)[j];
      KTs[(d0b + j) * 72 + lane]     = ((const bf16*)&ktA1)[j];
      KTs[(d0b + 8 + j) * 72 + lane] = ((const bf16*)&ktB1)[j];
    }
  }
  __syncthreads();

  short8 ka0 = *(const short8*)(KTs + (16 * wave + frow) * 72 + fk);
  short8 ka1 = *(const short8*)(KTs + (16 * wave + frow) * 72 + 32 + fk);
  short8 uu0 = *(const short8*)(UsT + (16 * wave + frow) * 72 + fk);
  short8 uu1 = *(const short8*)(UsT + (16 * wave + frow) * 72 + 32 + fk);
  #pragma unroll
  for (int n = 0; n < 4; ++n) {
    f32x4 aA = {}, aD = {};
    aA = __builtin_amdgcn_mfma_f32_16x16x32_bf16(ka0, *(const short8*)(GsT + (16 * n + frow) * 72 + fk), aA, 0, 0, 0);
    aA = __builtin_amdgcn_mfma_f32_16x16x32_bf16(ka1, *(const short8*)(GsT + (16 * n + frow) * 72 + 32 + fk), aA, 0, 0, 0);
    aD = __builtin_amdgcn_mfma_f32_16x16x32_bf16(uu0, *(const short8*)(KTs + (16 * n + frow) * 72 + fk), aD, 0, 0, 0);
    aD = __builtin_amdgcn_mfma_f32_16x16x32_bf16(uu1, *(const short8*)(KTs + (16 * n + frow) * 72 + 32 + fk), aD, 0, 0, 0);
    #pragma unroll
    for (int r = 0; r < 4; ++r) {
      Vs[(16 * wave + cm + r) * 64 + 16 * n + frow] = __float2bfloat16(aA[r]);
      Ks[(16 * wave + cm + r) * 64 + 16 * n + frow] = __float2bfloat16(aD[r]);
    }
  }
  __syncthreads();
  {
    const int r0 = tid >> 2, sc2 = (tid & 3) * 16;
    bf16* acg = AcT + (size_t)ch * 4096;
    bf16* dcg = Dc  + (size_t)ch * 4096;
    *(short8*)(acg + r0 * 64 + sc2)     = *(const short8*)(Vs + r0 * 64 + sc2);
    *(short8*)(acg + r0 * 64 + sc2 + 8) = *(const short8*)(Vs + r0 * 64 + sc2 + 8);
    *(short8*)(dcg + r0 * 64 + sc2)     = *(const short8*)(Ks + r0 * 64 + sc2);
    *(short8*)(dcg + r0 * 64 + sc2 + 8) = *(const short8*)(Ks + r0 * 64 + sc2 + 8);
    *(short8*)(v16 + rowb + (size_t)r0 * ND + sc2)     = *(const short8*)(UsT + r0 * 72 + sc2);
    *(short8*)(v16 + rowb + (size_t)r0 * ND + sc2 + 8) = *(const short8*)(UsT + r0 * 72 + sc2 + 8);
  }
}

// pass 2: minimal serial recurrence: sacc(fp32) += S_bf16 @ AcT^T + Dc, per chunk.
__global__ __launch_bounds__(256) void state_seq(const bf16* __restrict__ AcT,
                                                 const bf16* __restrict__ Dc,
                                                 bf16* __restrict__ Sbuf) {
  __shared__ bf16 ST[64 * 72];
  const int bh = blockIdx.x;
  const int wave = threadIdx.x >> 6, lane = threadIdx.x & 63;
  const int frow = lane & 15, fk = (lane >> 4) * 8, cm = (lane >> 4) * 4;
  for (int i = threadIdx.x; i < 64 * 72 / 2; i += 256) ((unsigned int*)ST)[i] = 0u;
  f32x4 sacc[4] = {};
  const bf16* ac = AcT + (size_t)bh * NCH * 4096;
  const bf16* dc = Dc  + (size_t)bh * NCH * 4096;
  bf16* sb = Sbuf + (size_t)bh * NCH * 4096;
  #pragma unroll
  for (int n = 0; n < 4; ++n)
    #pragma unroll
    for (int r = 0; r < 4; ++r)
      sb[(16 * wave + cm + r) * 64 + 16 * n + frow] = __float2bfloat16(0.f);
  short8 bpre[4][2];
  float dpre[16];
  #pragma unroll
  for (int n = 0; n < 4; ++n) {
    bpre[n][0] = *(const short8*)(ac + (16 * n + frow) * 64 + fk);
    bpre[n][1] = *(const short8*)(ac + (16 * n + frow) * 64 + 32 + fk);
    #pragma unroll
    for (int r = 0; r < 4; ++r)
      dpre[n * 4 + r] = __bfloat162float(dc[(16 * wave + cm + r) * 64 + 16 * n + frow]);
  }
  __syncthreads();
  #pragma unroll 1
  for (int c = 0; c < NCH; ++c) {
    short8 a0 = *(const short8*)(ST + (16 * wave + frow) * 72 + fk);
    short8 a1 = *(const short8*)(ST + (16 * wave + frow) * 72 + 32 + fk);
    short8 bcur[4][2];
    float dcur[16];
    #pragma unroll
    for (int n = 0; n < 4; ++n) {
      bcur[n][0] = bpre[n][0]; bcur[n][1] = bpre[n][1];
      #pragma unroll
      for (int r = 0; r < 4; ++r) dcur[n * 4 + r] = dpre[n * 4 + r];
    }
    if (c + 1 < NCH) {
      const bf16* acn = ac + (size_t)(c + 1) * 4096;
      const bf16* dcn = dc + (size_t)(c + 1) * 4096;
      #pragma unroll
      for (int n = 0; n < 4; ++n) {
        bpre[n][0] = *(const short8*)(acn + (16 * n + frow) * 64 + fk);
        bpre[n][1] = *(const short8*)(acn + (16 * n + frow) * 64 + 32 + fk);
        #pragma unroll
        for (int r = 0; r < 4; ++r)
          dpre[n * 4 + r] = __bfloat162float(dcn[(16 * wave + cm + r) * 64 + 16 * n + frow]);
      }
    }
    #pragma unroll
    for (int n = 0; n < 4; ++n) {
      sacc[n] = __builtin_amdgcn_mfma_f32_16x16x32_bf16(a0, bcur[n][0], sacc[n], 0, 0, 0);
      sacc[n] = __builtin_amdgcn_mfma_f32_16x16x32_bf16(a1, bcur[n][1], sacc[n], 0, 0, 0);
      #pragma unroll
      for (int r = 0; r < 4; ++r) sacc[n][r] += dcur[n * 4 + r];
    }
    __syncthreads();
    #pragma unroll
    for (int n = 0; n < 4; ++n)
      #pragma unroll
      for (int r = 0; r < 4; ++r) {
        const bf16 sv = __float2bfloat16(sacc[n][r]);
        ST[(16 * wave + cm + r) * 72 + 16 * n + frow] = sv;
        if (c + 1 < NCH)
          sb[(size_t)(c + 1) * 4096 + (16 * wave + cm + r) * 64 + 16 * n + frow] = sv;
      }
    __syncthreads();
  }
}

// pass 3: chunk-parallel outputs. O = Q*S_c + tril(QK^T)*U_c, in place over q16.
__global__ __launch_bounds__(256) void chunk_out(bf16* __restrict__ q16,
                                                 const bf16* __restrict__ k16,
                                                 const bf16* __restrict__ v16,
                                                 const bf16* __restrict__ Gneg,
                                                 const bf16* __restrict__ Sbuf) {
  __shared__ bf16 UTs[64 * 72];
  __shared__ bf16 Pt[64 * 72];
  const int ch = blockIdx.x;
  const int c = ch & (NCH - 1), bh = ch >> 5;
  const int h = bh & (NH - 1), b = bh >> 5;
  const int tid = threadIdx.x, wave = tid >> 6, lane = tid & 63;
  const int frow = lane & 15, fk = (lane >> 4) * 8, cm = (lane >> 4) * 4;
  const size_t qkb = ((size_t)b * NT + c * 64) * ND + (size_t)h * 64;
  const bf16* Sb = Sbuf + (size_t)ch * 4096;
  const bf16* Gc = Gneg + (size_t)ch * 4096;
  {
    const int r0 = tid >> 2, sc2 = (tid & 3) * 16;
    *(short8*)(UTs + r0 * 72 + sc2)     = *(const short8*)(v16 + qkb + (size_t)r0 * ND + sc2);
    *(short8*)(UTs + r0 * 72 + sc2 + 8) = *(const short8*)(v16 + qkb + (size_t)r0 * ND + sc2 + 8);
  }
  short8 qa0 = *(const short8*)(q16 + qkb + (size_t)(16 * wave + frow) * ND + fk);
  short8 qa1 = *(const short8*)(q16 + qkb + (size_t)(16 * wave + frow) * ND + 32 + fk);
  f32x4 pacc[4];
  #pragma unroll
  for (int n = 0; n < 4; ++n) {
    f32x4 a = {};
    a = __builtin_amdgcn_mfma_f32_16x16x32_bf16(qa0, *(const short8*)(k16 + qkb + (size_t)(16 * n + frow) * ND + fk), a, 0, 0, 0);
    a = __builtin_amdgcn_mfma_f32_16x16x32_bf16(qa1, *(const short8*)(k16 + qkb + (size_t)(16 * n + frow) * ND + 32 + fk), a, 0, 0, 0);
    pacc[n] = a;
  }
  __syncthreads();
  f32x4 uacc[4];
  #pragma unroll
  for (int n = 0; n < 4; ++n)
    #pragma unroll
    for (int r = 0; r < 4; ++r)
      uacc[n][r] = __bfloat162float(UTs[(16 * wave + cm + r) * 72 + 16 * n + frow]);
  #pragma unroll
  for (int n = 0; n < 4; ++n)
    #pragma unroll
    for (int r = 0; r < 4; ++r) {
      const int mg = 16 * wave + cm + r, ng = 16 * n + frow;
      Pt[mg * 72 + ng] = __float2bfloat16(ng <= mg ? pacc[n][r] : 0.f);
    }
  short8 sa0 = *(const short8*)(Sb + (16 * wave + frow) * 64 + fk);
  short8 sa1 = *(const short8*)(Sb + (16 * wave + frow) * 64 + 32 + fk);
  #pragma unroll
  for (int n = 0; n < 4; ++n) {
    uacc[n] = __builtin_amdgcn_mfma_f32_16x16x32_bf16(sa0, *(const short8*)(Gc + (16 * n + frow) * 64 + fk), uacc[n], 0, 0, 0);
    uacc[n] = __builtin_amdgcn_mfma_f32_16x16x32_bf16(sa1, *(const short8*)(Gc + (16 * n + frow) * 64 + 32 + fk), uacc[n], 0, 0, 0);
  }
  __syncthreads();
  #pragma unroll
  for (int n = 0; n < 4; ++n)
    #pragma unroll
    for (int r = 0; r < 4; ++r)
      UTs[(16 * wave + cm + r) * 72 + 16 * n + frow] = __float2bfloat16(uacc[n][r]);
  __syncthreads();
  short8 pa0 = *(const short8*)(Pt + (16 * wave + frow) * 72 + fk);
  short8 pa1 = *(const short8*)(Pt + (16 * wave + frow) * 72 + 32 + fk);
  #pragma unroll
  for (int n = 0; n < 4; ++n) {
    f32x4 o = {};
    o = __builtin_amdgcn_mfma_f32_16x16x32_bf16(qa0, *(const short8*)(Sb + (16 * n + frow) * 64 + fk), o, 0, 0, 0);
    o = __builtin_amdgcn_mfma_f32_16x16x32_bf16(qa1, *(const short8*)(Sb + (16 * n + frow) * 64 + 32 + fk), o, 0, 0, 0);
    o = __builtin_amdgcn_mfma_f32_16x16x32_bf16(pa0, *(const short8*)(UTs + (16 * n + frow) * 72 + fk), o, 0, 0, 0);
    o = __builtin_amdgcn_mfma_f32_16x16x32_bf16(pa1, *(const short8*)(UTs + (16 * n + frow) * 72 + 32 + fk), o, 0, 0, 0);
    #pragma unroll
    for (int r = 0; r < 4; ++r)
      q16[qkb + (size_t)(16 * wave + cm + r) * ND + 16 * n + frow] = __float2bfloat16(o[r]);
  }
}

// ======================= compact-fallback chunk kernels (round-4 proven) =======================

__global__ __launch_bounds__(128) void chunk_scan_c(const bf16* __restrict__ k16,
                                                    bf16* __restrict__ v16,
                                                    const bf16* __restrict__ betab,
                                                    const void* __restrict__ bb,
                                                    const int* __restrict__ flag,
                                                    bf16* __restrict__ Gneg) {
  __shared__ bf16 Ks[64 * 64];
  __shared__ bf16 Vs[64 * 64];
  __shared__ bf16 Gs[64 * 64];
  __shared__ float Bs[64];
  const int ch = blockIdx.x;
  const int c = ch & (NCH - 1), bh = ch >> 5;
  const int h = bh & (NH - 1), b = bh >> 5;
  const int tid = threadIdx.x;
  const int wave = tid >> 6, lane = tid & 63;
  const size_t rowb = ((size_t)b * NT + c * 64) * ND + (size_t)h * 64;
  const int sr = tid >> 3, sc = (tid & 7) * 8;
  #pragma unroll
  for (int rnd = 0; rnd < 4; ++rnd) {
    const int r = rnd * 16 + sr;
    *(short8*)(Ks + r * 64 + sc) = *(const short8*)(k16 + rowb + (size_t)r * ND + sc);
    *(short8*)(Vs + r * 64 + sc) = *(const short8*)(v16 + rowb + (size_t)r * ND + sc);
  }
  if (tid < 64) {
    const float x = __bfloat162float(betab[((size_t)b * NT + c * 64 + tid) * 128 + h])
                    + loadf(bb, h, *flag);
    Bs[tid] = 1.f / (1.f + expf(-x));
  }
  __syncthreads();
  float S[64];
  #pragma unroll
  for (int i = 0; i < 64; ++i) S[i] = 0.f;
  const bf16* val_src = wave ? Ks : Vs;
  #pragma unroll 1
  for (int t = 0; t < 64; ++t) {
    uint4 ku[8];
    #pragma unroll
    for (int i = 0; i < 8; ++i) ku[i] = ((const uint4*)(Ks + t * 64))[i];
    const float val = __bfloat162float(val_src[t * 64 + lane]);
    const float bt = Bs[t];
    float kvf[64];
    #pragma unroll
    for (int i = 0; i < 8; ++i) {
      kvf[8*i+0] = __uint_as_float(ku[i].x << 16);
      kvf[8*i+1] = __uint_as_float(ku[i].x & 0xffff0000u);
      kvf[8*i+2] = __uint_as_float(ku[i].y << 16);
      kvf[8*i+3] = __uint_as_float(ku[i].y & 0xffff0000u);
      kvf[8*i+4] = __uint_as_float(ku[i].z << 16);
      kvf[8*i+5] = __uint_as_float(ku[i].z & 0xffff0000u);
      kvf[8*i+6] = __uint_as_float(ku[i].w << 16);
      kvf[8*i+7] = __uint_as_float(ku[i].w & 0xffff0000u);
    }
    float p0 = 0, p1 = 0, p2 = 0, p3 = 0;
    #pragma unroll
    for (int i = 0; i < 16; ++i) {
      p0 += kvf[4*i+0] * S[4*i+0];
      p1 += kvf[4*i+1] * S[4*i+1];
      p2 += kvf[4*i+2] * S[4*i+2];
      p3 += kvf[4*i+3] * S[4*i+3];
    }
    const float u = bt * (val - ((p0 + p1) + (p2 + p3)));
    #pragma unroll
    for (int i = 0; i < 16; ++i) {
      S[4*i+0] += kvf[4*i+0] * u;
      S[4*i+1] += kvf[4*i+1] * u;
      S[4*i+2] += kvf[4*i+2] * u;
      S[4*i+3] += kvf[4*i+3] * u;
    }
    if (wave) Gs[t * 64 + lane] = __float2bfloat16(-u);
    else      Vs[t * 64 + lane] = __float2bfloat16(u);
  }
  __syncthreads();
  bf16* gout = Gneg + (size_t)ch * 4096;
  #pragma unroll
  for (int rnd = 0; rnd < 4; ++rnd) {
    const int r = rnd * 16 + sr;
    *(short8*)(v16 + rowb + (size_t)r * ND + sc) = *(const short8*)(Vs + r * 64 + sc);
    *(short8*)(gout + r * 64 + sc)               = *(const short8*)(Gs + r * 64 + sc);
  }
}

__global__ __launch_bounds__(256) void chunk_seq_mono(bf16* q16,
                                                      const bf16* __restrict__ k16,
                                                      const bf16* __restrict__ Ul,
                                                      const bf16* __restrict__ Gneg) {
  __shared__ bf16 ST[64 * 72];
  __shared__ bf16 Ubt[64 * 72];
  __shared__ bf16 Pt[64 * 72];
  __shared__ bf16 KTl[64 * 72];
  const int bh = blockIdx.x, h = bh & (NH - 1), b = bh >> 5;
  const int wave = threadIdx.x >> 6, lane = threadIdx.x & 63;
  const int frow = lane & 15, q4 = lane >> 4, fk = q4 * 8;
  const int cm = q4 * 4;
  for (int i = threadIdx.x; i < 64 * 72 / 2; i += 256) ((unsigned int*)ST)[i] = 0u;
  __syncthreads();
  f32x4 sacc[4] = {};
  #pragma unroll 1
  for (int c = 0; c < NCH; ++c) {
    const bf16* Gc = Gneg + ((size_t)bh * NCH + c) * 4096;
    const size_t qkb = ((size_t)b * NT + c * 64) * ND + (size_t)h * 64;
    {
      short8 r0 = *(const short8*)(k16 + qkb + (size_t)lane * ND + 16 * wave);
      short8 r1 = *(const short8*)(k16 + qkb + (size_t)lane * ND + 16 * wave + 8);
      #pragma unroll
      for (int j = 0; j < 8; ++j) {
        KTl[(16 * wave + j) * 72 + lane]     = ((const bf16*)&r0)[j];
        KTl[(16 * wave + 8 + j) * 72 + lane] = ((const bf16*)&r1)[j];
      }
    }
    short8 ga0 = *(const short8*)(Gc + (16 * wave + frow) * 64 + fk);
    short8 ga1 = *(const short8*)(Gc + (16 * wave + frow) * 64 + 32 + fk);
    #pragma unroll
    for (int n = 0; n < 4; ++n) {
      f32x4 acc;
      #pragma unroll
      for (int r = 0; r < 4; ++r)
        acc[r] = __bfloat162float(Ul[qkb + (size_t)(16 * wave + cm + r) * ND + 16 * n + frow]);
      acc = __builtin_amdgcn_mfma_f32_16x16x32_bf16(ga0, *(const short8*)(ST + (16 * n + frow) * 72 + fk), acc, 0, 0, 0);
      acc = __builtin_amdgcn_mfma_f32_16x16x32_bf16(ga1, *(const short8*)(ST + (16 * n + frow) * 72 + 32 + fk), acc, 0, 0, 0);
      #pragma unroll
      for (int r = 0; r < 4; ++r)
        Ubt[(16 * n + frow) * 72 + 16 * wave + cm + r] = __float2bfloat16(acc[r]);
    }
    __syncthreads();
    short8 qa0 = *(const short8*)(q16 + qkb + (size_t)(16 * wave + frow) * ND + fk);
    short8 qa1 = *(const short8*)(q16 + qkb + (size_t)(16 * wave + frow) * ND + 32 + fk);
    #pragma unroll
    for (int n = 0; n < 4; ++n) {
      f32x4 acc = {};
      acc = __builtin_amdgcn_mfma_f32_16x16x32_bf16(qa0, *(const short8*)(k16 + qkb + (size_t)(16 * n + frow) * ND + fk), acc, 0, 0, 0);
      acc = __builtin_amdgcn_mfma_f32_16x16x32_bf16(qa1, *(const short8*)(k16 + qkb + (size_t)(16 * n + frow) * ND + 32 + fk), acc, 0, 0, 0);
      #pragma unroll
      for (int r = 0; r < 4; ++r) {
        const int mg = 16 * wave + cm + r, ng = 16 * n + frow;
        Pt[mg * 72 + ng] = __float2bfloat16(ng <= mg ? acc[r] : 0.f);
      }
    }
    __syncthreads();
    short8 pa0 = *(const short8*)(Pt + (16 * wave + frow) * 72 + fk);
    short8 pa1 = *(const short8*)(Pt + (16 * wave + frow) * 72 + 32 + fk);
    #pragma unroll
    for (int n = 0; n < 4; ++n) {
      f32x4 acc = {};
      acc = __builtin_amdgcn_mfma_f32_16x16x32_bf16(qa0, *(const short8*)(ST + (16 * n + frow) * 72 + fk), acc, 0, 0, 0);
      acc = __builtin_amdgcn_mfma_f32_16x16x32_bf16(qa1, *(const short8*)(ST + (16 * n + frow) * 72 + 32 + fk), acc, 0, 0, 0);
      acc = __builtin_amdgcn_mfma_f32_16x16x32_bf16(pa0, *(const short8*)(Ubt + (16 * n + frow) * 72 + fk), acc, 0, 0, 0);
      acc = __builtin_amdgcn_mfma_f32_16x16x32_bf16(pa1, *(const short8*)(Ubt + (16 * n + frow) * 72 + 32 + fk), acc, 0, 0, 0);
      #pragma unroll
      for (int r = 0; r < 4; ++r)
        q16[qkb + (size_t)(16 * wave + cm + r) * ND + 16 * n + frow] = __float2bfloat16(acc[r]);
    }
    __syncthreads();
    short8 ua0 = *(const short8*)(Ubt + (16 * wave + frow) * 72 + fk);
    short8 ua1 = *(const short8*)(Ubt + (16 * wave + frow) * 72 + 32 + fk);
    #pragma unroll
    for (int n = 0; n < 4; ++n) {
      sacc[n] = __builtin_amdgcn_mfma_f32_16x16x32_bf16(ua0, *(const short8*)(KTl + (16 * n + frow) * 72 + fk), sacc[n], 0, 0, 0);
      sacc[n] = __builtin_amdgcn_mfma_f32_16x16x32_bf16(ua1, *(const short8*)(KTl + (16 * n + frow) * 72 + 32 + fk), sacc[n], 0, 0, 0);
      #pragma unroll
      for (int r = 0; r < 4; ++r)
        ST[(16 * wave + cm + r) * 72 + 16 * n + frow] = __float2bfloat16(sacc[n][r]);
    }
    __syncthreads();
  }
}

extern "C" void kernel_launch(void* const* d_in, const int* in_sizes, int n_in,
                              void* d_out, int out_size, void* d_ws, size_t ws_size,
                              hipStream_t stream) {
  const void* hs = d_in[0];
  const void* Wq = d_in[1];
  const void* Wk = d_in[2];
  const void* Wv = d_in[3];
  const void* Wb = d_in[4];
  const void* bb = d_in[5];
  const void* Wo = d_in[6];

  char* ws = (char*)d_ws;
  size_t off = 0;
  auto alloc = [&](size_t bytes) {
    void* p = ws + off;
    off += (bytes + 255) & ~(size_t)255;
    return p;
  };
  const size_t szW2 = (size_t)32 * 1024 * 1024;  // WT (26.2 MiB weights) + AcT alias region
  const size_t szM  = (size_t)NM * ND * 2;       // 16 MiB
  const size_t szB2 = (size_t)NM * 256 * 2;      // 2 MiB (beta logits, 256-padded)
  const size_t szB  = (size_t)NM * 128 * 2;      // fallback beta (128-padded)
  const size_t need_fused = 512 + szW2 + 4 * szM + szB2 + szM;   // ~119.6 MB

  if (ws_size >= need_fused) {
    // ---- fused path ----
    int*  flag  = (int*) alloc(256);
    bf16* WT    = (bf16*)alloc(szW2);  // weights [0,26.2Mi); later Gneg [0,16Mi) + AcT [16,32Mi)
    bf16* hs16  = (bf16*)alloc(szM);   // -> Sbuf after fused GEMM
    bf16* q16   = (bf16*)alloc(szM);   // O in place
    bf16* k16   = (bf16*)alloc(szM);
    bf16* v16   = (bf16*)alloc(szM);   // U^T (transposed-in-place)
    bf16* betab = (bf16*)alloc(szB2);
    bf16* Dc    = (bf16*)alloc(szM);
    bf16* Gneg  = WT;                                    // [0,16MiB) dead after fused GEMM
    bf16* AcT   = WT + (size_t)8 * 1024 * 1024;          // [16,32MiB)
    bf16* WoT   = AcT;                                   // reused after state_seq
    bf16* Sbuf  = hs16;

    detect_dtype<<<1, 64, 0, stream>>>((const unsigned short*)hs, flag);
    convert_bf16<<<(NM * ND) / (256 * 8), 256, 0, stream>>>(hs, hs16, (long)NM * ND, flag);

    transpose_qkvb<<<dim3(32, 32, 4), 256, 0, stream>>>(Wq, Wk, Wv, Wb, WT, flag);
    gemm128<<<800, 512, 0, stream>>>(hs16, WT, q16, k16, v16, betab,
                                     nullptr, nullptr, ND, 25);

    chunk_scan<<<NB * NH * NCH, 256, 0, stream>>>(k16, v16, betab, bb, flag, Gneg, AcT, Dc);
    state_seq<<<NB * NH, 256, 0, stream>>>(AcT, Dc, Sbuf);
    chunk_out<<<NB * NH * NCH, 256, 0, stream>>>(q16, k16, v16, Gneg, Sbuf);

    transpose_cvt<<<dim3(32, 32), 256, 0, stream>>>(Wo, WoT, 2048, 2048, flag);
    gemm128<<<256, 512, 0, stream>>>(q16, WoT, nullptr, nullptr, nullptr, nullptr,
                                     d_out, flag, ND, 8);
  } else {
    // ---- compact fallback (proven ~73 MB footprint) ----
    int*  flag  = (int*) alloc(256);
    bf16* Wt    = (bf16*)alloc((size_t)2048 * 2048 * 2);
    bf16* hs16  = (bf16*)alloc(szM);   // -> Gneg
    bf16* q16   = (bf16*)alloc(szM);
    bf16* k16   = (bf16*)alloc(szM);
    bf16* v16   = (bf16*)alloc(szM);
    bf16* betab = (bf16*)alloc(szB);
    bf16* Gneg  = hs16;

    detect_dtype<<<1, 64, 0, stream>>>((const unsigned short*)hs, flag);
    convert_bf16<<<(NM * ND) / (256 * 8), 256, 0, stream>>>(hs, hs16, (long)NM * ND, flag);

    transpose_cvt<<<dim3(32, 32), 256, 0, stream>>>(Wq, Wt, 2048, 2048, flag);
    gemm_bt<<<dim3(16, 32), 256, 0, stream>>>(hs16, Wt, q16, k16, v16, betab, nullptr, nullptr, NM, ND, 0);
    transpose_cvt<<<dim3(32, 32), 256, 0, stream>>>(Wk, Wt, 2048, 2048, flag);
    gemm_bt<<<dim3(16, 32), 256, 0, stream>>>(hs16, Wt, q16, k16, v16, betab, nullptr, nullptr, NM, ND, 2048);
    transpose_cvt<<<dim3(32, 32), 256, 0, stream>>>(Wv, Wt, 2048, 2048, flag);
    gemm_bt<<<dim3(16, 32), 256, 0, stream>>>(hs16, Wt, q16, k16, v16, betab, nullptr, nullptr, NM, ND, 4096);
    transpose_cvt<<<dim3(2, 32),  256, 0, stream>>>(Wb, Wt, 2048, 32, flag);
    gemm_bt<<<dim3(1, 32), 256, 0, stream>>>(hs16, Wt, q16, k16, v16, betab, nullptr, nullptr, NM, ND, 6144);

    chunk_scan_c<<<NB * NH * NCH, 128, 0, stream>>>(k16, v16, betab, bb, flag, Gneg);
    chunk_seq_mono<<<NB * NH, 256, 0, stream>>>(q16, k16, v16, Gneg);

    transpose_cvt<<<dim3(32, 32), 256, 0, stream>>>(Wo, Wt, 2048, 2048, flag);
    gemm_bt<<<dim3(16, 32), 256, 0, stream>>>(q16, Wt, nullptr, nullptr, nullptr, nullptr,
                                              d_out, flag, NM, ND, 0);
  }
}

// Round 7
// 543.689 us; speedup vs baseline: 1.0827x; 1.0159x over previous
//
#include <hip/hip_runtime.h>
#include <hip/hip_bf16.h>

typedef __hip_bfloat16 bf16;
typedef __attribute__((ext_vector_type(8))) short short8;   // 8 bf16 (4 VGPRs)
typedef __attribute__((ext_vector_type(4))) float f32x4;

#define NB 2
#define NT 2048
#define ND 2048
#define NH 32
#define NM (NB*NT)   // 4096 rows
#define NCH 32       // chunks per (b,h): NT/64

// ---- dtype hedge: inputs may be bf16 (harness-converted) or fp32 (per reference) ----
__global__ void detect_dtype(const unsigned short* __restrict__ hs, int* __restrict__ flag) {
  if (threadIdx.x == 0 && blockIdx.x == 0) {
    int cnt = 0;
    for (int i = 0; i < 2048; i += 2) {
      int e = (hs[i] >> 7) & 0xFF;
      if (e >= 141) ++cnt;
    }
    *flag = (cnt > 64) ? 1 : 0;   // 1 = fp32, 0 = bf16
  }
}

__device__ __forceinline__ float loadf(const void* p, size_t i, int isf32) {
  return isf32 ? ((const float*)p)[i] : __bfloat162float(((const bf16*)p)[i]);
}

__global__ __launch_bounds__(256) void convert_bf16(const void* __restrict__ src,
                                                    bf16* __restrict__ dst,
                                                    long n, const int* __restrict__ flag) {
  const long i0 = ((long)blockIdx.x * 256 + threadIdx.x) * 8;
  if (i0 >= n) return;
  if (*flag) {
    const float* s = (const float*)src;
    #pragma unroll
    for (int j = 0; j < 8; ++j) dst[i0 + j] = __float2bfloat16(s[i0 + j]);
  } else {
    *(short8*)(dst + i0) = *(const short8*)((const bf16*)src + i0);
  }
}

// ---- transpose + convert one matrix: dst[c][r] = bf16(src[r][c]); zero-pad cols ----
__global__ __launch_bounds__(256) void transpose_cvt(const void* __restrict__ src,
                                                     bf16* __restrict__ dst,
                                                     int src_rows, int src_cols,
                                                     const int* __restrict__ flag) {
  __shared__ bf16 tile[64][65];
  const int f = *flag;
  const int tb_r = blockIdx.y * 64, tb_c = blockIdx.x * 64;
  const int tx = threadIdx.x & 63, ty = threadIdx.x >> 6;
  #pragma unroll
  for (int i = 0; i < 64; i += 4) {
    const int cc = tb_c + tx;
    tile[i + ty][tx] = (cc < src_cols)
      ? __float2bfloat16(loadf(src, (size_t)(tb_r + i + ty) * src_cols + cc, f))
      : __float2bfloat16(0.f);
  }
  __syncthreads();
  #pragma unroll
  for (int i = 0; i < 64; i += 4)
    dst[(size_t)(tb_c + i + ty) * src_rows + tb_r + tx] = tile[tx][i + ty];
}

// ---- merged transpose of Wq/Wk/Wv/Wb into WT, z-sliced (beta block padded to 256 rows) ----
__global__ __launch_bounds__(256) void transpose_qkvb(const void* __restrict__ Wq,
                                                      const void* __restrict__ Wk,
                                                      const void* __restrict__ Wv,
                                                      const void* __restrict__ Wb,
                                                      bf16* __restrict__ WT,
                                                      const int* __restrict__ flag) {
  __shared__ bf16 tile[64][65];
  const int z = blockIdx.z;
  if (z == 3 && blockIdx.x >= 4) return;   // Wb^T: 256 padded rows
  const void* src = (z == 0) ? Wq : (z == 1) ? Wk : (z == 2) ? Wv : Wb;
  const int src_cols = (z == 3) ? 32 : 2048;
  bf16* dst = WT + (size_t)z * 2048 * 2048;
  const int f = *flag;
  const int tb_r = blockIdx.y * 64, tb_c = blockIdx.x * 64;
  const int tx = threadIdx.x & 63, ty = threadIdx.x >> 6;
  #pragma unroll
  for (int i = 0; i < 64; i += 4) {
    const int cc = tb_c + tx;
    tile[i + ty][tx] = (cc < src_cols)
      ? __float2bfloat16(loadf(src, (size_t)(tb_r + i + ty) * src_cols + cc, f))
      : __float2bfloat16(0.f);
  }
  __syncthreads();
  #pragma unroll
  for (int i = 0; i < 64; i += 4)
    dst[(size_t)(tb_c + i + ty) * 2048 + tb_r + tx] = tile[tx][i + ty];
}

// async 16B/lane global->LDS (wave-uniform LDS base + lane*16)
__device__ __forceinline__ void gload_lds16(const void* g, void* l) {
  __builtin_amdgcn_global_load_lds((__attribute__((address_space(1))) const void*)g,
                                   (__attribute__((address_space(3))) void*)l,
                                   16, 0, 0);
}

// ------------- legacy GEMM (fallback path only): C = A @ Bt^T -------------
__global__ __launch_bounds__(256) void gemm_bt(const bf16* __restrict__ A,
                                               const bf16* __restrict__ Bt,
                                               bf16* __restrict__ oq, bf16* __restrict__ ok2,
                                               bf16* __restrict__ ov, bf16* __restrict__ ob,
                                               void* __restrict__ outv,
                                               const int* __restrict__ outflag,
                                               int M, int K, int n_base) {
  __shared__ bf16 As[128 * 32];
  __shared__ bf16 Bs[128 * 32];
  const int tid = threadIdx.x;
  const int wave = tid >> 6, lane = tid & 63;
  const int m0 = blockIdx.y * 128, n0 = blockIdx.x * 128;
  const int wm = (wave >> 1) * 64, wn = (wave & 1) * 64;
  const int srow = lane >> 2, scol = (lane & 3) * 8;
  const int frow = lane & 15, fk = (lane >> 4) * 8;
  f32x4 acc[4][4] = {};

  for (int kb = 0; kb < K; kb += 32) {
    __syncthreads();
    #pragma unroll
    for (int j = 0; j < 2; ++j) {
      const int rbase = wave * 32 + j * 16;
      gload_lds16(A  + (size_t)(m0 + rbase + srow) * K + kb + scol, As + rbase * 32);
      gload_lds16(Bt + (size_t)(n0 + rbase + srow) * K + kb + scol, Bs + rbase * 32);
    }
    __syncthreads();
    short8 af[4], bfr[4];
    #pragma unroll
    for (int i = 0; i < 4; ++i)
      af[i] = *(const short8*)(As + (wm + i * 16 + frow) * 32 + fk);
    #pragma unroll
    for (int i = 0; i < 4; ++i)
      bfr[i] = *(const short8*)(Bs + (wn + i * 16 + frow) * 32 + fk);
    #pragma unroll
    for (int mi = 0; mi < 4; ++mi)
      #pragma unroll
      for (int ni = 0; ni < 4; ++ni)
        acc[mi][ni] = __builtin_amdgcn_mfma_f32_16x16x32_bf16(af[mi], bfr[ni], acc[mi][ni], 0, 0, 0);
  }

  const int crow = (lane >> 4) * 4, ccol = lane & 15;
  const int gn0 = n_base + n0;
  if (outflag) {
    const int f = *outflag;
    #pragma unroll
    for (int mi = 0; mi < 4; ++mi)
      #pragma unroll
      for (int ni = 0; ni < 4; ++ni)
        #pragma unroll
        for (int r = 0; r < 4; ++r) {
          const size_t idx = (size_t)(m0 + wm + mi * 16 + crow + r) * 2048 + gn0 + wn + ni * 16 + ccol;
          const float val = acc[mi][ni][r];
          if (f == 1) ((float*)outv)[idx] = val;
          else        ((bf16*)outv)[idx] = __float2bfloat16(val);
        }
  } else {
    const int seg = gn0 >> 11;
    bf16* o = (seg == 0) ? oq : (seg == 1) ? ok2 : (seg == 2) ? ov : ob;
    const int stride = (seg < 3) ? 2048 : 128;
    const int cb = (gn0 & 2047) + wn;
    if (seg <= 1) {
      #pragma unroll
      for (int mi = 0; mi < 4; ++mi)
        #pragma unroll
        for (int r = 0; r < 4; ++r) {
          float s = acc[mi][0][r] * acc[mi][0][r] + acc[mi][1][r] * acc[mi][1][r]
                  + acc[mi][2][r] * acc[mi][2][r] + acc[mi][3][r] * acc[mi][3][r];
          s += __shfl_xor(s, 1, 64); s += __shfl_xor(s, 2, 64);
          s += __shfl_xor(s, 4, 64); s += __shfl_xor(s, 8, 64);
          const float inv = rsqrtf(s + 1e-6f);
          #pragma unroll
          for (int ni = 0; ni < 4; ++ni) acc[mi][ni][r] *= inv;
        }
    }
    #pragma unroll
    for (int mi = 0; mi < 4; ++mi)
      #pragma unroll
      for (int ni = 0; ni < 4; ++ni)
        #pragma unroll
        for (int r = 0; r < 4; ++r)
          o[(size_t)(m0 + wm + mi * 16 + crow + r) * stride + cb + ni * 16 + ccol] =
            __float2bfloat16(acc[mi][ni][r]);
  }
}

// ============ 128x256 GEMM, 2 blocks/CU (occupancy-overlap variant) ============
// 8-slot swizzle (fixed from r6's 4-slot): byte_in_128 = (row&1)<<6 | cols; XOR bits 4-5
// with (row>>1)&3 -> (row&1, (row>>1)&3) spans all 8 16B slots uniformly (structurally
// identical to the r3-verified zero-conflict gemm256 config).
__global__ __launch_bounds__(512, 4) void gemm128(const bf16* __restrict__ A,
                                                  const bf16* __restrict__ Bt,
                                                  bf16* __restrict__ oq, bf16* __restrict__ ok2,
                                                  bf16* __restrict__ ov, bf16* __restrict__ ob,
                                                  void* __restrict__ outv,
                                                  const int* __restrict__ outflag,
                                                  int K, int ntn) {
  __shared__ __align__(16) bf16 LA[2][128 * 32];   // 2 x 8 KB
  __shared__ __align__(16) bf16 LB[2][256 * 32];   // 2 x 16 KB
  const int tid = threadIdx.x;
  const int wave = tid >> 6, lane = tid & 63;
  const int wm = wave >> 2, wn = wave & 3;          // 2M x 4N
  const int frow = lane & 15, fq = lane >> 4;
  // ---- tile mapping ----
  int mtile, ntile;
  if (ntn == 25) {
    // supertile XCD mapping for the 32x25 grid (800 blocks; bijective, r5/r6-verified)
    const int x = (int)blockIdx.x & 7, r = (int)blockIdx.x >> 3;   // r in 0..99
    const int mg = x >> 2, ng = x & 3;
    if (ng == 0)      { mtile = mg * 16 + (r & 15);  ntile = r >> 4; }
    else if (r < 96)  { mtile = mg * 16 + (r & 15);  ntile = 1 + ng * 6 + (r >> 4); }
    else { const int r2 = 100 + (ng - 1) * 4 + (r - 96);
           mtile = mg * 16 + (r2 & 15); ntile = r2 >> 4; }
  } else {
    const int cpx = (int)gridDim.x >> 3;
    const int wg = ((int)blockIdx.x & 7) * cpx + ((int)blockIdx.x >> 3);
    mtile = wg / ntn; ntile = wg % ntn;
  }
  const int m0 = mtile * 128, n0 = ntile * 256;
  const int NTK = K >> 5;
  // read-side swizzle: byte col = (fq*16) ^ (((row>>1)&3)<<4); frag rows = base16 + frow,
  // base16>>1 ≡ 0 (mod 4), so (row>>1)&3 == (frow>>1)&3
  const int fcol = (fq * 16) ^ (((frow >> 1) & 3) << 4);
  // staging: linear LDS dest (tid*16); inverse-swizzled source (same involution, bits 7-8 = row>>1)
  const int q  = tid * 16;
  const int qs = q ^ (((q >> 7) & 3) << 4);
  const int sr = qs >> 6;            // row 0..127
  const int sc = (qs & 63) >> 1;     // elem col 0..31
  const int wofs = wave * 1024;      // per-wave linear LDS byte base

  f32x4 acc[4][4] = {};

  #define STAGE128(T, BUF)                                                          \
    do { const int kc = (T) * 32;                                                   \
      gload_lds16(A  + (size_t)(m0 + sr) * K + kc + sc,       (char*)LA[BUF] + wofs);\
      gload_lds16(Bt + (size_t)(n0 + sr) * K + kc + sc,       (char*)LB[BUF] + wofs);\
      gload_lds16(Bt + (size_t)(n0 + 128 + sr) * K + kc + sc, (char*)LB[BUF] + 8192 + wofs);\
    } while (0)

  // prologue: stage tile 0
  STAGE128(0, 0);
  asm volatile("s_waitcnt vmcnt(0)" ::: "memory");
  __syncthreads();

  #pragma unroll 1
  for (int t = 0; t < NTK; ++t) {
    const int cur = t & 1;
    if (t + 1 < NTK) STAGE128(t + 1, cur ^ 1);
    const char* lA = (const char*)LA[cur];
    const char* lB = (const char*)LB[cur];
    short8 af[4], bfr[4];
    #pragma unroll
    for (int i = 0; i < 4; ++i)
      af[i] = *(const short8*)(lA + (wm * 64 + i * 16 + frow) * 64 + fcol);
    #pragma unroll
    for (int i = 0; i < 4; ++i)
      bfr[i] = *(const short8*)(lB + (wn * 64 + i * 16 + frow) * 64 + fcol);
    #pragma unroll
    for (int mi = 0; mi < 4; ++mi)
      #pragma unroll
      for (int ni = 0; ni < 4; ++ni)
        acc[mi][ni] = __builtin_amdgcn_mfma_f32_16x16x32_bf16(af[mi], bfr[ni], acc[mi][ni], 0, 0, 0);
    __syncthreads();   // drains staging (vmcnt) + all LDS reads of buf[cur^1] done
  }
  #undef STAGE128

  // epilogue
  const int crow = fq * 4, ccol = frow;
  const int rowb = m0 + wm * 64;
  if (outv) {
    const int f = *outflag;
    const int cb = n0 + wn * 64;
    #pragma unroll
    for (int mi = 0; mi < 4; ++mi)
      #pragma unroll
      for (int ni = 0; ni < 4; ++ni)
        #pragma unroll
        for (int r = 0; r < 4; ++r) {
          const size_t idx = (size_t)(rowb + mi * 16 + crow + r) * 2048 + cb + ni * 16 + ccol;
          const float val = acc[mi][ni][r];
          if (f == 1) ((float*)outv)[idx] = val;
          else        ((bf16*)outv)[idx] = __float2bfloat16(val);
        }
    return;
  }
  // routed epilogue: seg 0/1 l2norm per 64-col head, 2 plain, 3 beta (stride 256)
  const int gn0w = n0 + wn * 64;
  const int seg = gn0w >> 11;
  bf16* o = (seg == 0) ? oq : (seg == 1) ? ok2 : (seg == 2) ? ov : ob;
  const int stride = (seg < 3) ? 2048 : 256;
  const int cb = (seg < 3) ? (gn0w & 2047) : (gn0w - 6144);
  if (seg <= 1) {
    #pragma unroll
    for (int mi = 0; mi < 4; ++mi)
      #pragma unroll
      for (int r = 0; r < 4; ++r) {
        float s = acc[mi][0][r] * acc[mi][0][r] + acc[mi][1][r] * acc[mi][1][r]
                + acc[mi][2][r] * acc[mi][2][r] + acc[mi][3][r] * acc[mi][3][r];
        s += __shfl_xor(s, 1, 64); s += __shfl_xor(s, 2, 64);
        s += __shfl_xor(s, 4, 64); s += __shfl_xor(s, 8, 64);
        const float inv = rsqrtf(s + 1e-6f);
        #pragma unroll
        for (int ni = 0; ni < 4; ++ni) acc[mi][ni][r] *= inv;
      }
  }
  #pragma unroll
  for (int mi = 0; mi < 4; ++mi)
    #pragma unroll
    for (int ni = 0; ni < 4; ++ni)
      #pragma unroll
      for (int r = 0; r < 4; ++r)
        o[(size_t)(rowb + mi * 16 + crow + r) * stride + cb + ni * 16 + ccol] =
          __float2bfloat16(acc[mi][ni][r]);
}

// ============ 128x128 out-projection GEMM: 512 blocks -> 2-4 blocks/CU ============
// 8 waves as 4M x 2N (per-wave 32x64, acc = 32 regs), BK=32, 32 KB LDS double-buffer,
// same 8-slot swizzle. outv-only epilogue.
__global__ __launch_bounds__(512, 4) void gemm128o(const bf16* __restrict__ A,
                                                   const bf16* __restrict__ Bt,
                                                   void* __restrict__ outv,
                                                   const int* __restrict__ outflag,
                                                   int K, int ntn) {
  __shared__ __align__(16) bf16 LA[2][128 * 32];   // 2 x 8 KB
  __shared__ __align__(16) bf16 LB[2][128 * 32];   // 2 x 8 KB
  const int tid = threadIdx.x;
  const int wave = tid >> 6, lane = tid & 63;
  const int wm = wave >> 1, wn = wave & 1;          // 4M x 2N
  const int frow = lane & 15, fq = lane >> 4;
  const int cpx = (int)gridDim.x >> 3;
  const int wg = ((int)blockIdx.x & 7) * cpx + ((int)blockIdx.x >> 3);
  const int mtile = wg / ntn, ntile = wg % ntn;
  const int m0 = mtile * 128, n0 = ntile * 128;
  const int NTK = K >> 5;
  const int fcol = (fq * 16) ^ (((frow >> 1) & 3) << 4);
  const int q  = tid * 16;
  const int qs = q ^ (((q >> 7) & 3) << 4);
  const int sr = qs >> 6, sc = (qs & 63) >> 1;
  const int wofs = wave * 1024;

  f32x4 acc[2][4] = {};

  #define STAGEO(T, BUF)                                                            \
    do { const int kc = (T) * 32;                                                   \
      gload_lds16(A  + (size_t)(m0 + sr) * K + kc + sc, (char*)LA[BUF] + wofs);     \
      gload_lds16(Bt + (size_t)(n0 + sr) * K + kc + sc, (char*)LB[BUF] + wofs);     \
    } while (0)

  STAGEO(0, 0);
  asm volatile("s_waitcnt vmcnt(0)" ::: "memory");
  __syncthreads();

  #pragma unroll 1
  for (int t = 0; t < NTK; ++t) {
    const int cur = t & 1;
    if (t + 1 < NTK) STAGEO(t + 1, cur ^ 1);
    const char* lA = (const char*)LA[cur];
    const char* lB = (const char*)LB[cur];
    short8 af[2], bfr[4];
    #pragma unroll
    for (int i = 0; i < 2; ++i)
      af[i] = *(const short8*)(lA + (wm * 32 + i * 16 + frow) * 64 + fcol);
    #pragma unroll
    for (int i = 0; i < 4; ++i)
      bfr[i] = *(const short8*)(lB + (wn * 64 + i * 16 + frow) * 64 + fcol);
    #pragma unroll
    for (int mi = 0; mi < 2; ++mi)
      #pragma unroll
      for (int ni = 0; ni < 4; ++ni)
        acc[mi][ni] = __builtin_amdgcn_mfma_f32_16x16x32_bf16(af[mi], bfr[ni], acc[mi][ni], 0, 0, 0);
    __syncthreads();
  }
  #undef STAGEO

  const int crow = fq * 4, ccol = frow;
  const int rowb = m0 + wm * 32;
  const int cb = n0 + wn * 64;
  const int f = *outflag;
  #pragma unroll
  for (int mi = 0; mi < 2; ++mi)
    #pragma unroll
    for (int ni = 0; ni < 4; ++ni)
      #pragma unroll
      for (int r = 0; r < 4; ++r) {
        const size_t idx = (size_t)(rowb + mi * 16 + crow + r) * 2048 + cb + ni * 16 + ccol;
        const float val = acc[mi][ni][r];
        if (f == 1) ((float*)outv)[idx] = val;
        else        ((bf16*)outv)[idx] = __float2bfloat16(val);
      }
}

// ======================= fused-path chunk kernels =======================

template<int TB>
__device__ __forceinline__ void scan16(const float* __restrict__ Af,
                                       const bf16* __restrict__ vsrc,
                                       const float* __restrict__ Bsc,
                                       float (&u)[64], const int lane, const int wave,
                                       const float sgn,
                                       bf16* __restrict__ outT,
                                       bf16* __restrict__ gout) {
  constexpr int JM = (TB + 1) * 16;
  #pragma unroll
  for (int tt = 0; tt < 16; ++tt) {
    const int t = TB * 16 + tt;
    float pr0 = 0.f, pr1 = 0.f, pr2 = 0.f, pr3 = 0.f;
    #pragma unroll
    for (int i = 0; i < JM; i += 4) {
      const f32x4 a = *(const f32x4*)(Af + t * 64 + i);   // wave-uniform row read
      pr0 = __builtin_fmaf(a[0], u[i + 0], pr0);
      pr1 = __builtin_fmaf(a[1], u[i + 1], pr1);
      pr2 = __builtin_fmaf(a[2], u[i + 2], pr2);
      pr3 = __builtin_fmaf(a[3], u[i + 3], pr3);
    }
    const float ut = Bsc[t] * __bfloat162float(vsrc[t * 72 + lane])
                   - ((pr0 + pr1) + (pr2 + pr3));
    u[t] = ut;
    const bf16 sv = __float2bfloat16(sgn * ut);
    outT[lane * 72 + t] = sv;
    if (wave) gout[t * 64 + lane] = sv;
  }
}

// pass 1: A = beta*tril(K K^T) via MFMA (fp32 LDS), then two register forward substitutions.
__global__ __launch_bounds__(256) void chunk_scan(const bf16* __restrict__ k16,
                                                  bf16* __restrict__ v16,
                                                  const bf16* __restrict__ betab,
                                                  const void* __restrict__ bb,
                                                  const int* __restrict__ flag,
                                                  bf16* __restrict__ Gneg,
                                                  bf16* __restrict__ AcT,
                                                  bf16* __restrict__ Dc) {
  __shared__ bf16 Ks[64 * 72];
  __shared__ bf16 Vs[64 * 72];
  __shared__ bf16 GsT[64 * 72];
  __shared__ bf16 UsT[64 * 72];
  __shared__ float Af[64 * 64];
  __shared__ float Bsc[64];
  bf16* const KTs = (bf16*)Af;
  const int ch = blockIdx.x;
  const int c = ch & (NCH - 1), bh = ch >> 5;
  const int h = bh & (NH - 1), b = bh >> 5;
  const int tid = threadIdx.x, wave = tid >> 6, lane = tid & 63;
  const size_t rowb = ((size_t)b * NT + c * 64) * ND + (size_t)h * 64;

  short8 ktA0, ktB0, ktA1, ktB1;
  if (wave >= 2) {
    const int d0a = (wave - 2) * 16, d0b = d0a + 32;
    ktA0 = *(const short8*)(k16 + rowb + (size_t)lane * ND + d0a);
    ktB0 = *(const short8*)(k16 + rowb + (size_t)lane * ND + d0a + 8);
    ktA1 = *(const short8*)(k16 + rowb + (size_t)lane * ND + d0b);
    ktB1 = *(const short8*)(k16 + rowb + (size_t)lane * ND + d0b + 8);
  }
  {
    const int r0 = tid >> 3, sc = (tid & 7) * 8;
    #pragma unroll
    for (int rnd = 0; rnd < 2; ++rnd) {
      const int r = rnd * 32 + r0;
      *(short8*)(Ks + r * 72 + sc) = *(const short8*)(k16 + rowb + (size_t)r * ND + sc);
      *(short8*)(Vs + r * 72 + sc) = *(const short8*)(v16 + rowb + (size_t)r * ND + sc);
    }
  }
  if (tid < 64) {
    const float x = __bfloat162float(betab[((size_t)b * NT + c * 64 + tid) * 256 + h])
                    + loadf(bb, h, *flag);
    Bsc[tid] = 1.f / (1.f + expf(-x));
  }
  __syncthreads();

  const int frow = lane & 15, fk = (lane >> 4) * 8, cm = (lane >> 4) * 4;
  {
    short8 ma0 = *(const short8*)(Ks + (16 * wave + frow) * 72 + fk);
    short8 ma1 = *(const short8*)(Ks + (16 * wave + frow) * 72 + 32 + fk);
    #pragma unroll
    for (int n = 0; n < 4; ++n) {
      f32x4 m = {};
      m = __builtin_amdgcn_mfma_f32_16x16x32_bf16(ma0, *(const short8*)(Ks + (16 * n + frow) * 72 + fk), m, 0, 0, 0);
      m = __builtin_amdgcn_mfma_f32_16x16x32_bf16(ma1, *(const short8*)(Ks + (16 * n + frow) * 72 + 32 + fk), m, 0, 0, 0);
      #pragma unroll
      for (int r = 0; r < 4; ++r) {
        const int t = 16 * wave + cm + r, s = 16 * n + frow;
        Af[t * 64 + s] = (s < t) ? Bsc[t] * m[r] : 0.f;
      }
    }
  }
  __syncthreads();

  if (wave < 2) {
    float u[64];
    #pragma unroll
    for (int i = 0; i < 64; ++i) u[i] = 0.f;
    const bf16* vsrc = wave ? Ks : Vs;
    bf16* outT = wave ? GsT : UsT;
    bf16* gout = Gneg + (size_t)ch * 4096;
    const float sgn = wave ? -1.f : 1.f;
    scan16<0>(Af, vsrc, Bsc, u, lane, wave, sgn, outT, gout);
    scan16<1>(Af, vsrc, Bsc, u, lane, wave, sgn, outT, gout);
    scan16<2>(Af, vsrc, Bsc, u, lane, wave, sgn, outT, gout);
    scan16<3>(Af, vsrc, Bsc, u, lane, wave, sgn, outT, gout);
  }
  __syncthreads();

  if (wave >= 2) {
    const int d0a = (wave - 2) * 16, d0b = d0a + 32;
    #pragma unroll
    for (int j = 0; j < 8; ++j) {
      KTs[(d0a + j) * 72 + lane]     = ((const bf16*)&ktA0)[j];
      KTs[(d0a + 8 + j) * 72 + lane] = ((const bf16*)&ktB0)[j];
      KTs[(d0b + j) * 72 + lane]     = ((const bf16*)&ktA1)[j];
      KTs[(d0b + 8 + j) * 72 + lane] = ((const bf16*)&ktB1)[j];
    }
  }
  __syncthreads();

  short8 ka0 = *(const short8*)(KTs + (16 * wave + frow) * 72 + fk);
  short8 ka1 = *(const short8*)(KTs + (16 * wave + frow) * 72 + 32 + fk);
  short8 uu0 = *(const short8*)(UsT + (16 * wave + frow) * 72 + fk);
  short8 uu1 = *(const short8*)(UsT + (16 * wave + frow) * 72 + 32 + fk);
  #pragma unroll
  for (int n = 0; n < 4; ++n) {
    f32x4 aA = {}, aD = {};
    aA = __builtin_amdgcn_mfma_f32_16x16x32_bf16(ka0, *(const short8*)(GsT + (16 * n + frow) * 72 + fk), aA, 0, 0, 0);
    aA = __builtin_amdgcn_mfma_f32_16x16x32_bf16(ka1, *(const short8*)(GsT + (16 * n + frow) * 72 + 32 + fk), aA, 0, 0, 0);
    aD = __builtin_amdgcn_mfma_f32_16x16x32_bf16(uu0, *(const short8*)(KTs + (16 * n + frow) * 72 + fk), aD, 0, 0, 0);
    aD = __builtin_amdgcn_mfma_f32_16x16x32_bf16(uu1, *(const short8*)(KTs + (16 * n + frow) * 72 + 32 + fk), aD, 0, 0, 0);
    #pragma unroll
    for (int r = 0; r < 4; ++r) {
      Vs[(16 * wave + cm + r) * 64 + 16 * n + frow] = __float2bfloat16(aA[r]);
      Ks[(16 * wave + cm + r) * 64 + 16 * n + frow] = __float2bfloat16(aD[r]);
    }
  }
  __syncthreads();
  {
    const int r0 = tid >> 2, sc2 = (tid & 3) * 16;
    bf16* acg = AcT + (size_t)ch * 4096;
    bf16* dcg = Dc  + (size_t)ch * 4096;
    *(short8*)(acg + r0 * 64 + sc2)     = *(const short8*)(Vs + r0 * 64 + sc2);
    *(short8*)(acg + r0 * 64 + sc2 + 8) = *(const short8*)(Vs + r0 * 64 + sc2 + 8);
    *(short8*)(dcg + r0 * 64 + sc2)     = *(const short8*)(Ks + r0 * 64 + sc2);
    *(short8*)(dcg + r0 * 64 + sc2 + 8) = *(const short8*)(Ks + r0 * 64 + sc2 + 8);
    *(short8*)(v16 + rowb + (size_t)r0 * ND + sc2)     = *(const short8*)(UsT + r0 * 72 + sc2);
    *(short8*)(v16 + rowb + (size_t)r0 * ND + sc2 + 8) = *(const short8*)(UsT + r0 * 72 + sc2 + 8);
  }
}

// pass 2: minimal serial recurrence: sacc(fp32) += S_bf16 @ AcT^T + Dc, per chunk.
__global__ __launch_bounds__(256) void state_seq(const bf16* __restrict__ AcT,
                                                 const bf16* __restrict__ Dc,
                                                 bf16* __restrict__ Sbuf) {
  __shared__ bf16 ST[64 * 72];
  const int bh = blockIdx.x;
  const int wave = threadIdx.x >> 6, lane = threadIdx.x & 63;
  const int frow = lane & 15, fk = (lane >> 4) * 8, cm = (lane >> 4) * 4;
  for (int i = threadIdx.x; i < 64 * 72 / 2; i += 256) ((unsigned int*)ST)[i] = 0u;
  f32x4 sacc[4] = {};
  const bf16* ac = AcT + (size_t)bh * NCH * 4096;
  const bf16* dc = Dc  + (size_t)bh * NCH * 4096;
  bf16* sb = Sbuf + (size_t)bh * NCH * 4096;
  #pragma unroll
  for (int n = 0; n < 4; ++n)
    #pragma unroll
    for (int r = 0; r < 4; ++r)
      sb[(16 * wave + cm + r) * 64 + 16 * n + frow] = __float2bfloat16(0.f);
  short8 bpre[4][2];
  float dpre[16];
  #pragma unroll
  for (int n = 0; n < 4; ++n) {
    bpre[n][0] = *(const short8*)(ac + (16 * n + frow) * 64 + fk);
    bpre[n][1] = *(const short8*)(ac + (16 * n + frow) * 64 + 32 + fk);
    #pragma unroll
    for (int r = 0; r < 4; ++r)
      dpre[n * 4 + r] = __bfloat162float(dc[(16 * wave + cm + r) * 64 + 16 * n + frow]);
  }
  __syncthreads();
  #pragma unroll 1
  for (int c = 0; c < NCH; ++c) {
    short8 a0 = *(const short8*)(ST + (16 * wave + frow) * 72 + fk);
    short8 a1 = *(const short8*)(ST + (16 * wave + frow) * 72 + 32 + fk);
    short8 bcur[4][2];
    float dcur[16];
    #pragma unroll
    for (int n = 0; n < 4; ++n) {
      bcur[n][0] = bpre[n][0]; bcur[n][1] = bpre[n][1];
      #pragma unroll
      for (int r = 0; r < 4; ++r) dcur[n * 4 + r] = dpre[n * 4 + r];
    }
    if (c + 1 < NCH) {
      const bf16* acn = ac + (size_t)(c + 1) * 4096;
      const bf16* dcn = dc + (size_t)(c + 1) * 4096;
      #pragma unroll
      for (int n = 0; n < 4; ++n) {
        bpre[n][0] = *(const short8*)(acn + (16 * n + frow) * 64 + fk);
        bpre[n][1] = *(const short8*)(acn + (16 * n + frow) * 64 + 32 + fk);
        #pragma unroll
        for (int r = 0; r < 4; ++r)
          dpre[n * 4 + r] = __bfloat162float(dcn[(16 * wave + cm + r) * 64 + 16 * n + frow]);
      }
    }
    #pragma unroll
    for (int n = 0; n < 4; ++n) {
      sacc[n] = __builtin_amdgcn_mfma_f32_16x16x32_bf16(a0, bcur[n][0], sacc[n], 0, 0, 0);
      sacc[n] = __builtin_amdgcn_mfma_f32_16x16x32_bf16(a1, bcur[n][1], sacc[n], 0, 0, 0);
      #pragma unroll
      for (int r = 0; r < 4; ++r) sacc[n][r] += dcur[n * 4 + r];
    }
    __syncthreads();
    #pragma unroll
    for (int n = 0; n < 4; ++n)
      #pragma unroll
      for (int r = 0; r < 4; ++r) {
        const bf16 sv = __float2bfloat16(sacc[n][r]);
        ST[(16 * wave + cm + r) * 72 + 16 * n + frow] = sv;
        if (c + 1 < NCH)
          sb[(size_t)(c + 1) * 4096 + (16 * wave + cm + r) * 64 + 16 * n + frow] = sv;
      }
    __syncthreads();
  }
}

// pass 3: chunk-parallel outputs. O = Q*S_c + tril(QK^T)*U_c, in place over q16.
__global__ __launch_bounds__(256) void chunk_out(bf16* __restrict__ q16,
                                                 const bf16* __restrict__ k16,
                                                 const bf16* __restrict__ v16,
                                                 const bf16* __restrict__ Gneg,
                                                 const bf16* __restrict__ Sbuf) {
  __shared__ bf16 UTs[64 * 72];
  __shared__ bf16 Pt[64 * 72];
  const int ch = blockIdx.x;
  const int c = ch & (NCH - 1), bh = ch >> 5;
  const int h = bh & (NH - 1), b = bh >> 5;
  const int tid = threadIdx.x, wave = tid >> 6, lane = tid & 63;
  const int frow = lane & 15, fk = (lane >> 4) * 8, cm = (lane >> 4) * 4;
  const size_t qkb = ((size_t)b * NT + c * 64) * ND + (size_t)h * 64;
  const bf16* Sb = Sbuf + (size_t)ch * 4096;
  const bf16* Gc = Gneg + (size_t)ch * 4096;
  {
    const int r0 = tid >> 2, sc2 = (tid & 3) * 16;
    *(short8*)(UTs + r0 * 72 + sc2)     = *(const short8*)(v16 + qkb + (size_t)r0 * ND + sc2);
    *(short8*)(UTs + r0 * 72 + sc2 + 8) = *(const short8*)(v16 + qkb + (size_t)r0 * ND + sc2 + 8);
  }
  short8 qa0 = *(const short8*)(q16 + qkb + (size_t)(16 * wave + frow) * ND + fk);
  short8 qa1 = *(const short8*)(q16 + qkb + (size_t)(16 * wave + frow) * ND + 32 + fk);
  f32x4 pacc[4];
  #pragma unroll
  for (int n = 0; n < 4; ++n) {
    f32x4 a = {};
    a = __builtin_amdgcn_mfma_f32_16x16x32_bf16(qa0, *(const short8*)(k16 + qkb + (size_t)(16 * n + frow) * ND + fk), a, 0, 0, 0);
    a = __builtin_amdgcn_mfma_f32_16x16x32_bf16(qa1, *(const short8*)(k16 + qkb + (size_t)(16 * n + frow) * ND + 32 + fk), a, 0, 0, 0);
    pacc[n] = a;
  }
  __syncthreads();
  f32x4 uacc[4];
  #pragma unroll
  for (int n = 0; n < 4; ++n)
    #pragma unroll
    for (int r = 0; r < 4; ++r)
      uacc[n][r] = __bfloat162float(UTs[(16 * wave + cm + r) * 72 + 16 * n + frow]);
  #pragma unroll
  for (int n = 0; n < 4; ++n)
    #pragma unroll
    for (int r = 0; r < 4; ++r) {
      const int mg = 16 * wave + cm + r, ng = 16 * n + frow;
      Pt[mg * 72 + ng] = __float2bfloat16(ng <= mg ? pacc[n][r] : 0.f);
    }
  short8 sa0 = *(const short8*)(Sb + (16 * wave + frow) * 64 + fk);
  short8 sa1 = *(const short8*)(Sb + (16 * wave + frow) * 64 + 32 + fk);
  #pragma unroll
  for (int n = 0; n < 4; ++n) {
    uacc[n] = __builtin_amdgcn_mfma_f32_16x16x32_bf16(sa0, *(const short8*)(Gc + (16 * n + frow) * 64 + fk), uacc[n], 0, 0, 0);
    uacc[n] = __builtin_amdgcn_mfma_f32_16x16x32_bf16(sa1, *(const short8*)(Gc + (16 * n + frow) * 64 + 32 + fk), uacc[n], 0, 0, 0);
  }
  __syncthreads();
  #pragma unroll
  for (int n = 0; n < 4; ++n)
    #pragma unroll
    for (int r = 0; r < 4; ++r)
      UTs[(16 * wave + cm + r) * 72 + 16 * n + frow] = __float2bfloat16(uacc[n][r]);
  __syncthreads();
  short8 pa0 = *(const short8*)(Pt + (16 * wave + frow) * 72 + fk);
  short8 pa1 = *(const short8*)(Pt + (16 * wave + frow) * 72 + 32 + fk);
  #pragma unroll
  for (int n = 0; n < 4; ++n) {
    f32x4 o = {};
    o = __builtin_amdgcn_mfma_f32_16x16x32_bf16(qa0, *(const short8*)(Sb + (16 * n + frow) * 64 + fk), o, 0, 0, 0);
    o = __builtin_amdgcn_mfma_f32_16x16x32_bf16(qa1, *(const short8*)(Sb + (16 * n + frow) * 64 + 32 + fk), o, 0, 0, 0);
    o = __builtin_amdgcn_mfma_f32_16x16x32_bf16(pa0, *(const short8*)(UTs + (16 * n + frow) * 72 + fk), o, 0, 0, 0);
    o = __builtin_amdgcn_mfma_f32_16x16x32_bf16(pa1, *(const short8*)(UTs + (16 * n + frow) * 72 + 32 + fk), o, 0, 0, 0);
    #pragma unroll
    for (int r = 0; r < 4; ++r)
      q16[qkb + (size_t)(16 * wave + cm + r) * ND + 16 * n + frow] = __float2bfloat16(o[r]);
  }
}

// ======================= compact-fallback chunk kernels (round-4 proven) =======================

__global__ __launch_bounds__(128) void chunk_scan_c(const bf16* __restrict__ k16,
                                                    bf16* __restrict__ v16,
                                                    const bf16* __restrict__ betab,
                                                    const void* __restrict__ bb,
                                                    const int* __restrict__ flag,
                                                    bf16* __restrict__ Gneg) {
  __shared__ bf16 Ks[64 * 64];
  __shared__ bf16 Vs[64 * 64];
  __shared__ bf16 Gs[64 * 64];
  __shared__ float Bs[64];
  const int ch = blockIdx.x;
  const int c = ch & (NCH - 1), bh = ch >> 5;
  const int h = bh & (NH - 1), b = bh >> 5;
  const int tid = threadIdx.x;
  const int wave = tid >> 6, lane = tid & 63;
  const size_t rowb = ((size_t)b * NT + c * 64) * ND + (size_t)h * 64;
  const int sr = tid >> 3, sc = (tid & 7) * 8;
  #pragma unroll
  for (int rnd = 0; rnd < 4; ++rnd) {
    const int r = rnd * 16 + sr;
    *(short8*)(Ks + r * 64 + sc) = *(const short8*)(k16 + rowb + (size_t)r * ND + sc);
    *(short8*)(Vs + r * 64 + sc) = *(const short8*)(v16 + rowb + (size_t)r * ND + sc);
  }
  if (tid < 64) {
    const float x = __bfloat162float(betab[((size_t)b * NT + c * 64 + tid) * 128 + h])
                    + loadf(bb, h, *flag);
    Bs[tid] = 1.f / (1.f + expf(-x));
  }
  __syncthreads();
  float S[64];
  #pragma unroll
  for (int i = 0; i < 64; ++i) S[i] = 0.f;
  const bf16* val_src = wave ? Ks : Vs;
  #pragma unroll 1
  for (int t = 0; t < 64; ++t) {
    uint4 ku[8];
    #pragma unroll
    for (int i = 0; i < 8; ++i) ku[i] = ((const uint4*)(Ks + t * 64))[i];
    const float val = __bfloat162float(val_src[t * 64 + lane]);
    const float bt = Bs[t];
    float kvf[64];
    #pragma unroll
    for (int i = 0; i < 8; ++i) {
      kvf[8*i+0] = __uint_as_float(ku[i].x << 16);
      kvf[8*i+1] = __uint_as_float(ku[i].x & 0xffff0000u);
      kvf[8*i+2] = __uint_as_float(ku[i].y << 16);
      kvf[8*i+3] = __uint_as_float(ku[i].y & 0xffff0000u);
      kvf[8*i+4] = __uint_as_float(ku[i].z << 16);
      kvf[8*i+5] = __uint_as_float(ku[i].z & 0xffff0000u);
      kvf[8*i+6] = __uint_as_float(ku[i].w << 16);
      kvf[8*i+7] = __uint_as_float(ku[i].w & 0xffff0000u);
    }
    float p0 = 0, p1 = 0, p2 = 0, p3 = 0;
    #pragma unroll
    for (int i = 0; i < 16; ++i) {
      p0 += kvf[4*i+0] * S[4*i+0];
      p1 += kvf[4*i+1] * S[4*i+1];
      p2 += kvf[4*i+2] * S[4*i+2];
      p3 += kvf[4*i+3] * S[4*i+3];
    }
    const float u = bt * (val - ((p0 + p1) + (p2 + p3)));
    #pragma unroll
    for (int i = 0; i < 16; ++i) {
      S[4*i+0] += kvf[4*i+0] * u;
      S[4*i+1] += kvf[4*i+1] * u;
      S[4*i+2] += kvf[4*i+2] * u;
      S[4*i+3] += kvf[4*i+3] * u;
    }
    if (wave) Gs[t * 64 + lane] = __float2bfloat16(-u);
    else      Vs[t * 64 + lane] = __float2bfloat16(u);
  }
  __syncthreads();
  bf16* gout = Gneg + (size_t)ch * 4096;
  #pragma unroll
  for (int rnd = 0; rnd < 4; ++rnd) {
    const int r = rnd * 16 + sr;
    *(short8*)(v16 + rowb + (size_t)r * ND + sc) = *(const short8*)(Vs + r * 64 + sc);
    *(short8*)(gout + r * 64 + sc)               = *(const short8*)(Gs + r * 64 + sc);
  }
}

__global__ __launch_bounds__(256) void chunk_seq_mono(bf16* q16,
                                                      const bf16* __restrict__ k16,
                                                      const bf16* __restrict__ Ul,
                                                      const bf16* __restrict__ Gneg) {
  __shared__ bf16 ST[64 * 72];
  __shared__ bf16 Ubt[64 * 72];
  __shared__ bf16 Pt[64 * 72];
  __shared__ bf16 KTl[64 * 72];
  const int bh = blockIdx.x, h = bh & (NH - 1), b = bh >> 5;
  const int wave = threadIdx.x >> 6, lane = threadIdx.x & 63;
  const int frow = lane & 15, q4 = lane >> 4, fk = q4 * 8;
  const int cm = q4 * 4;
  for (int i = threadIdx.x; i < 64 * 72 / 2; i += 256) ((unsigned int*)ST)[i] = 0u;
  __syncthreads();
  f32x4 sacc[4] = {};
  #pragma unroll 1
  for (int c = 0; c < NCH; ++c) {
    const bf16* Gc = Gneg + ((size_t)bh * NCH + c) * 4096;
    const size_t qkb = ((size_t)b * NT + c * 64) * ND + (size_t)h * 64;
    {
      short8 r0 = *(const short8*)(k16 + qkb + (size_t)lane * ND + 16 * wave);
      short8 r1 = *(const short8*)(k16 + qkb + (size_t)lane * ND + 16 * wave + 8);
      #pragma unroll
      for (int j = 0; j < 8; ++j) {
        KTl[(16 * wave + j) * 72 + lane]     = ((const bf16*)&r0)[j];
        KTl[(16 * wave + 8 + j) * 72 + lane] = ((const bf16*)&r1)[j];
      }
    }
    short8 ga0 = *(const short8*)(Gc + (16 * wave + frow) * 64 + fk);
    short8 ga1 = *(const short8*)(Gc + (16 * wave + frow) * 64 + 32 + fk);
    #pragma unroll
    for (int n = 0; n < 4; ++n) {
      f32x4 acc;
      #pragma unroll
      for (int r = 0; r < 4; ++r)
        acc[r] = __bfloat162float(Ul[qkb + (size_t)(16 * wave + cm + r) * ND + 16 * n + frow]);
      acc = __builtin_amdgcn_mfma_f32_16x16x32_bf16(ga0, *(const short8*)(ST + (16 * n + frow) * 72 + fk), acc, 0, 0, 0);
      acc = __builtin_amdgcn_mfma_f32_16x16x32_bf16(ga1, *(const short8*)(ST + (16 * n + frow) * 72 + 32 + fk), acc, 0, 0, 0);
      #pragma unroll
      for (int r = 0; r < 4; ++r)
        Ubt[(16 * n + frow) * 72 + 16 * wave + cm + r] = __float2bfloat16(acc[r]);
    }
    __syncthreads();
    short8 qa0 = *(const short8*)(q16 + qkb + (size_t)(16 * wave + frow) * ND + fk);
    short8 qa1 = *(const short8*)(q16 + qkb + (size_t)(16 * wave + frow) * ND + 32 + fk);
    #pragma unroll
    for (int n = 0; n < 4; ++n) {
      f32x4 acc = {};
      acc = __builtin_amdgcn_mfma_f32_16x16x32_bf16(qa0, *(const short8*)(k16 + qkb + (size_t)(16 * n + frow) * ND + fk), acc, 0, 0, 0);
      acc = __builtin_amdgcn_mfma_f32_16x16x32_bf16(qa1, *(const short8*)(k16 + qkb + (size_t)(16 * n + frow) * ND + 32 + fk), acc, 0, 0, 0);
      #pragma unroll
      for (int r = 0; r < 4; ++r) {
        const int mg = 16 * wave + cm + r, ng = 16 * n + frow;
        Pt[mg * 72 + ng] = __float2bfloat16(ng <= mg ? acc[r] : 0.f);
      }
    }
    __syncthreads();
    short8 pa0 = *(const short8*)(Pt + (16 * wave + frow) * 72 + fk);
    short8 pa1 = *(const short8*)(Pt + (16 * wave + frow) * 72 + 32 + fk);
    #pragma unroll
    for (int n = 0; n < 4; ++n) {
      f32x4 acc = {};
      acc = __builtin_amdgcn_mfma_f32_16x16x32_bf16(qa0, *(const short8*)(ST + (16 * n + frow) * 72 + fk), acc, 0, 0, 0);
      acc = __builtin_amdgcn_mfma_f32_16x16x32_bf16(qa1, *(const short8*)(ST + (16 * n + frow) * 72 + 32 + fk), acc, 0, 0, 0);
      acc = __builtin_amdgcn_mfma_f32_16x16x32_bf16(pa0, *(const short8*)(Ubt + (16 * n + frow) * 72 + fk), acc, 0, 0, 0);
      acc = __builtin_amdgcn_mfma_f32_16x16x32_bf16(pa1, *(const short8*)(Ubt + (16 * n + frow) * 72 + 32 + fk), acc, 0, 0, 0);
      #pragma unroll
      for (int r = 0; r < 4; ++r)
        q16[qkb + (size_t)(16 * wave + cm + r) * ND + 16 * n + frow] = __float2bfloat16(acc[r]);
    }
    __syncthreads();
    short8 ua0 = *(const short8*)(Ubt + (16 * wave + frow) * 72 + fk);
    short8 ua1 = *(const short8*)(Ubt + (16 * wave + frow) * 72 + 32 + fk);
    #pragma unroll
    for (int n = 0; n < 4; ++n) {
      sacc[n] = __builtin_amdgcn_mfma_f32_16x16x32_bf16(ua0, *(const short8*)(KTl + (16 * n + frow) * 72 + fk), sacc[n], 0, 0, 0);
      sacc[n] = __builtin_amdgcn_mfma_f32_16x16x32_bf16(ua1, *(const short8*)(KTl + (16 * n + frow) * 72 + 32 + fk), sacc[n], 0, 0, 0);
      #pragma unroll
      for (int r = 0; r < 4; ++r)
        ST[(16 * wave + cm + r) * 72 + 16 * n + frow] = __float2bfloat16(sacc[n][r]);
    }
    __syncthreads();
  }
}

extern "C" void kernel_launch(void* const* d_in, const int* in_sizes, int n_in,
                              void* d_out, int out_size, void* d_ws, size_t ws_size,
                              hipStream_t stream) {
  const void* hs = d_in[0];
  const void* Wq = d_in[1];
  const void* Wk = d_in[2];
  const void* Wv = d_in[3];
  const void* Wb = d_in[4];
  const void* bb = d_in[5];
  const void* Wo = d_in[6];

  char* ws = (char*)d_ws;
  size_t off = 0;
  auto alloc = [&](size_t bytes) {
    void* p = ws + off;
    off += (bytes + 255) & ~(size_t)255;
    return p;
  };
  const size_t szW2 = (size_t)32 * 1024 * 1024;  // WT (26.2 MiB weights) + AcT alias region
  const size_t szM  = (size_t)NM * ND * 2;       // 16 MiB
  const size_t szB2 = (size_t)NM * 256 * 2;      // 2 MiB (beta logits, 256-padded)
  const size_t szB  = (size_t)NM * 128 * 2;      // fallback beta (128-padded)
  const size_t need_fused = 512 + szW2 + 4 * szM + szB2 + szM;   // ~119.6 MB

  if (ws_size >= need_fused) {
    // ---- fused path ----
    int*  flag  = (int*) alloc(256);
    bf16* WT    = (bf16*)alloc(szW2);  // weights [0,26.2Mi); later Gneg [0,16Mi) + AcT [16,32Mi)
    bf16* hs16  = (bf16*)alloc(szM);   // -> Sbuf after fused GEMM
    bf16* q16   = (bf16*)alloc(szM);   // O in place
    bf16* k16   = (bf16*)alloc(szM);
    bf16* v16   = (bf16*)alloc(szM);   // U^T (transposed-in-place)
    bf16* betab = (bf16*)alloc(szB2);
    bf16* Dc    = (bf16*)alloc(szM);
    bf16* Gneg  = WT;                                    // [0,16MiB) dead after fused GEMM
    bf16* AcT   = WT + (size_t)8 * 1024 * 1024;          // [16,32MiB)
    bf16* WoT   = AcT;                                   // reused after state_seq
    bf16* Sbuf  = hs16;

    detect_dtype<<<1, 64, 0, stream>>>((const unsigned short*)hs, flag);
    convert_bf16<<<(NM * ND) / (256 * 8), 256, 0, stream>>>(hs, hs16, (long)NM * ND, flag);

    transpose_qkvb<<<dim3(32, 32, 4), 256, 0, stream>>>(Wq, Wk, Wv, Wb, WT, flag);
    gemm128<<<800, 512, 0, stream>>>(hs16, WT, q16, k16, v16, betab,
                                     nullptr, nullptr, ND, 25);

    chunk_scan<<<NB * NH * NCH, 256, 0, stream>>>(k16, v16, betab, bb, flag, Gneg, AcT, Dc);
    state_seq<<<NB * NH, 256, 0, stream>>>(AcT, Dc, Sbuf);
    chunk_out<<<NB * NH * NCH, 256, 0, stream>>>(q16, k16, v16, Gneg, Sbuf);

    transpose_cvt<<<dim3(32, 32), 256, 0, stream>>>(Wo, WoT, 2048, 2048, flag);
    gemm128o<<<512, 512, 0, stream>>>(q16, WoT, d_out, flag, ND, 16);
  } else {
    // ---- compact fallback (proven ~73 MB footprint) ----
    int*  flag  = (int*) alloc(256);
    bf16* Wt    = (bf16*)alloc((size_t)2048 * 2048 * 2);
    bf16* hs16  = (bf16*)alloc(szM);   // -> Gneg
    bf16* q16   = (bf16*)alloc(szM);
    bf16* k16   = (bf16*)alloc(szM);
    bf16* v16   = (bf16*)alloc(szM);
    bf16* betab = (bf16*)alloc(szB);
    bf16* Gneg  = hs16;

    detect_dtype<<<1, 64, 0, stream>>>((const unsigned short*)hs, flag);
    convert_bf16<<<(NM * ND) / (256 * 8), 256, 0, stream>>>(hs, hs16, (long)NM * ND, flag);

    transpose_cvt<<<dim3(32, 32), 256, 0, stream>>>(Wq, Wt, 2048, 2048, flag);
    gemm_bt<<<dim3(16, 32), 256, 0, stream>>>(hs16, Wt, q16, k16, v16, betab, nullptr, nullptr, NM, ND, 0);
    transpose_cvt<<<dim3(32, 32), 256, 0, stream>>>(Wk, Wt, 2048, 2048, flag);
    gemm_bt<<<dim3(16, 32), 256, 0, stream>>>(hs16, Wt, q16, k16, v16, betab, nullptr, nullptr, NM, ND, 2048);
    transpose_cvt<<<dim3(32, 32), 256, 0, stream>>>(Wv, Wt, 2048, 2048, flag);
    gemm_bt<<<dim3(16, 32), 256, 0, stream>>>(hs16, Wt, q16, k16, v16, betab, nullptr, nullptr, NM, ND, 4096);
    transpose_cvt<<<dim3(2, 32),  256, 0, stream>>>(Wb, Wt, 2048, 32, flag);
    gemm_bt<<<dim3(1, 32), 256, 0, stream>>>(hs16, Wt, q16, k16, v16, betab, nullptr, nullptr, NM, ND, 6144);

    chunk_scan_c<<<NB * NH * NCH, 128, 0, stream>>>(k16, v16, betab, bb, flag, Gneg);
    chunk_seq_mono<<<NB * NH, 256, 0, stream>>>(q16, k16, v16, Gneg);

    transpose_cvt<<<dim3(32, 32), 256, 0, stream>>>(Wo, Wt, 2048, 2048, flag);
    gemm_bt<<<dim3(16, 32), 256, 0, stream>>>(q16, Wt, nullptr, nullptr, nullptr, nullptr,
                                              d_out, flag, NM, ND, 0);
  }
}

// Round 8
// 523.064 us; speedup vs baseline: 1.1254x; 1.0394x over previous
//
#include <hip/hip_runtime.h>
#include <hip/hip_bf16.h>

typedef __hip_bfloat16 bf16;
typedef __attribute__((ext_vector_type(8))) short short8;   // 8 bf16 (4 VGPRs)
typedef __attribute__((ext_vector_type(4))) float f32x4;

#define NB 2
#define NT 2048
#define ND 2048
#define NH 32
#define NM (NB*NT)   // 4096 rows
#define NCH 32       // chunks per (b,h): NT/64

// ---- dtype hedge: inputs may be bf16 (harness-converted) or fp32 (per reference) ----
__global__ void detect_dtype(const unsigned short* __restrict__ hs, int* __restrict__ flag) {
  if (threadIdx.x == 0 && blockIdx.x == 0) {
    int cnt = 0;
    for (int i = 0; i < 2048; i += 2) {
      int e = (hs[i] >> 7) & 0xFF;
      if (e >= 141) ++cnt;
    }
    *flag = (cnt > 64) ? 1 : 0;   // 1 = fp32, 0 = bf16
  }
}

__device__ __forceinline__ float loadf(const void* p, size_t i, int isf32) {
  return isf32 ? ((const float*)p)[i] : __bfloat162float(((const bf16*)p)[i]);
}

__global__ __launch_bounds__(256) void convert_bf16(const void* __restrict__ src,
                                                    bf16* __restrict__ dst,
                                                    long n, const int* __restrict__ flag) {
  const long i0 = ((long)blockIdx.x * 256 + threadIdx.x) * 8;
  if (i0 >= n) return;
  if (*flag) {
    const float* s = (const float*)src;
    #pragma unroll
    for (int j = 0; j < 8; ++j) dst[i0 + j] = __float2bfloat16(s[i0 + j]);
  } else {
    *(short8*)(dst + i0) = *(const short8*)((const bf16*)src + i0);
  }
}

// ---- transpose + convert one matrix: dst[c][r] = bf16(src[r][c]); zero-pad cols ----
__global__ __launch_bounds__(256) void transpose_cvt(const void* __restrict__ src,
                                                     bf16* __restrict__ dst,
                                                     int src_rows, int src_cols,
                                                     const int* __restrict__ flag) {
  __shared__ bf16 tile[64][65];
  const int f = *flag;
  const int tb_r = blockIdx.y * 64, tb_c = blockIdx.x * 64;
  const int tx = threadIdx.x & 63, ty = threadIdx.x >> 6;
  #pragma unroll
  for (int i = 0; i < 64; i += 4) {
    const int cc = tb_c + tx;
    tile[i + ty][tx] = (cc < src_cols)
      ? __float2bfloat16(loadf(src, (size_t)(tb_r + i + ty) * src_cols + cc, f))
      : __float2bfloat16(0.f);
  }
  __syncthreads();
  #pragma unroll
  for (int i = 0; i < 64; i += 4)
    dst[(size_t)(tb_c + i + ty) * src_rows + tb_r + tx] = tile[tx][i + ty];
}

// ---- merged transpose of Wq/Wk/Wv/Wb into WT, z-sliced (beta block padded to 256 rows) ----
__global__ __launch_bounds__(256) void transpose_qkvb(const void* __restrict__ Wq,
                                                      const void* __restrict__ Wk,
                                                      const void* __restrict__ Wv,
                                                      const void* __restrict__ Wb,
                                                      bf16* __restrict__ WT,
                                                      const int* __restrict__ flag) {
  __shared__ bf16 tile[64][65];
  const int z = blockIdx.z;
  if (z == 3 && blockIdx.x >= 4) return;   // Wb^T: 256 padded rows
  const void* src = (z == 0) ? Wq : (z == 1) ? Wk : (z == 2) ? Wv : Wb;
  const int src_cols = (z == 3) ? 32 : 2048;
  bf16* dst = WT + (size_t)z * 2048 * 2048;
  const int f = *flag;
  const int tb_r = blockIdx.y * 64, tb_c = blockIdx.x * 64;
  const int tx = threadIdx.x & 63, ty = threadIdx.x >> 6;
  #pragma unroll
  for (int i = 0; i < 64; i += 4) {
    const int cc = tb_c + tx;
    tile[i + ty][tx] = (cc < src_cols)
      ? __float2bfloat16(loadf(src, (size_t)(tb_r + i + ty) * src_cols + cc, f))
      : __float2bfloat16(0.f);
  }
  __syncthreads();
  #pragma unroll
  for (int i = 0; i < 64; i += 4)
    dst[(size_t)(tb_c + i + ty) * 2048 + tb_r + tx] = tile[tx][i + ty];
}

// async 16B/lane global->LDS (wave-uniform LDS base + lane*16)
__device__ __forceinline__ void gload_lds16(const void* g, void* l) {
  __builtin_amdgcn_global_load_lds((__attribute__((address_space(1))) const void*)g,
                                   (__attribute__((address_space(3))) void*)l,
                                   16, 0, 0);
}

// ------------- legacy GEMM (fallback path only): C = A @ Bt^T -------------
__global__ __launch_bounds__(256) void gemm_bt(const bf16* __restrict__ A,
                                               const bf16* __restrict__ Bt,
                                               bf16* __restrict__ oq, bf16* __restrict__ ok2,
                                               bf16* __restrict__ ov, bf16* __restrict__ ob,
                                               void* __restrict__ outv,
                                               const int* __restrict__ outflag,
                                               int M, int K, int n_base) {
  __shared__ bf16 As[128 * 32];
  __shared__ bf16 Bs[128 * 32];
  const int tid = threadIdx.x;
  const int wave = tid >> 6, lane = tid & 63;
  const int m0 = blockIdx.y * 128, n0 = blockIdx.x * 128;
  const int wm = (wave >> 1) * 64, wn = (wave & 1) * 64;
  const int srow = lane >> 2, scol = (lane & 3) * 8;
  const int frow = lane & 15, fk = (lane >> 4) * 8;
  f32x4 acc[4][4] = {};

  for (int kb = 0; kb < K; kb += 32) {
    __syncthreads();
    #pragma unroll
    for (int j = 0; j < 2; ++j) {
      const int rbase = wave * 32 + j * 16;
      gload_lds16(A  + (size_t)(m0 + rbase + srow) * K + kb + scol, As + rbase * 32);
      gload_lds16(Bt + (size_t)(n0 + rbase + srow) * K + kb + scol, Bs + rbase * 32);
    }
    __syncthreads();
    short8 af[4], bfr[4];
    #pragma unroll
    for (int i = 0; i < 4; ++i)
      af[i] = *(const short8*)(As + (wm + i * 16 + frow) * 32 + fk);
    #pragma unroll
    for (int i = 0; i < 4; ++i)
      bfr[i] = *(const short8*)(Bs + (wn + i * 16 + frow) * 32 + fk);
    #pragma unroll
    for (int mi = 0; mi < 4; ++mi)
      #pragma unroll
      for (int ni = 0; ni < 4; ++ni)
        acc[mi][ni] = __builtin_amdgcn_mfma_f32_16x16x32_bf16(af[mi], bfr[ni], acc[mi][ni], 0, 0, 0);
  }

  const int crow = (lane >> 4) * 4, ccol = lane & 15;
  const int gn0 = n_base + n0;
  if (outflag) {
    const int f = *outflag;
    #pragma unroll
    for (int mi = 0; mi < 4; ++mi)
      #pragma unroll
      for (int ni = 0; ni < 4; ++ni)
        #pragma unroll
        for (int r = 0; r < 4; ++r) {
          const size_t idx = (size_t)(m0 + wm + mi * 16 + crow + r) * 2048 + gn0 + wn + ni * 16 + ccol;
          const float val = acc[mi][ni][r];
          if (f == 1) ((float*)outv)[idx] = val;
          else        ((bf16*)outv)[idx] = __float2bfloat16(val);
        }
  } else {
    const int seg = gn0 >> 11;
    bf16* o = (seg == 0) ? oq : (seg == 1) ? ok2 : (seg == 2) ? ov : ob;
    const int stride = (seg < 3) ? 2048 : 128;
    const int cb = (gn0 & 2047) + wn;
    if (seg <= 1) {
      #pragma unroll
      for (int mi = 0; mi < 4; ++mi)
        #pragma unroll
        for (int r = 0; r < 4; ++r) {
          float s = acc[mi][0][r] * acc[mi][0][r] + acc[mi][1][r] * acc[mi][1][r]
                  + acc[mi][2][r] * acc[mi][2][r] + acc[mi][3][r] * acc[mi][3][r];
          s += __shfl_xor(s, 1, 64); s += __shfl_xor(s, 2, 64);
          s += __shfl_xor(s, 4, 64); s += __shfl_xor(s, 8, 64);
          const float inv = rsqrtf(s + 1e-6f);
          #pragma unroll
          for (int ni = 0; ni < 4; ++ni) acc[mi][ni][r] *= inv;
        }
    }
    #pragma unroll
    for (int mi = 0; mi < 4; ++mi)
      #pragma unroll
      for (int ni = 0; ni < 4; ++ni)
        #pragma unroll
        for (int r = 0; r < 4; ++r)
          o[(size_t)(m0 + wm + mi * 16 + crow + r) * stride + cb + ni * 16 + ccol] =
            __float2bfloat16(acc[mi][ni][r]);
  }
}

// ============ 128x256 GEMM v2: 2 blocks/CU + TRIPLE buffer + counted vmcnt ============
// r6/r7 showed: 2 blocks/CU helps (+10%), zero conflicts neutral, but __syncthreads
// drains vmcnt(0) -> the 24 staging loads issued THIS K-step must complete before the
// barrier => ~1000 cyc exposed latency per 1680-cyc K-step. Fix: 3 LDS buffers, stage
// tile t+2 during iteration t, raw s_barrier + s_waitcnt vmcnt(3) (per-wave: 3 loads per
// STAGE; FIFO semantics [m135] => the older tile-(t+1) loads are proven complete while
// tile-(t+2)'s 3 stay in flight). Each staging batch gets ~2 K-steps (~3400 cyc) of slack.
// Hazards: frag reads of buf[t%3] guarded by the prior boundary vmcnt+barrier; WAR on
// buf[(t+2)%3]=buf[(t-1)%3] guarded by end-of-(t-1) barrier (its reads completed under
// lgkmcnt(0) before that barrier). Rule #18: sched_barrier(0) after each lgkmcnt wait.
__global__ __launch_bounds__(512, 4) void gemm128(const bf16* __restrict__ A,
                                                  const bf16* __restrict__ Bt,
                                                  bf16* __restrict__ oq, bf16* __restrict__ ok2,
                                                  bf16* __restrict__ ov, bf16* __restrict__ ob,
                                                  void* __restrict__ outv,
                                                  const int* __restrict__ outflag,
                                                  int K, int ntn) {
  __shared__ __align__(16) bf16 LA[3][128 * 32];   // 3 x 8 KB
  __shared__ __align__(16) bf16 LB[3][256 * 32];   // 3 x 16 KB  (total 72 KB -> 2 blocks/CU)
  const int tid = threadIdx.x;
  const int wave = tid >> 6, lane = tid & 63;
  const int wm = wave >> 2, wn = wave & 3;          // 2M x 4N
  const int frow = lane & 15, fq = lane >> 4;
  // ---- tile mapping ----
  int mtile, ntile;
  if (ntn == 25) {
    // supertile XCD mapping for the 32x25 grid (800 blocks; bijective, r5/r6-verified)
    const int x = (int)blockIdx.x & 7, r = (int)blockIdx.x >> 3;   // r in 0..99
    const int mg = x >> 2, ng = x & 3;
    if (ng == 0)      { mtile = mg * 16 + (r & 15);  ntile = r >> 4; }
    else if (r < 96)  { mtile = mg * 16 + (r & 15);  ntile = 1 + ng * 6 + (r >> 4); }
    else { const int r2 = 100 + (ng - 1) * 4 + (r - 96);
           mtile = mg * 16 + (r2 & 15); ntile = r2 >> 4; }
  } else {
    const int cpx = (int)gridDim.x >> 3;
    const int wg = ((int)blockIdx.x & 7) * cpx + ((int)blockIdx.x >> 3);
    mtile = wg / ntn; ntile = wg % ntn;
  }
  const int m0 = mtile * 128, n0 = ntile * 256;
  const int NTK = K >> 5;
  // 8-slot read swizzle (r7-verified zero-conflict): byte col = fq*16 ^ ((row>>1&3)<<4)
  const int fcol = (fq * 16) ^ (((frow >> 1) & 3) << 4);
  // staging: linear LDS dest (tid*16); inverse-swizzled source (same involution)
  const int q  = tid * 16;
  const int qs = q ^ (((q >> 7) & 3) << 4);
  const int sr = qs >> 6;            // row 0..127
  const int sc = (qs & 63) >> 1;     // elem col 0..31
  const int wofs = wave * 1024;      // per-wave linear LDS byte base

  f32x4 acc[4][4] = {};

  #define STAGE128(T, BUF)                                                          \
    do { const int kc = (T) * 32;                                                   \
      gload_lds16(A  + (size_t)(m0 + sr) * K + kc + sc,       (char*)LA[BUF] + wofs);\
      gload_lds16(Bt + (size_t)(n0 + sr) * K + kc + sc,       (char*)LB[BUF] + wofs);\
      gload_lds16(Bt + (size_t)(n0 + 128 + sr) * K + kc + sc, (char*)LB[BUF] + 8192 + wofs);\
    } while (0)

  // prologue: stage tiles 0 and 1; wait for tile 0 only (tile 1's 3 loads stay in flight)
  STAGE128(0, 0);
  if (NTK > 1) {
    STAGE128(1, 1);
    asm volatile("s_waitcnt vmcnt(3)" ::: "memory");
  } else {
    asm volatile("s_waitcnt vmcnt(0)" ::: "memory");
  }
  __builtin_amdgcn_s_barrier();

  int cur = 0, n2 = 2;   // n2 == (cur + 2) % 3
  #pragma unroll 1
  for (int t = 0; t < NTK; ++t) {
    const char* lA = (const char*)LA[cur];
    const char* lB = (const char*)LB[cur];
    short8 af[4], bfr[4];
    #pragma unroll
    for (int i = 0; i < 4; ++i)
      af[i] = *(const short8*)(lA + (wm * 64 + i * 16 + frow) * 64 + fcol);
    #pragma unroll
    for (int i = 0; i < 4; ++i)
      bfr[i] = *(const short8*)(lB + (wn * 64 + i * 16 + frow) * 64 + fcol);
    if (t + 2 < NTK) STAGE128(t + 2, n2);
    asm volatile("s_waitcnt lgkmcnt(0)" ::: "memory");
    __builtin_amdgcn_sched_barrier(0);
    #pragma unroll
    for (int mi = 0; mi < 4; ++mi)
      #pragma unroll
      for (int ni = 0; ni < 4; ++ni)
        acc[mi][ni] = __builtin_amdgcn_mfma_f32_16x16x32_bf16(af[mi], bfr[ni], acc[mi][ni], 0, 0, 0);
    if (t + 1 < NTK) {
      if (t + 2 < NTK) asm volatile("s_waitcnt vmcnt(3)" ::: "memory");  // t+1 resident
      else             asm volatile("s_waitcnt vmcnt(0)" ::: "memory");  // tail drain
      __builtin_amdgcn_s_barrier();
    }
    cur = (cur == 2) ? 0 : cur + 1;
    n2  = (n2 == 2) ? 0 : n2 + 1;
  }
  #undef STAGE128

  // epilogue
  const int crow = fq * 4, ccol = frow;
  const int rowb = m0 + wm * 64;
  if (outv) {
    const int f = *outflag;
    const int cb = n0 + wn * 64;
    #pragma unroll
    for (int mi = 0; mi < 4; ++mi)
      #pragma unroll
      for (int ni = 0; ni < 4; ++ni)
        #pragma unroll
        for (int r = 0; r < 4; ++r) {
          const size_t idx = (size_t)(rowb + mi * 16 + crow + r) * 2048 + cb + ni * 16 + ccol;
          const float val = acc[mi][ni][r];
          if (f == 1) ((float*)outv)[idx] = val;
          else        ((bf16*)outv)[idx] = __float2bfloat16(val);
        }
    return;
  }
  // routed epilogue: seg 0/1 l2norm per 64-col head, 2 plain, 3 beta (stride 256)
  const int gn0w = n0 + wn * 64;
  const int seg = gn0w >> 11;
  bf16* o = (seg == 0) ? oq : (seg == 1) ? ok2 : (seg == 2) ? ov : ob;
  const int stride = (seg < 3) ? 2048 : 256;
  const int cb = (seg < 3) ? (gn0w & 2047) : (gn0w - 6144);
  if (seg <= 1) {
    #pragma unroll
    for (int mi = 0; mi < 4; ++mi)
      #pragma unroll
      for (int r = 0; r < 4; ++r) {
        float s = acc[mi][0][r] * acc[mi][0][r] + acc[mi][1][r] * acc[mi][1][r]
                + acc[mi][2][r] * acc[mi][2][r] + acc[mi][3][r] * acc[mi][3][r];
        s += __shfl_xor(s, 1, 64); s += __shfl_xor(s, 2, 64);
        s += __shfl_xor(s, 4, 64); s += __shfl_xor(s, 8, 64);
        const float inv = rsqrtf(s + 1e-6f);
        #pragma unroll
        for (int ni = 0; ni < 4; ++ni) acc[mi][ni][r] *= inv;
      }
  }
  #pragma unroll
  for (int mi = 0; mi < 4; ++mi)
    #pragma unroll
    for (int ni = 0; ni < 4; ++ni)
      #pragma unroll
      for (int r = 0; r < 4; ++r)
        o[(size_t)(rowb + mi * 16 + crow + r) * stride + cb + ni * 16 + ccol] =
          __float2bfloat16(acc[mi][ni][r]);
}

// ============ 128x128 out-projection GEMM v2: triple-buffer + counted vmcnt ============
// 8 waves as 4M x 2N (per-wave 32x64, acc = 32 regs), BK=32, 48 KB LDS (3 bufs).
// STAGE = 2 loads/wave -> boundary vmcnt(2). outv-only epilogue.
__global__ __launch_bounds__(512, 4) void gemm128o(const bf16* __restrict__ A,
                                                   const bf16* __restrict__ Bt,
                                                   void* __restrict__ outv,
                                                   const int* __restrict__ outflag,
                                                   int K, int ntn) {
  __shared__ __align__(16) bf16 LA[3][128 * 32];   // 3 x 8 KB
  __shared__ __align__(16) bf16 LB[3][128 * 32];   // 3 x 8 KB
  const int tid = threadIdx.x;
  const int wave = tid >> 6, lane = tid & 63;
  const int wm = wave >> 1, wn = wave & 1;          // 4M x 2N
  const int frow = lane & 15, fq = lane >> 4;
  const int cpx = (int)gridDim.x >> 3;
  const int wg = ((int)blockIdx.x & 7) * cpx + ((int)blockIdx.x >> 3);
  const int mtile = wg / ntn, ntile = wg % ntn;
  const int m0 = mtile * 128, n0 = ntile * 128;
  const int NTK = K >> 5;
  const int fcol = (fq * 16) ^ (((frow >> 1) & 3) << 4);
  const int q  = tid * 16;
  const int qs = q ^ (((q >> 7) & 3) << 4);
  const int sr = qs >> 6, sc = (qs & 63) >> 1;
  const int wofs = wave * 1024;

  f32x4 acc[2][4] = {};

  #define STAGEO(T, BUF)                                                            \
    do { const int kc = (T) * 32;                                                   \
      gload_lds16(A  + (size_t)(m0 + sr) * K + kc + sc, (char*)LA[BUF] + wofs);     \
      gload_lds16(Bt + (size_t)(n0 + sr) * K + kc + sc, (char*)LB[BUF] + wofs);     \
    } while (0)

  STAGEO(0, 0);
  if (NTK > 1) {
    STAGEO(1, 1);
    asm volatile("s_waitcnt vmcnt(2)" ::: "memory");
  } else {
    asm volatile("s_waitcnt vmcnt(0)" ::: "memory");
  }
  __builtin_amdgcn_s_barrier();

  int cur = 0, n2 = 2;
  #pragma unroll 1
  for (int t = 0; t < NTK; ++t) {
    const char* lA = (const char*)LA[cur];
    const char* lB = (const char*)LB[cur];
    short8 af[2], bfr[4];
    #pragma unroll
    for (int i = 0; i < 2; ++i)
      af[i] = *(const short8*)(lA + (wm * 32 + i * 16 + frow) * 64 + fcol);
    #pragma unroll
    for (int i = 0; i < 4; ++i)
      bfr[i] = *(const short8*)(lB + (wn * 64 + i * 16 + frow) * 64 + fcol);
    if (t + 2 < NTK) STAGEO(t + 2, n2);
    asm volatile("s_waitcnt lgkmcnt(0)" ::: "memory");
    __builtin_amdgcn_sched_barrier(0);
    #pragma unroll
    for (int mi = 0; mi < 2; ++mi)
      #pragma unroll
      for (int ni = 0; ni < 4; ++ni)
        acc[mi][ni] = __builtin_amdgcn_mfma_f32_16x16x32_bf16(af[mi], bfr[ni], acc[mi][ni], 0, 0, 0);
    if (t + 1 < NTK) {
      if (t + 2 < NTK) asm volatile("s_waitcnt vmcnt(2)" ::: "memory");
      else             asm volatile("s_waitcnt vmcnt(0)" ::: "memory");
      __builtin_amdgcn_s_barrier();
    }
    cur = (cur == 2) ? 0 : cur + 1;
    n2  = (n2 == 2) ? 0 : n2 + 1;
  }
  #undef STAGEO

  const int crow = fq * 4, ccol = frow;
  const int rowb = m0 + wm * 32;
  const int cb = n0 + wn * 64;
  const int f = *outflag;
  #pragma unroll
  for (int mi = 0; mi < 2; ++mi)
    #pragma unroll
    for (int ni = 0; ni < 4; ++ni)
      #pragma unroll
      for (int r = 0; r < 4; ++r) {
        const size_t idx = (size_t)(rowb + mi * 16 + crow + r) * 2048 + cb + ni * 16 + ccol;
        const float val = acc[mi][ni][r];
        if (f == 1) ((float*)outv)[idx] = val;
        else        ((bf16*)outv)[idx] = __float2bfloat16(val);
      }
}

// ======================= fused-path chunk kernels =======================

template<int TB>
__device__ __forceinline__ void scan16(const float* __restrict__ Af,
                                       const bf16* __restrict__ vsrc,
                                       const float* __restrict__ Bsc,
                                       float (&u)[64], const int lane, const int wave,
                                       const float sgn,
                                       bf16* __restrict__ outT,
                                       bf16* __restrict__ gout) {
  constexpr int JM = (TB + 1) * 16;
  #pragma unroll
  for (int tt = 0; tt < 16; ++tt) {
    const int t = TB * 16 + tt;
    float pr0 = 0.f, pr1 = 0.f, pr2 = 0.f, pr3 = 0.f;
    #pragma unroll
    for (int i = 0; i < JM; i += 4) {
      const f32x4 a = *(const f32x4*)(Af + t * 64 + i);   // wave-uniform row read
      pr0 = __builtin_fmaf(a[0], u[i + 0], pr0);
      pr1 = __builtin_fmaf(a[1], u[i + 1], pr1);
      pr2 = __builtin_fmaf(a[2], u[i + 2], pr2);
      pr3 = __builtin_fmaf(a[3], u[i + 3], pr3);
    }
    const float ut = Bsc[t] * __bfloat162float(vsrc[t * 72 + lane])
                   - ((pr0 + pr1) + (pr2 + pr3));
    u[t] = ut;
    const bf16 sv = __float2bfloat16(sgn * ut);
    outT[lane * 72 + t] = sv;
    if (wave) gout[t * 64 + lane] = sv;
  }
}

// pass 1: A = beta*tril(K K^T) via MFMA (fp32 LDS), then two register forward substitutions.
__global__ __launch_bounds__(256) void chunk_scan(const bf16* __restrict__ k16,
                                                  bf16* __restrict__ v16,
                                                  const bf16* __restrict__ betab,
                                                  const void* __restrict__ bb,
                                                  const int* __restrict__ flag,
                                                  bf16* __restrict__ Gneg,
                                                  bf16* __restrict__ AcT,
                                                  bf16* __restrict__ Dc) {
  __shared__ bf16 Ks[64 * 72];
  __shared__ bf16 Vs[64 * 72];
  __shared__ bf16 GsT[64 * 72];
  __shared__ bf16 UsT[64 * 72];
  __shared__ float Af[64 * 64];
  __shared__ float Bsc[64];
  bf16* const KTs = (bf16*)Af;
  const int ch = blockIdx.x;
  const int c = ch & (NCH - 1), bh = ch >> 5;
  const int h = bh & (NH - 1), b = bh >> 5;
  const int tid = threadIdx.x, wave = tid >> 6, lane = tid & 63;
  const size_t rowb = ((size_t)b * NT + c * 64) * ND + (size_t)h * 64;

  short8 ktA0, ktB0, ktA1, ktB1;
  if (wave >= 2) {
    const int d0a = (wave - 2) * 16, d0b = d0a + 32;
    ktA0 = *(const short8*)(k16 + rowb + (size_t)lane * ND + d0a);
    ktB0 = *(const short8*)(k16 + rowb + (size_t)lane * ND + d0a + 8);
    ktA1 = *(const short8*)(k16 + rowb + (size_t)lane * ND + d0b);
    ktB1 = *(const short8*)(k16 + rowb + (size_t)lane * ND + d0b + 8);
  }
  {
    const int r0 = tid >> 3, sc = (tid & 7) * 8;
    #pragma unroll
    for (int rnd = 0; rnd < 2; ++rnd) {
      const int r = rnd * 32 + r0;
      *(short8*)(Ks + r * 72 + sc) = *(const short8*)(k16 + rowb + (size_t)r * ND + sc);
      *(short8*)(Vs + r * 72 + sc) = *(const short8*)(v16 + rowb + (size_t)r * ND + sc);
    }
  }
  if (tid < 64) {
    const float x = __bfloat162float(betab[((size_t)b * NT + c * 64 + tid) * 256 + h])
                    + loadf(bb, h, *flag);
    Bsc[tid] = 1.f / (1.f + expf(-x));
  }
  __syncthreads();

  const int frow = lane & 15, fk = (lane >> 4) * 8, cm = (lane >> 4) * 4;
  {
    short8 ma0 = *(const short8*)(Ks + (16 * wave + frow) * 72 + fk);
    short8 ma1 = *(const short8*)(Ks + (16 * wave + frow) * 72 + 32 + fk);
    #pragma unroll
    for (int n = 0; n < 4; ++n) {
      f32x4 m = {};
      m = __builtin_amdgcn_mfma_f32_16x16x32_bf16(ma0, *(const short8*)(Ks + (16 * n + frow) * 72 + fk), m, 0, 0, 0);
      m = __builtin_amdgcn_mfma_f32_16x16x32_bf16(ma1, *(const short8*)(Ks + (16 * n + frow) * 72 + 32 + fk), m, 0, 0, 0);
      #pragma unroll
      for (int r = 0; r < 4; ++r) {
        const int t = 16 * wave + cm + r, s = 16 * n + frow;
        Af[t * 64 + s] = (s < t) ? Bsc[t] * m[r] : 0.f;
      }
    }
  }
  __syncthreads();

  if (wave < 2) {
    float u[64];
    #pragma unroll
    for (int i = 0; i < 64; ++i) u[i] = 0.f;
    const bf16* vsrc = wave ? Ks : Vs;
    bf16* outT = wave ? GsT : UsT;
    bf16* gout = Gneg + (size_t)ch * 4096;
    const float sgn = wave ? -1.f : 1.f;
    scan16<0>(Af, vsrc, Bsc, u, lane, wave, sgn, outT, gout);
    scan16<1>(Af, vsrc, Bsc, u, lane, wave, sgn, outT, gout);
    scan16<2>(Af, vsrc, Bsc, u, lane, wave, sgn, outT, gout);
    scan16<3>(Af, vsrc, Bsc, u, lane, wave, sgn, outT, gout);
  }
  __syncthreads();

  if (wave >= 2) {
    const int d0a = (wave - 2) * 16, d0b = d0a + 32;
    #pragma unroll
    for (int j = 0; j < 8; ++j) {
      KTs[(d0a + j) * 72 + lane]     = ((const bf16*)&ktA0)[j];
      KTs[(d0a + 8 + j) * 72 + lane] = ((const bf16*)&ktB0)[j];
      KTs[(d0b + j) * 72 + lane]     = ((const bf16*)&ktA1)[j];
      KTs[(d0b + 8 + j) * 72 + lane] = ((const bf16*)&ktB1)[j];
    }
  }
  __syncthreads();

  short8 ka0 = *(const short8*)(KTs + (16 * wave + frow) * 72 + fk);
  short8 ka1 = *(const short8*)(KTs + (16 * wave + frow) * 72 + 32 + fk);
  short8 uu0 = *(const short8*)(UsT + (16 * wave + frow) * 72 + fk);
  short8 uu1 = *(const short8*)(UsT + (16 * wave + frow) * 72 + 32 + fk);
  #pragma unroll
  for (int n = 0; n < 4; ++n) {
    f32x4 aA = {}, aD = {};
    aA = __builtin_amdgcn_mfma_f32_16x16x32_bf16(ka0, *(const short8*)(GsT + (16 * n + frow) * 72 + fk), aA, 0, 0, 0);
    aA = __builtin_amdgcn_mfma_f32_16x16x32_bf16(ka1, *(const short8*)(GsT + (16 * n + frow) * 72 + 32 + fk), aA, 0, 0, 0);
    aD = __builtin_amdgcn_mfma_f32_16x16x32_bf16(uu0, *(const short8*)(KTs + (16 * n + frow) * 72 + fk), aD, 0, 0, 0);
    aD = __builtin_amdgcn_mfma_f32_16x16x32_bf16(uu1, *(const short8*)(KTs + (16 * n + frow) * 72 + 32 + fk), aD, 0, 0, 0);
    #pragma unroll
    for (int r = 0; r < 4; ++r) {
      Vs[(16 * wave + cm + r) * 64 + 16 * n + frow] = __float2bfloat16(aA[r]);
      Ks[(16 * wave + cm + r) * 64 + 16 * n + frow] = __float2bfloat16(aD[r]);
    }
  }
  __syncthreads();
  {
    const int r0 = tid >> 2, sc2 = (tid & 3) * 16;
    bf16* acg = AcT + (size_t)ch * 4096;
    bf16* dcg = Dc  + (size_t)ch * 4096;
    *(short8*)(acg + r0 * 64 + sc2)     = *(const short8*)(Vs + r0 * 64 + sc2);
    *(short8*)(acg + r0 * 64 + sc2 + 8) = *(const short8*)(Vs + r0 * 64 + sc2 + 8);
    *(short8*)(dcg + r0 * 64 + sc2)     = *(const short8*)(Ks + r0 * 64 + sc2);
    *(short8*)(dcg + r0 * 64 + sc2 + 8) = *(const short8*)(Ks + r0 * 64 + sc2 + 8);
    *(short8*)(v16 + rowb + (size_t)r0 * ND + sc2)     = *(const short8*)(UsT + r0 * 72 + sc2);
    *(short8*)(v16 + rowb + (size_t)r0 * ND + sc2 + 8) = *(const short8*)(UsT + r0 * 72 + sc2 + 8);
  }
}

// pass 2: minimal serial recurrence: sacc(fp32) += S_bf16 @ AcT^T + Dc, per chunk.
__global__ __launch_bounds__(256) void state_seq(const bf16* __restrict__ AcT,
                                                 const bf16* __restrict__ Dc,
                                                 bf16* __restrict__ Sbuf) {
  __shared__ bf16 ST[64 * 72];
  const int bh = blockIdx.x;
  const int wave = threadIdx.x >> 6, lane = threadIdx.x & 63;
  const int frow = lane & 15, fk = (lane >> 4) * 8, cm = (lane >> 4) * 4;
  for (int i = threadIdx.x; i < 64 * 72 / 2; i += 256) ((unsigned int*)ST)[i] = 0u;
  f32x4 sacc[4] = {};
  const bf16* ac = AcT + (size_t)bh * NCH * 4096;
  const bf16* dc = Dc  + (size_t)bh * NCH * 4096;
  bf16* sb = Sbuf + (size_t)bh * NCH * 4096;
  #pragma unroll
  for (int n = 0; n < 4; ++n)
    #pragma unroll
    for (int r = 0; r < 4; ++r)
      sb[(16 * wave + cm + r) * 64 + 16 * n + frow] = __float2bfloat16(0.f);
  short8 bpre[4][2];
  float dpre[16];
  #pragma unroll
  for (int n = 0; n < 4; ++n) {
    bpre[n][0] = *(const short8*)(ac + (16 * n + frow) * 64 + fk);
    bpre[n][1] = *(const short8*)(ac + (16 * n + frow) * 64 + 32 + fk);
    #pragma unroll
    for (int r = 0; r < 4; ++r)
      dpre[n * 4 + r] = __bfloat162float(dc[(16 * wave + cm + r) * 64 + 16 * n + frow]);
  }
  __syncthreads();
  #pragma unroll 1
  for (int c = 0; c < NCH; ++c) {
    short8 a0 = *(const short8*)(ST + (16 * wave + frow) * 72 + fk);
    short8 a1 = *(const short8*)(ST + (16 * wave + frow) * 72 + 32 + fk);
    short8 bcur[4][2];
    float dcur[16];
    #pragma unroll
    for (int n = 0; n < 4; ++n) {
      bcur[n][0] = bpre[n][0]; bcur[n][1] = bpre[n][1];
      #pragma unroll
      for (int r = 0; r < 4; ++r) dcur[n * 4 + r] = dpre[n * 4 + r];
    }
    if (c + 1 < NCH) {
      const bf16* acn = ac + (size_t)(c + 1) * 4096;
      const bf16* dcn = dc + (size_t)(c + 1) * 4096;
      #pragma unroll
      for (int n = 0; n < 4; ++n) {
        bpre[n][0] = *(const short8*)(acn + (16 * n + frow) * 64 + fk);
        bpre[n][1] = *(const short8*)(acn + (16 * n + frow) * 64 + 32 + fk);
        #pragma unroll
        for (int r = 0; r < 4; ++r)
          dpre[n * 4 + r] = __bfloat162float(dcn[(16 * wave + cm + r) * 64 + 16 * n + frow]);
      }
    }
    #pragma unroll
    for (int n = 0; n < 4; ++n) {
      sacc[n] = __builtin_amdgcn_mfma_f32_16x16x32_bf16(a0, bcur[n][0], sacc[n], 0, 0, 0);
      sacc[n] = __builtin_amdgcn_mfma_f32_16x16x32_bf16(a1, bcur[n][1], sacc[n], 0, 0, 0);
      #pragma unroll
      for (int r = 0; r < 4; ++r) sacc[n][r] += dcur[n * 4 + r];
    }
    __syncthreads();
    #pragma unroll
    for (int n = 0; n < 4; ++n)
      #pragma unroll
      for (int r = 0; r < 4; ++r) {
        const bf16 sv = __float2bfloat16(sacc[n][r]);
        ST[(16 * wave + cm + r) * 72 + 16 * n + frow] = sv;
        if (c + 1 < NCH)
          sb[(size_t)(c + 1) * 4096 + (16 * wave + cm + r) * 64 + 16 * n + frow] = sv;
      }
    __syncthreads();
  }
}

// pass 3: chunk-parallel outputs. O = Q*S_c + tril(QK^T)*U_c, in place over q16.
__global__ __launch_bounds__(256) void chunk_out(bf16* __restrict__ q16,
                                                 const bf16* __restrict__ k16,
                                                 const bf16* __restrict__ v16,
                                                 const bf16* __restrict__ Gneg,
                                                 const bf16* __restrict__ Sbuf) {
  __shared__ bf16 UTs[64 * 72];
  __shared__ bf16 Pt[64 * 72];
  const int ch = blockIdx.x;
  const int c = ch & (NCH - 1), bh = ch >> 5;
  const int h = bh & (NH - 1), b = bh >> 5;
  const int tid = threadIdx.x, wave = tid >> 6, lane = tid & 63;
  const int frow = lane & 15, fk = (lane >> 4) * 8, cm = (lane >> 4) * 4;
  const size_t qkb = ((size_t)b * NT + c * 64) * ND + (size_t)h * 64;
  const bf16* Sb = Sbuf + (size_t)ch * 4096;
  const bf16* Gc = Gneg + (size_t)ch * 4096;
  {
    const int r0 = tid >> 2, sc2 = (tid & 3) * 16;
    *(short8*)(UTs + r0 * 72 + sc2)     = *(const short8*)(v16 + qkb + (size_t)r0 * ND + sc2);
    *(short8*)(UTs + r0 * 72 + sc2 + 8) = *(const short8*)(v16 + qkb + (size_t)r0 * ND + sc2 + 8);
  }
  short8 qa0 = *(const short8*)(q16 + qkb + (size_t)(16 * wave + frow) * ND + fk);
  short8 qa1 = *(const short8*)(q16 + qkb + (size_t)(16 * wave + frow) * ND + 32 + fk);
  f32x4 pacc[4];
  #pragma unroll
  for (int n = 0; n < 4; ++n) {
    f32x4 a = {};
    a = __builtin_amdgcn_mfma_f32_16x16x32_bf16(qa0, *(const short8*)(k16 + qkb + (size_t)(16 * n + frow) * ND + fk), a, 0, 0, 0);
    a = __builtin_amdgcn_mfma_f32_16x16x32_bf16(qa1, *(const short8*)(k16 + qkb + (size_t)(16 * n + frow) * ND + 32 + fk), a, 0, 0, 0);
    pacc[n] = a;
  }
  __syncthreads();
  f32x4 uacc[4];
  #pragma unroll
  for (int n = 0; n < 4; ++n)
    #pragma unroll
    for (int r = 0; r < 4; ++r)
      uacc[n][r] = __bfloat162float(UTs[(16 * wave + cm + r) * 72 + 16 * n + frow]);
  #pragma unroll
  for (int n = 0; n < 4; ++n)
    #pragma unroll
    for (int r = 0; r < 4; ++r) {
      const int mg = 16 * wave + cm + r, ng = 16 * n + frow;
      Pt[mg * 72 + ng] = __float2bfloat16(ng <= mg ? pacc[n][r] : 0.f);
    }
  short8 sa0 = *(const short8*)(Sb + (16 * wave + frow) * 64 + fk);
  short8 sa1 = *(const short8*)(Sb + (16 * wave + frow) * 64 + 32 + fk);
  #pragma unroll
  for (int n = 0; n < 4; ++n) {
    uacc[n] = __builtin_amdgcn_mfma_f32_16x16x32_bf16(sa0, *(const short8*)(Gc + (16 * n + frow) * 64 + fk), uacc[n], 0, 0, 0);
    uacc[n] = __builtin_amdgcn_mfma_f32_16x16x32_bf16(sa1, *(const short8*)(Gc + (16 * n + frow) * 64 + 32 + fk), uacc[n], 0, 0, 0);
  }
  __syncthreads();
  #pragma unroll
  for (int n = 0; n < 4; ++n)
    #pragma unroll
    for (int r = 0; r < 4; ++r)
      UTs[(16 * wave + cm + r) * 72 + 16 * n + frow] = __float2bfloat16(uacc[n][r]);
  __syncthreads();
  short8 pa0 = *(const short8*)(Pt + (16 * wave + frow) * 72 + fk);
  short8 pa1 = *(const short8*)(Pt + (16 * wave + frow) * 72 + 32 + fk);
  #pragma unroll
  for (int n = 0; n < 4; ++n) {
    f32x4 o = {};
    o = __builtin_amdgcn_mfma_f32_16x16x32_bf16(qa0, *(const short8*)(Sb + (16 * n + frow) * 64 + fk), o, 0, 0, 0);
    o = __builtin_amdgcn_mfma_f32_16x16x32_bf16(qa1, *(const short8*)(Sb + (16 * n + frow) * 64 + 32 + fk), o, 0, 0, 0);
    o = __builtin_amdgcn_mfma_f32_16x16x32_bf16(pa0, *(const short8*)(UTs + (16 * n + frow) * 72 + fk), o, 0, 0, 0);
    o = __builtin_amdgcn_mfma_f32_16x16x32_bf16(pa1, *(const short8*)(UTs + (16 * n + frow) * 72 + 32 + fk), o, 0, 0, 0);
    #pragma unroll
    for (int r = 0; r < 4; ++r)
      q16[qkb + (size_t)(16 * wave + cm + r) * ND + 16 * n + frow] = __float2bfloat16(o[r]);
  }
}

// ======================= compact-fallback chunk kernels (round-4 proven) =======================

__global__ __launch_bounds__(128) void chunk_scan_c(const bf16* __restrict__ k16,
                                                    bf16* __restrict__ v16,
                                                    const bf16* __restrict__ betab,
                                                    const void* __restrict__ bb,
                                                    const int* __restrict__ flag,
                                                    bf16* __restrict__ Gneg) {
  __shared__ bf16 Ks[64 * 64];
  __shared__ bf16 Vs[64 * 64];
  __shared__ bf16 Gs[64 * 64];
  __shared__ float Bs[64];
  const int ch = blockIdx.x;
  const int c = ch & (NCH - 1), bh = ch >> 5;
  const int h = bh & (NH - 1), b = bh >> 5;
  const int tid = threadIdx.x;
  const int wave = tid >> 6, lane = tid & 63;
  const size_t rowb = ((size_t)b * NT + c * 64) * ND + (size_t)h * 64;
  const int sr = tid >> 3, sc = (tid & 7) * 8;
  #pragma unroll
  for (int rnd = 0; rnd < 4; ++rnd) {
    const int r = rnd * 16 + sr;
    *(short8*)(Ks + r * 64 + sc) = *(const short8*)(k16 + rowb + (size_t)r * ND + sc);
    *(short8*)(Vs + r * 64 + sc) = *(const short8*)(v16 + rowb + (size_t)r * ND + sc);
  }
  if (tid < 64) {
    const float x = __bfloat162float(betab[((size_t)b * NT + c * 64 + tid) * 128 + h])
                    + loadf(bb, h, *flag);
    Bs[tid] = 1.f / (1.f + expf(-x));
  }
  __syncthreads();
  float S[64];
  #pragma unroll
  for (int i = 0; i < 64; ++i) S[i] = 0.f;
  const bf16* val_src = wave ? Ks : Vs;
  #pragma unroll 1
  for (int t = 0; t < 64; ++t) {
    uint4 ku[8];
    #pragma unroll
    for (int i = 0; i < 8; ++i) ku[i] = ((const uint4*)(Ks + t * 64))[i];
    const float val = __bfloat162float(val_src[t * 64 + lane]);
    const float bt = Bs[t];
    float kvf[64];
    #pragma unroll
    for (int i = 0; i < 8; ++i) {
      kvf[8*i+0] = __uint_as_float(ku[i].x << 16);
      kvf[8*i+1] = __uint_as_float(ku[i].x & 0xffff0000u);
      kvf[8*i+2] = __uint_as_float(ku[i].y << 16);
      kvf[8*i+3] = __uint_as_float(ku[i].y & 0xffff0000u);
      kvf[8*i+4] = __uint_as_float(ku[i].z << 16);
      kvf[8*i+5] = __uint_as_float(ku[i].z & 0xffff0000u);
      kvf[8*i+6] = __uint_as_float(ku[i].w << 16);
      kvf[8*i+7] = __uint_as_float(ku[i].w & 0xffff0000u);
    }
    float p0 = 0, p1 = 0, p2 = 0, p3 = 0;
    #pragma unroll
    for (int i = 0; i < 16; ++i) {
      p0 += kvf[4*i+0] * S[4*i+0];
      p1 += kvf[4*i+1] * S[4*i+1];
      p2 += kvf[4*i+2] * S[4*i+2];
      p3 += kvf[4*i+3] * S[4*i+3];
    }
    const float u = bt * (val - ((p0 + p1) + (p2 + p3)));
    #pragma unroll
    for (int i = 0; i < 16; ++i) {
      S[4*i+0] += kvf[4*i+0] * u;
      S[4*i+1] += kvf[4*i+1] * u;
      S[4*i+2] += kvf[4*i+2] * u;
      S[4*i+3] += kvf[4*i+3] * u;
    }
    if (wave) Gs[t * 64 + lane] = __float2bfloat16(-u);
    else      Vs[t * 64 + lane] = __float2bfloat16(u);
  }
  __syncthreads();
  bf16* gout = Gneg + (size_t)ch * 4096;
  #pragma unroll
  for (int rnd = 0; rnd < 4; ++rnd) {
    const int r = rnd * 16 + sr;
    *(short8*)(v16 + rowb + (size_t)r * ND + sc) = *(const short8*)(Vs + r * 64 + sc);
    *(short8*)(gout + r * 64 + sc)               = *(const short8*)(Gs + r * 64 + sc);
  }
}

__global__ __launch_bounds__(256) void chunk_seq_mono(bf16* q16,
                                                      const bf16* __restrict__ k16,
                                                      const bf16* __restrict__ Ul,
                                                      const bf16* __restrict__ Gneg) {
  __shared__ bf16 ST[64 * 72];
  __shared__ bf16 Ubt[64 * 72];
  __shared__ bf16 Pt[64 * 72];
  __shared__ bf16 KTl[64 * 72];
  const int bh = blockIdx.x, h = bh & (NH - 1), b = bh >> 5;
  const int wave = threadIdx.x >> 6, lane = threadIdx.x & 63;
  const int frow = lane & 15, q4 = lane >> 4, fk = q4 * 8;
  const int cm = q4 * 4;
  for (int i = threadIdx.x; i < 64 * 72 / 2; i += 256) ((unsigned int*)ST)[i] = 0u;
  __syncthreads();
  f32x4 sacc[4] = {};
  #pragma unroll 1
  for (int c = 0; c < NCH; ++c) {
    const bf16* Gc = Gneg + ((size_t)bh * NCH + c) * 4096;
    const size_t qkb = ((size_t)b * NT + c * 64) * ND + (size_t)h * 64;
    {
      short8 r0 = *(const short8*)(k16 + qkb + (size_t)lane * ND + 16 * wave);
      short8 r1 = *(const short8*)(k16 + qkb + (size_t)lane * ND + 16 * wave + 8);
      #pragma unroll
      for (int j = 0; j < 8; ++j) {
        KTl[(16 * wave + j) * 72 + lane]     = ((const bf16*)&r0)[j];
        KTl[(16 * wave + 8 + j) * 72 + lane] = ((const bf16*)&r1)[j];
      }
    }
    short8 ga0 = *(const short8*)(Gc + (16 * wave + frow) * 64 + fk);
    short8 ga1 = *(const short8*)(Gc + (16 * wave + frow) * 64 + 32 + fk);
    #pragma unroll
    for (int n = 0; n < 4; ++n) {
      f32x4 acc;
      #pragma unroll
      for (int r = 0; r < 4; ++r)
        acc[r] = __bfloat162float(Ul[qkb + (size_t)(16 * wave + cm + r) * ND + 16 * n + frow]);
      acc = __builtin_amdgcn_mfma_f32_16x16x32_bf16(ga0, *(const short8*)(ST + (16 * n + frow) * 72 + fk), acc, 0, 0, 0);
      acc = __builtin_amdgcn_mfma_f32_16x16x32_bf16(ga1, *(const short8*)(ST + (16 * n + frow) * 72 + 32 + fk), acc, 0, 0, 0);
      #pragma unroll
      for (int r = 0; r < 4; ++r)
        Ubt[(16 * n + frow) * 72 + 16 * wave + cm + r] = __float2bfloat16(acc[r]);
    }
    __syncthreads();
    short8 qa0 = *(const short8*)(q16 + qkb + (size_t)(16 * wave + frow) * ND + fk);
    short8 qa1 = *(const short8*)(q16 + qkb + (size_t)(16 * wave + frow) * ND + 32 + fk);
    #pragma unroll
    for (int n = 0; n < 4; ++n) {
      f32x4 acc = {};
      acc = __builtin_amdgcn_mfma_f32_16x16x32_bf16(qa0, *(const short8*)(k16 + qkb + (size_t)(16 * n + frow) * ND + fk), acc, 0, 0, 0);
      acc = __builtin_amdgcn_mfma_f32_16x16x32_bf16(qa1, *(const short8*)(k16 + qkb + (size_t)(16 * n + frow) * ND + 32 + fk), acc, 0, 0, 0);
      #pragma unroll
      for (int r = 0; r < 4; ++r) {
        const int mg = 16 * wave + cm + r, ng = 16 * n + frow;
        Pt[mg * 72 + ng] = __float2bfloat16(ng <= mg ? acc[r] : 0.f);
      }
    }
    __syncthreads();
    short8 pa0 = *(const short8*)(Pt + (16 * wave + frow) * 72 + fk);
    short8 pa1 = *(const short8*)(Pt + (16 * wave + frow) * 72 + 32 + fk);
    #pragma unroll
    for (int n = 0; n < 4; ++n) {
      f32x4 acc = {};
      acc = __builtin_amdgcn_mfma_f32_16x16x32_bf16(qa0, *(const short8*)(ST + (16 * n + frow) * 72 + fk), acc, 0, 0, 0);
      acc = __builtin_amdgcn_mfma_f32_16x16x32_bf16(qa1, *(const short8*)(ST + (16 * n + frow) * 72 + 32 + fk), acc, 0, 0, 0);
      acc = __builtin_amdgcn_mfma_f32_16x16x32_bf16(pa0, *(const short8*)(Ubt + (16 * n + frow) * 72 + fk), acc, 0, 0, 0);
      acc = __builtin_amdgcn_mfma_f32_16x16x32_bf16(pa1, *(const short8*)(Ubt + (16 * n + frow) * 72 + 32 + fk), acc, 0, 0, 0);
      #pragma unroll
      for (int r = 0; r < 4; ++r)
        q16[qkb + (size_t)(16 * wave + cm + r) * ND + 16 * n + frow] = __float2bfloat16(acc[r]);
    }
    __syncthreads();
    short8 ua0 = *(const short8*)(Ubt + (16 * wave + frow) * 72 + fk);
    short8 ua1 = *(const short8*)(Ubt + (16 * wave + frow) * 72 + 32 + fk);
    #pragma unroll
    for (int n = 0; n < 4; ++n) {
      sacc[n] = __builtin_amdgcn_mfma_f32_16x16x32_bf16(ua0, *(const short8*)(KTl + (16 * n + frow) * 72 + fk), sacc[n], 0, 0, 0);
      sacc[n] = __builtin_amdgcn_mfma_f32_16x16x32_bf16(ua1, *(const short8*)(KTl + (16 * n + frow) * 72 + 32 + fk), sacc[n], 0, 0, 0);
      #pragma unroll
      for (int r = 0; r < 4; ++r)
        ST[(16 * wave + cm + r) * 72 + 16 * n + frow] = __float2bfloat16(sacc[n][r]);
    }
    __syncthreads();
  }
}

extern "C" void kernel_launch(void* const* d_in, const int* in_sizes, int n_in,
                              void* d_out, int out_size, void* d_ws, size_t ws_size,
                              hipStream_t stream) {
  const void* hs = d_in[0];
  const void* Wq = d_in[1];
  const void* Wk = d_in[2];
  const void* Wv = d_in[3];
  const void* Wb = d_in[4];
  const void* bb = d_in[5];
  const void* Wo = d_in[6];

  char* ws = (char*)d_ws;
  size_t off = 0;
  auto alloc = [&](size_t bytes) {
    void* p = ws + off;
    off += (bytes + 255) & ~(size_t)255;
    return p;
  };
  const size_t szW2 = (size_t)32 * 1024 * 1024;  // WT (26.2 MiB weights) + AcT alias region
  const size_t szM  = (size_t)NM * ND * 2;       // 16 MiB
  const size_t szB2 = (size_t)NM * 256 * 2;      // 2 MiB (beta logits, 256-padded)
  const size_t szB  = (size_t)NM * 128 * 2;      // fallback beta (128-padded)
  const size_t need_fused = 512 + szW2 + 4 * szM + szB2 + szM;   // ~119.6 MB

  if (ws_size >= need_fused) {
    // ---- fused path ----
    int*  flag  = (int*) alloc(256);
    bf16* WT    = (bf16*)alloc(szW2);  // weights [0,26.2Mi); later Gneg [0,16Mi) + AcT [16,32Mi)
    bf16* hs16  = (bf16*)alloc(szM);   // -> Sbuf after fused GEMM
    bf16* q16   = (bf16*)alloc(szM);   // O in place
    bf16* k16   = (bf16*)alloc(szM);
    bf16* v16   = (bf16*)alloc(szM);   // U^T (transposed-in-place)
    bf16* betab = (bf16*)alloc(szB2);
    bf16* Dc    = (bf16*)alloc(szM);
    bf16* Gneg  = WT;                                    // [0,16MiB) dead after fused GEMM
    bf16* AcT   = WT + (size_t)8 * 1024 * 1024;          // [16,32MiB)
    bf16* WoT   = AcT;                                   // reused after state_seq
    bf16* Sbuf  = hs16;

    detect_dtype<<<1, 64, 0, stream>>>((const unsigned short*)hs, flag);
    convert_bf16<<<(NM * ND) / (256 * 8), 256, 0, stream>>>(hs, hs16, (long)NM * ND, flag);

    transpose_qkvb<<<dim3(32, 32, 4), 256, 0, stream>>>(Wq, Wk, Wv, Wb, WT, flag);
    gemm128<<<800, 512, 0, stream>>>(hs16, WT, q16, k16, v16, betab,
                                     nullptr, nullptr, ND, 25);

    chunk_scan<<<NB * NH * NCH, 256, 0, stream>>>(k16, v16, betab, bb, flag, Gneg, AcT, Dc);
    state_seq<<<NB * NH, 256, 0, stream>>>(AcT, Dc, Sbuf);
    chunk_out<<<NB * NH * NCH, 256, 0, stream>>>(q16, k16, v16, Gneg, Sbuf);

    transpose_cvt<<<dim3(32, 32), 256, 0, stream>>>(Wo, WoT, 2048, 2048, flag);
    gemm128o<<<512, 512, 0, stream>>>(q16, WoT, d_out, flag, ND, 16);
  } else {
    // ---- compact fallback (proven ~73 MB footprint) ----
    int*  flag  = (int*) alloc(256);
    bf16* Wt    = (bf16*)alloc((size_t)2048 * 2048 * 2);
    bf16* hs16  = (bf16*)alloc(szM);   // -> Gneg
    bf16* q16   = (bf16*)alloc(szM);
    bf16* k16   = (bf16*)alloc(szM);
    bf16* v16   = (bf16*)alloc(szM);
    bf16* betab = (bf16*)alloc(szB);
    bf16* Gneg  = hs16;

    detect_dtype<<<1, 64, 0, stream>>>((const unsigned short*)hs, flag);
    convert_bf16<<<(NM * ND) / (256 * 8), 256, 0, stream>>>(hs, hs16, (long)NM * ND, flag);

    transpose_cvt<<<dim3(32, 32), 256, 0, stream>>>(Wq, Wt, 2048, 2048, flag);
    gemm_bt<<<dim3(16, 32), 256, 0, stream>>>(hs16, Wt, q16, k16, v16, betab, nullptr, nullptr, NM, ND, 0);
    transpose_cvt<<<dim3(32, 32), 256, 0, stream>>>(Wk, Wt, 2048, 2048, flag);
    gemm_bt<<<dim3(16, 32), 256, 0, stream>>>(hs16, Wt, q16, k16, v16, betab, nullptr, nullptr, NM, ND, 2048);
    transpose_cvt<<<dim3(32, 32), 256, 0, stream>>>(Wv, Wt, 2048, 2048, flag);
    gemm_bt<<<dim3(16, 32), 256, 0, stream>>>(hs16, Wt, q16, k16, v16, betab, nullptr, nullptr, NM, ND, 4096);
    transpose_cvt<<<dim3(2, 32),  256, 0, stream>>>(Wb, Wt, 2048, 32, flag);
    gemm_bt<<<dim3(1, 32), 256, 0, stream>>>(hs16, Wt, q16, k16, v16, betab, nullptr, nullptr, NM, ND, 6144);

    chunk_scan_c<<<NB * NH * NCH, 128, 0, stream>>>(k16, v16, betab, bb, flag, Gneg);
    chunk_seq_mono<<<NB * NH, 256, 0, stream>>>(q16, k16, v16, Gneg);

    transpose_cvt<<<dim3(32, 32), 256, 0, stream>>>(Wo, Wt, 2048, 2048, flag);
    gemm_bt<<<dim3(16, 32), 256, 0, stream>>>(q16, Wt, nullptr, nullptr, nullptr, nullptr,
                                              d_out, flag, NM, ND, 0);
  }
}